// Round 1
// baseline (5135.638 us; speedup 1.0000x reference)
//
#include <hip/hip_runtime.h>
#include <math.h>

#define NN 50000
#define NE 400000
#define NG 64
#define HD 128
#define LN_EPS 1e-5f

// ---------------------------------------------------------------------------
// Node encoder: Linear(3,128)+ReLU -> Linear(128,128)+ReLU -> Linear(128,128)
//               -> LayerNorm.  One block (128 threads) per node.
// ---------------------------------------------------------------------------
__global__ __launch_bounds__(128)
void enc_node(const float* __restrict__ x,
              const float* __restrict__ w1, const float* __restrict__ b1,
              const float* __restrict__ w2, const float* __restrict__ b2,
              const float* __restrict__ w3, const float* __restrict__ b3,
              const float* __restrict__ gg, const float* __restrict__ bb,
              float* __restrict__ out)
{
    int node = blockIdx.x;
    int j = threadIdx.x;             // 0..127
    __shared__ float sin0[4];
    __shared__ float s1[HD];
    __shared__ float s2[HD];
    __shared__ float part[4];
    __shared__ float stat[2];
    if (j < 3) sin0[j] = x[node*3 + j];
    __syncthreads();
    float a = b1[j];
#pragma unroll
    for (int i = 0; i < 3; ++i) a = fmaf(sin0[i], w1[i*HD + j], a);
    s1[j] = fmaxf(a, 0.f);
    __syncthreads();
    a = b2[j];
    for (int i = 0; i < HD; ++i) a = fmaf(s1[i], w2[i*HD + j], a);
    s2[j] = fmaxf(a, 0.f);
    __syncthreads();
    a = b3[j];
    for (int i = 0; i < HD; ++i) a = fmaf(s2[i], w3[i*HD + j], a);
    // LayerNorm across the 128 threads (2 waves)
    float s = a, q = a*a;
    for (int o = 32; o > 0; o >>= 1) { s += __shfl_down(s, o); q += __shfl_down(q, o); }
    int wid = j >> 6, lane = j & 63;
    if (lane == 0) { part[wid] = s; part[2 + wid] = q; }
    __syncthreads();
    if (j == 0) {
        float S = part[0] + part[1], Q = part[2] + part[3];
        float mu = S * (1.f/HD);
        stat[0] = mu;
        stat[1] = Q * (1.f/HD) - mu*mu;
    }
    __syncthreads();
    out[node*HD + j] = (a - stat[0]) * rsqrtf(stat[1] + LN_EPS) * gg[j] + bb[j];
}

// ---------------------------------------------------------------------------
// xw = h @ W  (N x 128 @ 128 x 128). One block (128 threads) per node.
// ---------------------------------------------------------------------------
__global__ __launch_bounds__(128)
void gemm_nh(const float* __restrict__ hin, const float* __restrict__ w,
             float* __restrict__ out)
{
    int node = blockIdx.x, j = threadIdx.x;
    __shared__ float s[HD];
    s[j] = hin[node*HD + j];
    __syncthreads();
    float a = 0.f;
    for (int i = 0; i < HD; ++i) a = fmaf(s[i], w[i*HD + j], a);
    out[node*HD + j] = a;
}

__global__ __launch_bounds__(256)
void deg_count(const int* __restrict__ ei, float* __restrict__ deg)
{
    int e = blockIdx.x*256 + threadIdx.x;
    if (e < NE) atomicAdd(&deg[ei[NE + e]], 1.f);
}

__global__ __launch_bounds__(256)
void dinv_k(const float* __restrict__ deg, float* __restrict__ dinv)
{
    int n = blockIdx.x*256 + threadIdx.x;
    if (n < NN) dinv[n] = rsqrtf(deg[n] + 1.f);
}

// msgs scatter: agg[dst] += xw[src] * dinv[src]*dinv[dst]
__global__ __launch_bounds__(256)
void gcn_scatter(const float* __restrict__ xw, const int* __restrict__ ei,
                 const float* __restrict__ dinv, float* __restrict__ agg)
{
    int idx = blockIdx.x*256 + threadIdx.x;   // e*128 + j
    int e = idx >> 7, j = idx & 127;
    int s = ei[e], d = ei[NE + e];
    float c = dinv[s] * dinv[d];
    atomicAdd(&agg[d*HD + j], xw[s*HD + j] * c);
}

// h_out = (agg + xw*dinv^2 + b) [relu?]
__global__ __launch_bounds__(256)
void gcn_combine(const float* __restrict__ agg, const float* __restrict__ xw,
                 const float* __restrict__ dinv, const float* __restrict__ b,
                 float* __restrict__ outp, int do_relu)
{
    int idx = blockIdx.x*256 + threadIdx.x;   // n*128 + j
    int n = idx >> 7, j = idx & 127;
    float di = dinv[n];
    float v = agg[idx] + xw[idx]*di*di + b[j];
    if (do_relu) v = fmaxf(v, 0.f);
    outp[idx] = v;
}

__global__ __launch_bounds__(256)
void pool_kernel(const float* __restrict__ h, const int* __restrict__ batch,
                 float* __restrict__ sums, float* __restrict__ cnts)
{
    int idx = blockIdx.x*256 + threadIdx.x;   // n*128 + j
    int n = idx >> 7, j = idx & 127;
    int g = batch[n];
    atomicAdd(&sums[g*HD + j], h[idx]);
    if (j == 0) atomicAdd(&cnts[g], 1.f);
}

// graph feature MLP: relu(gmean@gp1+b) -> LN(@gp2+b).  One block per graph.
__global__ __launch_bounds__(128)
void graph_feat(const float* __restrict__ sums, const float* __restrict__ cnts,
                const float* __restrict__ w1, const float* __restrict__ b1,
                const float* __restrict__ w2, const float* __restrict__ b2,
                const float* __restrict__ gg, const float* __restrict__ bb,
                float* __restrict__ gf)
{
    int gi = blockIdx.x, j = threadIdx.x;
    __shared__ float s0[HD];
    __shared__ float s1[HD];
    __shared__ float part[4];
    __shared__ float stat[2];
    float cnt = fmaxf(cnts[gi], 1.f);
    s0[j] = sums[gi*HD + j] / cnt;
    __syncthreads();
    float a = b1[j];
    for (int i = 0; i < HD; ++i) a = fmaf(s0[i], w1[i*HD + j], a);
    s1[j] = fmaxf(a, 0.f);
    __syncthreads();
    a = b2[j];
    for (int i = 0; i < HD; ++i) a = fmaf(s1[i], w2[i*HD + j], a);
    float s = a, q = a*a;
    for (int o = 32; o > 0; o >>= 1) { s += __shfl_down(s, o); q += __shfl_down(q, o); }
    int wid = j >> 6, lane = j & 63;
    if (lane == 0) { part[wid] = s; part[2 + wid] = q; }
    __syncthreads();
    if (j == 0) {
        float S = part[0] + part[1], Q = part[2] + part[3];
        float mu = S * (1.f/HD);
        stat[0] = mu;
        stat[1] = Q * (1.f/HD) - mu*mu;
    }
    __syncthreads();
    gf[gi*HD + j] = (a - stat[0]) * rsqrtf(stat[1] + LN_EPS) * gg[j] + bb[j];
}

// ---------------------------------------------------------------------------
// Fused per-edge kernel: edge encoder (3->128->128->128+LN) computed inline,
// then comb=[h[src],h[dst],gf[batch[src]],ef] (512) -> tanh(256) -> tanh(128)
// -> relu(64) -> sigmoid(1).  32 edges per block, 256 threads.
// LDS: bufA(16KB) + bufB(16KB) + bufC(32KB) = 64KB.
// ---------------------------------------------------------------------------
__global__ __launch_bounds__(256)
void edge_mlp(const float* __restrict__ h,     // [N,H] (post-GCN2)
              const float* __restrict__ gf,    // [G,H]
              const int* __restrict__ ei,      // [2,E]
              const int* __restrict__ batch,   // [N]
              const float* __restrict__ ea,    // [E,3]
              const float* __restrict__ ew1, const float* __restrict__ eb1,
              const float* __restrict__ ew2, const float* __restrict__ eb2,
              const float* __restrict__ ew3, const float* __restrict__ eb3,
              const float* __restrict__ egm, const float* __restrict__ ebb,
              const float* __restrict__ p1w, const float* __restrict__ p1b,
              const float* __restrict__ p2w, const float* __restrict__ p2b,
              const float* __restrict__ p3w, const float* __restrict__ p3b,
              const float* __restrict__ p4w, const float* __restrict__ p4b,
              float* __restrict__ out)
{
    __shared__ float bufA[32*HD];    // 16KB
    __shared__ float bufB[32*HD];    // 16KB
    __shared__ float bufC[32*256];   // 32KB  (also holds LN stats early on)
    int t = threadIdx.x;
    int e0 = blockIdx.x * 32;

    // ---------------- edge encoder ----------------
    if (t < 96) bufA[t] = ea[e0*3 + t];           // 32 edges x 3 attrs
    __syncthreads();
    // L1: 3->128 relu (ea in bufA -> bufB)
    for (int r = 0; r < 16; ++r) {
        int idx = r*256 + t; int e = idx >> 7, j = idx & 127;
        float a = eb1[j];
#pragma unroll
        for (int i = 0; i < 3; ++i) a = fmaf(bufA[e*3 + i], ew1[i*HD + j], a);
        bufB[idx] = fmaxf(a, 0.f);
    }
    __syncthreads();
    // L2: 128->128 relu (bufB -> bufA)
    for (int r = 0; r < 16; ++r) {
        int idx = r*256 + t; int e = idx >> 7, j = idx & 127;
        float a = eb2[j];
        for (int i = 0; i < HD; ++i) a = fmaf(bufB[e*HD + i], ew2[i*HD + j], a);
        bufA[idx] = fmaxf(a, 0.f);
    }
    __syncthreads();
    // L3: 128->128 (bufA -> bufB, pre-LN)
    for (int r = 0; r < 16; ++r) {
        int idx = r*256 + t; int e = idx >> 7, j = idx & 127;
        float a = eb3[j];
        for (int i = 0; i < HD; ++i) a = fmaf(bufA[e*HD + i], ew3[i*HD + j], a);
        bufB[idx] = a;
    }
    __syncthreads();
    // LN stats per edge (wave w handles edges w*8..w*8+7); stats in bufC[0:64]
    {
        int wid = t >> 6, lane = t & 63;
        for (int er = 0; er < 8; ++er) {
            int e = wid*8 + er;
            float v0 = bufB[e*HD + lane], v1 = bufB[e*HD + 64 + lane];
            float s = v0 + v1, q = v0*v0 + v1*v1;
#pragma unroll
            for (int o = 1; o < 64; o <<= 1) { s += __shfl_xor(s, o); q += __shfl_xor(q, o); }
            if (lane == 0) {
                float mu = s * (1.f/HD);
                bufC[e] = mu;
                bufC[32 + e] = q * (1.f/HD) - mu*mu;
            }
        }
    }
    __syncthreads();
    // normalize -> bufA = ef
    for (int r = 0; r < 16; ++r) {
        int idx = r*256 + t; int e = idx >> 7, j = idx & 127;
        bufA[idx] = (bufB[idx] - bufC[e]) * rsqrtf(bufC[32 + e] + LN_EPS) * egm[j] + ebb[j];
    }
    __syncthreads();

    // ---------------- ep1: comb[32,512] @ p1w[512,256], tanh ----------------
    int q = t & 63;                 // feature base (j = q + 64*f)
    int eg8 = (t >> 6) * 8;         // this thread's 8 edges
    float acc[4][8];
#pragma unroll
    for (int f = 0; f < 4; ++f) {
        float bv = p1b[q + 64*f];
#pragma unroll
        for (int ee = 0; ee < 8; ++ee) acc[f][ee] = bv;
    }
    for (int c = 0; c < 4; ++c) {
        const float* chunk;
        if (c < 3) {
            // gather chunk c into bufB: 0=h[src], 1=h[dst], 2=gf[batch[src]]
            for (int r = 0; r < 16; ++r) {
                int idx = r*256 + t; int e = idx >> 7, j = idx & 127;
                int geid = e0 + e;
                int row;
                const float* srcp;
                if (c == 0)      { row = ei[geid];            srcp = h;  }
                else if (c == 1) { row = ei[NE + geid];       srcp = h;  }
                else             { row = batch[ei[geid]];     srcp = gf; }
                bufB[idx] = srcp[row*HD + j];
            }
            chunk = bufB;
        } else {
            chunk = bufA;   // ef
        }
        __syncthreads();
        const float* wbase = p1w + (size_t)(c*HD)*256;
        for (int i = 0; i < HD; ++i) {
            float w0 = wbase[i*256 + q];
            float w1v = wbase[i*256 + q + 64];
            float w2v = wbase[i*256 + q + 128];
            float w3v = wbase[i*256 + q + 192];
            float cv[8];
#pragma unroll
            for (int ee = 0; ee < 8; ++ee) cv[ee] = chunk[(eg8 + ee)*HD + i];
#pragma unroll
            for (int ee = 0; ee < 8; ++ee) {
                acc[0][ee] = fmaf(cv[ee], w0,  acc[0][ee]);
                acc[1][ee] = fmaf(cv[ee], w1v, acc[1][ee]);
                acc[2][ee] = fmaf(cv[ee], w2v, acc[2][ee]);
                acc[3][ee] = fmaf(cv[ee], w3v, acc[3][ee]);
            }
        }
        __syncthreads();
    }
#pragma unroll
    for (int f = 0; f < 4; ++f)
#pragma unroll
        for (int ee = 0; ee < 8; ++ee)
            bufC[(eg8 + ee)*256 + q + 64*f] = tanhf(acc[f][ee]);
    __syncthreads();

    // ---------------- ep2: [32,256] @ p2w[256,128], tanh -> bufB ----------------
    float a2[2][8];
#pragma unroll
    for (int f = 0; f < 2; ++f) {
        float bv = p2b[q + 64*f];
#pragma unroll
        for (int ee = 0; ee < 8; ++ee) a2[f][ee] = bv;
    }
    for (int i = 0; i < 256; ++i) {
        float w0 = p2w[i*HD + q];
        float w1v = p2w[i*HD + q + 64];
        float cv[8];
#pragma unroll
        for (int ee = 0; ee < 8; ++ee) cv[ee] = bufC[(eg8 + ee)*256 + i];
#pragma unroll
        for (int ee = 0; ee < 8; ++ee) {
            a2[0][ee] = fmaf(cv[ee], w0,  a2[0][ee]);
            a2[1][ee] = fmaf(cv[ee], w1v, a2[1][ee]);
        }
    }
    __syncthreads();
#pragma unroll
    for (int f = 0; f < 2; ++f)
#pragma unroll
        for (int ee = 0; ee < 8; ++ee)
            bufB[(eg8 + ee)*HD + q + 64*f] = tanhf(a2[f][ee]);
    __syncthreads();

    // ---------------- ep3: [32,128] @ p3w[128,64], relu -> bufA[0:2048] ----------------
    float a3[8];
    {
        float bv = p3b[q];
#pragma unroll
        for (int ee = 0; ee < 8; ++ee) a3[ee] = bv;
    }
    for (int i = 0; i < HD; ++i) {
        float w0 = p3w[i*64 + q];
        float cv[8];
#pragma unroll
        for (int ee = 0; ee < 8; ++ee) cv[ee] = bufB[(eg8 + ee)*HD + i];
#pragma unroll
        for (int ee = 0; ee < 8; ++ee) a3[ee] = fmaf(cv[ee], w0, a3[ee]);
    }
    __syncthreads();
#pragma unroll
    for (int ee = 0; ee < 8; ++ee) bufA[(eg8 + ee)*64 + q] = fmaxf(a3[ee], 0.f);
    __syncthreads();

    // ---------------- ep4: [32,64] @ p4w[64,1], sigmoid ----------------
    if (t < 32) {
        float a = p4b[0];
        for (int i = 0; i < 64; ++i) a = fmaf(bufA[t*64 + i], p4w[i], a);
        out[e0 + t] = 1.f / (1.f + expf(-a));
    }
}

// ---------------------------------------------------------------------------
extern "C" void kernel_launch(void* const* d_in, const int* in_sizes, int n_in,
                              void* d_out, int out_size, void* d_ws, size_t ws_size,
                              hipStream_t stream)
{
    const float* x     = (const float*)d_in[0];
    const int*   ei    = (const int*)  d_in[1];
    const float* ea    = (const float*)d_in[2];
    const int*   batch = (const int*)  d_in[3];
    const float* ne1w = (const float*)d_in[4];  const float* ne1b = (const float*)d_in[5];
    const float* ne2w = (const float*)d_in[6];  const float* ne2b = (const float*)d_in[7];
    const float* ne3w = (const float*)d_in[8];  const float* ne3b = (const float*)d_in[9];
    const float* neg  = (const float*)d_in[10]; const float* nebb = (const float*)d_in[11];
    const float* ee1w = (const float*)d_in[12]; const float* ee1b = (const float*)d_in[13];
    const float* ee2w = (const float*)d_in[14]; const float* ee2b = (const float*)d_in[15];
    const float* ee3w = (const float*)d_in[16]; const float* ee3b = (const float*)d_in[17];
    const float* eeg  = (const float*)d_in[18]; const float* eebb = (const float*)d_in[19];
    const float* g1w  = (const float*)d_in[20]; const float* g1b  = (const float*)d_in[21];
    const float* g2w  = (const float*)d_in[22]; const float* g2b  = (const float*)d_in[23];
    const float* gp1w = (const float*)d_in[24]; const float* gp1b = (const float*)d_in[25];
    const float* gp2w = (const float*)d_in[26]; const float* gp2b = (const float*)d_in[27];
    const float* gpg  = (const float*)d_in[28]; const float* gpbb = (const float*)d_in[29];
    const float* p1w  = (const float*)d_in[30]; const float* p1b  = (const float*)d_in[31];
    const float* p2w  = (const float*)d_in[32]; const float* p2b  = (const float*)d_in[33];
    const float* p3w  = (const float*)d_in[34]; const float* p3b  = (const float*)d_in[35];
    const float* p4w  = (const float*)d_in[36]; const float* p4b  = (const float*)d_in[37];

    float* ws   = (float*)d_ws;
    float* hbuf = ws;                       // N*H
    float* xw   = hbuf + (size_t)NN*HD;     // N*H
    float* agg  = xw   + (size_t)NN*HD;     // N*H
    float* deg  = agg  + (size_t)NN*HD;     // N
    float* dinv = deg  + NN;                // N
    float* sums = dinv + NN;                // G*H
    float* cnts = sums + NG*HD;             // G
    float* gfb  = cnts + NG;                // G*H

    float* out = (float*)d_out;

    hipMemsetAsync(agg,  0, (size_t)NN*HD*sizeof(float), stream);
    hipMemsetAsync(deg,  0, (size_t)NN*sizeof(float), stream);
    hipMemsetAsync(sums, 0, (size_t)(NG*HD + NG)*sizeof(float), stream);

    // node encoder -> hbuf
    enc_node<<<NN, 128, 0, stream>>>(x, ne1w, ne1b, ne2w, ne2b, ne3w, ne3b,
                                     neg, nebb, hbuf);
    // degrees (shared by both GCN layers)
    deg_count<<<(NE + 255)/256, 256, 0, stream>>>(ei, deg);
    dinv_k<<<(NN + 255)/256, 256, 0, stream>>>(deg, dinv);

    // GCN layer 1 (relu)
    gemm_nh<<<NN, 128, 0, stream>>>(hbuf, g1w, xw);
    gcn_scatter<<<(NE*HD)/256, 256, 0, stream>>>(xw, ei, dinv, agg);
    gcn_combine<<<(NN*HD)/256, 256, 0, stream>>>(agg, xw, dinv, g1b, hbuf, 1);

    // GCN layer 2 (no relu)
    hipMemsetAsync(agg, 0, (size_t)NN*HD*sizeof(float), stream);
    gemm_nh<<<NN, 128, 0, stream>>>(hbuf, g2w, xw);
    gcn_scatter<<<(NE*HD)/256, 256, 0, stream>>>(xw, ei, dinv, agg);
    gcn_combine<<<(NN*HD)/256, 256, 0, stream>>>(agg, xw, dinv, g2b, hbuf, 0);

    // global mean pool + graph MLP
    pool_kernel<<<(NN*HD)/256, 256, 0, stream>>>(hbuf, batch, sums, cnts);
    graph_feat<<<NG, 128, 0, stream>>>(sums, cnts, gp1w, gp1b, gp2w, gp2b,
                                       gpg, gpbb, gfb);

    // fused edge encoder + edge-score MLP
    edge_mlp<<<NE/32, 256, 0, stream>>>(hbuf, gfb, ei, batch, ea,
                                        ee1w, ee1b, ee2w, ee2b, ee3w, ee3b,
                                        eeg, eebb,
                                        p1w, p1b, p2w, p2b, p3w, p3b, p4w, p4b,
                                        out);
}

// Round 2
// 1689.313 us; speedup vs baseline: 3.0401x; 3.0401x over previous
//
#include <hip/hip_runtime.h>
#include <math.h>

#define NN 50000
#define NE 400000
#define NG 64
#define HD 128
#define LN_EPS 1e-5f

typedef unsigned short u16;
typedef unsigned int u32;
typedef __attribute__((ext_vector_type(8))) short short8;
typedef __attribute__((ext_vector_type(4))) float f32x4;

#define MFMA16(a,b,c) __builtin_amdgcn_mfma_f32_16x16x32_bf16((a),(b),(c),0,0,0)

__device__ __forceinline__ u16 f2bf(float f) {
    union { float f; u32 u; } v; v.f = f;
    u32 r = v.u + 0x7FFFu + ((v.u >> 16) & 1u);
    return (u16)(r >> 16);
}
__device__ __forceinline__ float bf2f(u32 hs) {
    union { u32 u; float f; } v; v.u = hs << 16;
    return v.f;
}
__device__ __forceinline__ float fast_tanh(float x) {
    float xc = fminf(fmaxf(x, -15.f), 15.f);
    float t = __expf(2.f * xc);
    return __fdividef(t - 1.f, t + 1.f);
}
__device__ __forceinline__ float fast_sigmoid(float x) {
    return __fdividef(1.f, 1.f + __expf(-x));
}

// A-fragment load from swizzled [64][128] bf16 chunk buffer.
// lane l supplies A[row=16*mi+(l&15)][k = kk*32 + (l>>4)*8 + 0..7]
__device__ __forceinline__ short8 loadA(const u16* buf, int mi, int kk, int l) {
    int row = mi*16 + (l & 15);
    int ci  = kk*4 + (l >> 4);
    return *(const short8*)(buf + row*128 + ((ci ^ (row & 7)) << 3));
}
// B-fragment from packed weights: frag (nt, ks) is 64 lanes x 16B contiguous
__device__ __forceinline__ short8 loadB(const u16* wp, int nt, int ks, int nk, int l) {
    return *(const short8*)(wp + (((nt*nk + ks)*64 + l) << 3));
}
__device__ __forceinline__ void storeChunkBf(u16* buf, int row, int col, float v) {
    int ci = col >> 3;
    buf[row*128 + ((ci ^ (row & 7)) << 3) + (col & 7)] = f2bf(v);
}

// ---------------------------------------------------------------------------
// Pack W[K,N] fp32 -> bf16 MFMA B-fragment order:
// out[((nt*(K/32)+kk)*64 + l)*8 + e] = W[kk*32 + (l>>4)*8 + e][nt*16 + (l&15)]
// ---------------------------------------------------------------------------
__global__ __launch_bounds__(256)
void pack_w(const float* __restrict__ w, u16* __restrict__ out, int K, int N)
{
    int idx = blockIdx.x*256 + threadIdx.x;
    if (idx >= K*N) return;
    int e = idx & 7, l = (idx >> 3) & 63, r = idx >> 9;
    int nk = K >> 5;
    int nt = r / nk, kk = r % nk;
    int k = kk*32 + ((l >> 4) << 3) + e;
    int n = nt*16 + (l & 15);
    out[idx] = f2bf(w[k*N + n]);
}

// ---------------------------------------------------------------------------
// Node encoder (unchanged from round 1)
// ---------------------------------------------------------------------------
__global__ __launch_bounds__(128)
void enc_node(const float* __restrict__ x,
              const float* __restrict__ w1, const float* __restrict__ b1,
              const float* __restrict__ w2, const float* __restrict__ b2,
              const float* __restrict__ w3, const float* __restrict__ b3,
              const float* __restrict__ gg, const float* __restrict__ bb,
              float* __restrict__ out)
{
    int node = blockIdx.x;
    int j = threadIdx.x;
    __shared__ float sin0[4];
    __shared__ float s1[HD];
    __shared__ float s2[HD];
    __shared__ float part[4];
    __shared__ float stat[2];
    if (j < 3) sin0[j] = x[node*3 + j];
    __syncthreads();
    float a = b1[j];
#pragma unroll
    for (int i = 0; i < 3; ++i) a = fmaf(sin0[i], w1[i*HD + j], a);
    s1[j] = fmaxf(a, 0.f);
    __syncthreads();
    a = b2[j];
    for (int i = 0; i < HD; ++i) a = fmaf(s1[i], w2[i*HD + j], a);
    s2[j] = fmaxf(a, 0.f);
    __syncthreads();
    a = b3[j];
    for (int i = 0; i < HD; ++i) a = fmaf(s2[i], w3[i*HD + j], a);
    float s = a, q = a*a;
    for (int o = 32; o > 0; o >>= 1) { s += __shfl_down(s, o); q += __shfl_down(q, o); }
    int wid = j >> 6, lane = j & 63;
    if (lane == 0) { part[wid] = s; part[2 + wid] = q; }
    __syncthreads();
    if (j == 0) {
        float S = part[0] + part[1], Q = part[2] + part[3];
        float mu = S * (1.f/HD);
        stat[0] = mu;
        stat[1] = Q * (1.f/HD) - mu*mu;
    }
    __syncthreads();
    out[node*HD + j] = (a - stat[0]) * rsqrtf(stat[1] + LN_EPS) * gg[j] + bb[j];
}

__global__ __launch_bounds__(128)
void gemm_nh(const float* __restrict__ hin, const float* __restrict__ w,
             float* __restrict__ out)
{
    int node = blockIdx.x, j = threadIdx.x;
    __shared__ float s[HD];
    s[j] = hin[node*HD + j];
    __syncthreads();
    float a = 0.f;
    for (int i = 0; i < HD; ++i) a = fmaf(s[i], w[i*HD + j], a);
    out[node*HD + j] = a;
}

__global__ __launch_bounds__(256)
void deg_count(const int* __restrict__ ei, float* __restrict__ deg)
{
    int e = blockIdx.x*256 + threadIdx.x;
    if (e < NE) atomicAdd(&deg[ei[NE + e]], 1.f);
}

__global__ __launch_bounds__(256)
void dinv_k(const float* __restrict__ deg, float* __restrict__ dinv)
{
    int n = blockIdx.x*256 + threadIdx.x;
    if (n < NN) dinv[n] = rsqrtf(deg[n] + 1.f);
}

__global__ __launch_bounds__(256)
void gcn_scatter(const float* __restrict__ xw, const int* __restrict__ ei,
                 const float* __restrict__ dinv, float* __restrict__ agg)
{
    int idx = blockIdx.x*256 + threadIdx.x;
    int e = idx >> 7, j = idx & 127;
    int s = ei[e], d = ei[NE + e];
    float c = dinv[s] * dinv[d];
    atomicAdd(&agg[d*HD + j], xw[s*HD + j] * c);
}

// h_out = (agg + xw*dinv^2 + b) [relu?]; optionally also emit bf16 copy
__global__ __launch_bounds__(256)
void gcn_combine(const float* __restrict__ agg, const float* __restrict__ xw,
                 const float* __restrict__ dinv, const float* __restrict__ b,
                 float* __restrict__ outp, u16* __restrict__ outbf, int do_relu)
{
    int idx = blockIdx.x*256 + threadIdx.x;
    int n = idx >> 7, j = idx & 127;
    float di = dinv[n];
    float v = agg[idx] + xw[idx]*di*di + b[j];
    if (do_relu) v = fmaxf(v, 0.f);
    outp[idx] = v;
    if (outbf) outbf[idx] = f2bf(v);
}

__global__ __launch_bounds__(256)
void pool_kernel(const float* __restrict__ h, const int* __restrict__ batch,
                 float* __restrict__ sums, float* __restrict__ cnts)
{
    int idx = blockIdx.x*256 + threadIdx.x;
    int n = idx >> 7, j = idx & 127;
    int g = batch[n];
    atomicAdd(&sums[g*HD + j], h[idx]);
    if (j == 0) atomicAdd(&cnts[g], 1.f);
}

__global__ __launch_bounds__(128)
void graph_feat(const float* __restrict__ sums, const float* __restrict__ cnts,
                const float* __restrict__ w1, const float* __restrict__ b1,
                const float* __restrict__ w2, const float* __restrict__ b2,
                const float* __restrict__ gg, const float* __restrict__ bb,
                float* __restrict__ gf, u16* __restrict__ gf16)
{
    int gi = blockIdx.x, j = threadIdx.x;
    __shared__ float s0[HD];
    __shared__ float s1[HD];
    __shared__ float part[4];
    __shared__ float stat[2];
    float cnt = fmaxf(cnts[gi], 1.f);
    s0[j] = sums[gi*HD + j] / cnt;
    __syncthreads();
    float a = b1[j];
    for (int i = 0; i < HD; ++i) a = fmaf(s0[i], w1[i*HD + j], a);
    s1[j] = fmaxf(a, 0.f);
    __syncthreads();
    a = b2[j];
    for (int i = 0; i < HD; ++i) a = fmaf(s1[i], w2[i*HD + j], a);
    float s = a, q = a*a;
    for (int o = 32; o > 0; o >>= 1) { s += __shfl_down(s, o); q += __shfl_down(q, o); }
    int wid = j >> 6, lane = j & 63;
    if (lane == 0) { part[wid] = s; part[2 + wid] = q; }
    __syncthreads();
    if (j == 0) {
        float S = part[0] + part[1], Q = part[2] + part[3];
        float mu = S * (1.f/HD);
        stat[0] = mu;
        stat[1] = Q * (1.f/HD) - mu*mu;
    }
    __syncthreads();
    float v = (a - stat[0]) * rsqrtf(stat[1] + LN_EPS) * gg[j] + bb[j];
    gf[gi*HD + j] = v;
    gf16[gi*HD + j] = f2bf(v);
}

// ---------------------------------------------------------------------------
// Stage 64 gathered bf16 rows into swizzled LDS chunk (4 threads/row)
// ---------------------------------------------------------------------------
__device__ __forceinline__ void stageRows(u16* dst, const u16* __restrict__ srcBase,
                                          const int* ridx, int t)
{
    int e = t >> 2, part = t & 3;
    const u16* src = srcBase + (size_t)ridx[e]*HD + part*32;
    u16* drow = dst + e*128;
    int re = e & 7;
#pragma unroll
    for (int w = 0; w < 4; ++w) {
        int ci = part*4 + w;
        *(short8*)(drow + ((ci ^ re) << 3)) = *(const short8*)(src + w*8);
    }
}

// ---------------------------------------------------------------------------
// Fused edge kernel, MFMA bf16 version. 64 edges/block, 256 threads (4 waves).
// ---------------------------------------------------------------------------
__global__ __launch_bounds__(256, 3)
void edge_mlp_mfma(const u16* __restrict__ hbf, const u16* __restrict__ gfbf,
                   const int* __restrict__ ei, const int* __restrict__ batch,
                   const float* __restrict__ ea,
                   const float* __restrict__ ew1, const float* __restrict__ eb1,
                   const u16* __restrict__ ew2p, const float* __restrict__ eb2,
                   const u16* __restrict__ ew3p, const float* __restrict__ eb3,
                   const float* __restrict__ egm, const float* __restrict__ ebb,
                   const u16* __restrict__ p1wp, const float* __restrict__ p1b,
                   const u16* __restrict__ p2wp, const float* __restrict__ p2b,
                   const u16* __restrict__ p3wp, const float* __restrict__ p3b,
                   const float* __restrict__ p4w, const float* __restrict__ p4b,
                   float* __restrict__ out)
{
    __shared__ u16 bufChunk[64*128];   // 16KB swizzled A-chunk
    __shared__ u16 bufWide[64*256];    // 32KB (2 chunks / fp32 scratch)
    __shared__ float sEa[192];
    __shared__ int sSrc[64], sDst[64], sGf[64];
    __shared__ float rstat[128];

    const int t = threadIdx.x;
    const int l = t & 63;
    const int wid = t >> 6;
    const int e0 = blockIdx.x * 64;

    if (t < 64) {
        int s = ei[e0 + t];
        sSrc[t] = s;
        sDst[t] = ei[NE + e0 + t];
        sGf[t]  = batch[s];
    }
    if (t < 192) sEa[t] = ea[e0*3 + t];
    __syncthreads();

    // ---- enc1: relu(ea@ew1+b1) -> bufChunk (bf16, swizzled) ----
    for (int it = 0; it < 16; ++it) {
        int dw = it*256 + t;                 // 4096 dwords = 64x128 bf16
        int e = dw >> 6, cd = dw & 63;
        int c0 = cd*2;
        float x0 = sEa[e*3], x1 = sEa[e*3+1], x2 = sEa[e*3+2];
        float v0 = eb1[c0]   + x0*ew1[c0]   + x1*ew1[HD+c0]   + x2*ew1[2*HD+c0];
        float v1 = eb1[c0+1] + x0*ew1[c0+1] + x1*ew1[HD+c0+1] + x2*ew1[2*HD+c0+1];
        v0 = fmaxf(v0, 0.f); v1 = fmaxf(v1, 0.f);
        int ci = cd >> 2;
        ((u32*)bufChunk)[e*64 + ((ci ^ (e & 7)) << 2) + (cd & 3)] =
            (u32)f2bf(v0) | ((u32)f2bf(v1) << 16);
    }
    __syncthreads();

    // ---- enc2: relu(enc1@ew2+b2) -> bufWide chunk0 ----
    {
        f32x4 acc[4][2];
#pragma unroll
        for (int mi = 0; mi < 4; ++mi)
#pragma unroll
            for (int ni = 0; ni < 2; ++ni) acc[mi][ni] = (f32x4){0.f,0.f,0.f,0.f};
#pragma unroll
        for (int kk = 0; kk < 4; ++kk) {
            short8 af[4];
#pragma unroll
            for (int mi = 0; mi < 4; ++mi) af[mi] = loadA(bufChunk, mi, kk, l);
#pragma unroll
            for (int ni = 0; ni < 2; ++ni) {
                short8 bw = loadB(ew2p, 2*wid + ni, kk, 4, l);
#pragma unroll
                for (int mi = 0; mi < 4; ++mi) acc[mi][ni] = MFMA16(af[mi], bw, acc[mi][ni]);
            }
        }
#pragma unroll
        for (int ni = 0; ni < 2; ++ni) {
            int col = (2*wid + ni)*16 + (l & 15);
            float bias = eb2[col];
#pragma unroll
            for (int mi = 0; mi < 4; ++mi)
#pragma unroll
                for (int rr = 0; rr < 4; ++rr) {
                    int row = mi*16 + ((l >> 4) << 2) + rr;
                    storeChunkBf(bufWide, row, col, fmaxf(acc[mi][ni][rr] + bias, 0.f));
                }
        }
    }
    __syncthreads();

    // ---- enc3: enc2@ew3+b3 (pre-LN) -> bufChunk ----
    {
        f32x4 acc[4][2];
#pragma unroll
        for (int mi = 0; mi < 4; ++mi)
#pragma unroll
            for (int ni = 0; ni < 2; ++ni) acc[mi][ni] = (f32x4){0.f,0.f,0.f,0.f};
#pragma unroll
        for (int kk = 0; kk < 4; ++kk) {
            short8 af[4];
#pragma unroll
            for (int mi = 0; mi < 4; ++mi) af[mi] = loadA(bufWide, mi, kk, l);
#pragma unroll
            for (int ni = 0; ni < 2; ++ni) {
                short8 bw = loadB(ew3p, 2*wid + ni, kk, 4, l);
#pragma unroll
                for (int mi = 0; mi < 4; ++mi) acc[mi][ni] = MFMA16(af[mi], bw, acc[mi][ni]);
            }
        }
#pragma unroll
        for (int ni = 0; ni < 2; ++ni) {
            int col = (2*wid + ni)*16 + (l & 15);
            float bias = eb3[col];
#pragma unroll
            for (int mi = 0; mi < 4; ++mi)
#pragma unroll
                for (int rr = 0; rr < 4; ++rr) {
                    int row = mi*16 + ((l >> 4) << 2) + rr;
                    storeChunkBf(bufChunk, row, col, acc[mi][ni][rr] + bias);
                }
        }
    }
    __syncthreads();

    // ---- LN stats per edge (wave wid handles 16 edges) ----
    for (int er = 0; er < 16; ++er) {
        int e = wid*16 + er;
        u32 pk = ((const u32*)bufChunk)[e*64 + l];
        float v0 = bf2f(pk & 0xffffu), v1 = bf2f(pk >> 16);
        float s = v0 + v1, q = v0*v0 + v1*v1;
#pragma unroll
        for (int o = 1; o < 64; o <<= 1) { s += __shfl_xor(s, o); q += __shfl_xor(q, o); }
        if (l == 0) {
            float mu = s * (1.f/HD);
            rstat[e] = mu;
            rstat[64 + e] = rsqrtf(q*(1.f/HD) - mu*mu + LN_EPS);
        }
    }
    __syncthreads();

    // ---- normalize in place: bufChunk = ef ----
    for (int it = 0; it < 16; ++it) {
        int pd = it*256 + t;
        int row = pd >> 6, cwd = pd & 63;
        int ci = (cwd >> 2) ^ (row & 7);
        int col = ci*8 + (cwd & 3)*2;
        u32 pk = ((u32*)bufChunk)[pd];
        float mu = rstat[row], ri = rstat[64 + row];
        float v0 = (bf2f(pk & 0xffffu) - mu)*ri*egm[col]     + ebb[col];
        float v1 = (bf2f(pk >> 16)     - mu)*ri*egm[col + 1] + ebb[col + 1];
        ((u32*)bufChunk)[pd] = (u32)f2bf(v0) | ((u32)f2bf(v1) << 16);
    }
    __syncthreads();

    // ---- ep1: comb[64,512] @ p1w[512,256] + b, tanh -> bufWide ----
    // comb row blocks: 0=h[src], 1=h[dst], 2=gf[batch[src]], 3=ef
    f32x4 acc1[4][4];
#pragma unroll
    for (int mi = 0; mi < 4; ++mi)
#pragma unroll
        for (int ni = 0; ni < 4; ++ni) acc1[mi][ni] = (f32x4){0.f,0.f,0.f,0.f};

    const int cOrd[4] = {3, 0, 1, 2};
    for (int ii = 0; ii < 4; ++ii) {
        int c = cOrd[ii];
        if (ii > 0) {
            __syncthreads();
            const u16* sb = (c == 2) ? gfbf : hbf;
            const int* ridx = (c == 0) ? sSrc : ((c == 1) ? sDst : sGf);
            stageRows(bufChunk, sb, ridx, t);
            __syncthreads();
        }
#pragma unroll
        for (int kk = 0; kk < 4; ++kk) {
            short8 af[4];
#pragma unroll
            for (int mi = 0; mi < 4; ++mi) af[mi] = loadA(bufChunk, mi, kk, l);
            int ks = c*4 + kk;
#pragma unroll
            for (int ni = 0; ni < 4; ++ni) {
                short8 bw = loadB(p1wp, 4*wid + ni, ks, 16, l);
#pragma unroll
                for (int mi = 0; mi < 4; ++mi) acc1[mi][ni] = MFMA16(af[mi], bw, acc1[mi][ni]);
            }
        }
    }
#pragma unroll
    for (int ni = 0; ni < 4; ++ni) {
        int col = (4*wid + ni)*16 + (l & 15);
        float bias = p1b[col];
        u16* dst = bufWide + ((col >> 7) << 13);
        int cc = col & 127;
#pragma unroll
        for (int mi = 0; mi < 4; ++mi)
#pragma unroll
            for (int rr = 0; rr < 4; ++rr) {
                int row = mi*16 + ((l >> 4) << 2) + rr;
                storeChunkBf(dst, row, cc, fast_tanh(acc1[mi][ni][rr] + bias));
            }
    }
    __syncthreads();

    // ---- ep2: [64,256] @ p2w[256,128] + b, tanh -> bufChunk ----
    {
        f32x4 acc[4][2];
#pragma unroll
        for (int mi = 0; mi < 4; ++mi)
#pragma unroll
            for (int ni = 0; ni < 2; ++ni) acc[mi][ni] = (f32x4){0.f,0.f,0.f,0.f};
        for (int kc = 0; kc < 2; ++kc) {
            const u16* abuf = bufWide + (kc << 13);
#pragma unroll
            for (int kk = 0; kk < 4; ++kk) {
                short8 af[4];
#pragma unroll
                for (int mi = 0; mi < 4; ++mi) af[mi] = loadA(abuf, mi, kk, l);
                int ks = kc*4 + kk;
#pragma unroll
                for (int ni = 0; ni < 2; ++ni) {
                    short8 bw = loadB(p2wp, 2*wid + ni, ks, 8, l);
#pragma unroll
                    for (int mi = 0; mi < 4; ++mi) acc[mi][ni] = MFMA16(af[mi], bw, acc[mi][ni]);
                }
            }
        }
#pragma unroll
        for (int ni = 0; ni < 2; ++ni) {
            int col = (2*wid + ni)*16 + (l & 15);
            float bias = p2b[col];
#pragma unroll
            for (int mi = 0; mi < 4; ++mi)
#pragma unroll
                for (int rr = 0; rr < 4; ++rr) {
                    int row = mi*16 + ((l >> 4) << 2) + rr;
                    storeChunkBf(bufChunk, row, col, fast_tanh(acc[mi][ni][rr] + bias));
                }
        }
    }
    __syncthreads();

    // ---- ep3: [64,128] @ p3w[128,64] + b, relu -> bufWide as fp32 ----
    {
        f32x4 acc[4];
#pragma unroll
        for (int mi = 0; mi < 4; ++mi) acc[mi] = (f32x4){0.f,0.f,0.f,0.f};
#pragma unroll
        for (int kk = 0; kk < 4; ++kk) {
            short8 af[4];
#pragma unroll
            for (int mi = 0; mi < 4; ++mi) af[mi] = loadA(bufChunk, mi, kk, l);
            short8 bw = loadB(p3wp, wid, kk, 4, l);
#pragma unroll
            for (int mi = 0; mi < 4; ++mi) acc[mi] = MFMA16(af[mi], bw, acc[mi]);
        }
        float* fb = (float*)bufWide;
        int col = wid*16 + (l & 15);
        float bias = p3b[col];
#pragma unroll
        for (int mi = 0; mi < 4; ++mi)
#pragma unroll
            for (int rr = 0; rr < 4; ++rr) {
                int row = mi*16 + ((l >> 4) << 2) + rr;
                fb[row*64 + col] = fmaxf(acc[mi][rr] + bias, 0.f);
            }
    }
    __syncthreads();

    // ---- ep4: dot-64 + sigmoid ----
    {
        const float* fb = (const float*)bufWide;
        float wv = p4w[l];
        float b4 = p4b[0];
        for (int er = 0; er < 16; ++er) {
            int e = wid*16 + er;
            float v = fb[e*64 + l] * wv;
#pragma unroll
            for (int o = 32; o > 0; o >>= 1) v += __shfl_down(v, o);
            if (l == 0) out[e0 + e] = fast_sigmoid(v + b4);
        }
    }
}

// ---------------------------------------------------------------------------
extern "C" void kernel_launch(void* const* d_in, const int* in_sizes, int n_in,
                              void* d_out, int out_size, void* d_ws, size_t ws_size,
                              hipStream_t stream)
{
    const float* x     = (const float*)d_in[0];
    const int*   ei    = (const int*)  d_in[1];
    const float* ea    = (const float*)d_in[2];
    const int*   batch = (const int*)  d_in[3];
    const float* ne1w = (const float*)d_in[4];  const float* ne1b = (const float*)d_in[5];
    const float* ne2w = (const float*)d_in[6];  const float* ne2b = (const float*)d_in[7];
    const float* ne3w = (const float*)d_in[8];  const float* ne3b = (const float*)d_in[9];
    const float* neg  = (const float*)d_in[10]; const float* nebb = (const float*)d_in[11];
    const float* ee1w = (const float*)d_in[12]; const float* ee1b = (const float*)d_in[13];
    const float* ee2w = (const float*)d_in[14]; const float* ee2b = (const float*)d_in[15];
    const float* ee3w = (const float*)d_in[16]; const float* ee3b = (const float*)d_in[17];
    const float* eeg  = (const float*)d_in[18]; const float* eebb = (const float*)d_in[19];
    const float* g1w  = (const float*)d_in[20]; const float* g1b  = (const float*)d_in[21];
    const float* g2w  = (const float*)d_in[22]; const float* g2b  = (const float*)d_in[23];
    const float* gp1w = (const float*)d_in[24]; const float* gp1b = (const float*)d_in[25];
    const float* gp2w = (const float*)d_in[26]; const float* gp2b = (const float*)d_in[27];
    const float* gpg  = (const float*)d_in[28]; const float* gpbb = (const float*)d_in[29];
    const float* p1w  = (const float*)d_in[30]; const float* p1b  = (const float*)d_in[31];
    const float* p2w  = (const float*)d_in[32]; const float* p2b  = (const float*)d_in[33];
    const float* p3w  = (const float*)d_in[34]; const float* p3b  = (const float*)d_in[35];
    const float* p4w  = (const float*)d_in[36]; const float* p4b  = (const float*)d_in[37];

    float* hbuf = (float*)d_ws;
    float* xw   = hbuf + (size_t)NN*HD;
    float* agg  = xw   + (size_t)NN*HD;
    float* deg  = agg  + (size_t)NN*HD;
    float* dinv = deg  + NN;
    float* sums = dinv + NN;
    float* cnts = sums + NG*HD;
    float* gfb  = cnts + NG;
    u16*  hbf   = (u16*)(gfb + NG*HD);
    u16*  gfb16 = hbf + (size_t)NN*HD;
    u16*  ew2p  = gfb16 + NG*HD;
    u16*  ew3p  = ew2p + 128*128;
    u16*  p1wp  = ew3p + 128*128;
    u16*  p2wp  = p1wp + 512*256;
    u16*  p3wp  = p2wp + 256*128;

    float* out = (float*)d_out;

    hipMemsetAsync(agg,  0, (size_t)NN*HD*sizeof(float), stream);
    hipMemsetAsync(deg,  0, (size_t)NN*sizeof(float), stream);
    hipMemsetAsync(sums, 0, (size_t)(NG*HD + NG)*sizeof(float), stream);

    // weight packing (runs every call; trivial cost)
    pack_w<<<(128*128 + 255)/256, 256, 0, stream>>>(ee2w, ew2p, 128, 128);
    pack_w<<<(128*128 + 255)/256, 256, 0, stream>>>(ee3w, ew3p, 128, 128);
    pack_w<<<(512*256 + 255)/256, 256, 0, stream>>>(p1w, p1wp, 512, 256);
    pack_w<<<(256*128 + 255)/256, 256, 0, stream>>>(p2w, p2wp, 256, 128);
    pack_w<<<(128*64  + 255)/256, 256, 0, stream>>>(p3w, p3wp, 128, 64);

    enc_node<<<NN, 128, 0, stream>>>(x, ne1w, ne1b, ne2w, ne2b, ne3w, ne3b,
                                     neg, nebb, hbuf);
    deg_count<<<(NE + 255)/256, 256, 0, stream>>>(ei, deg);
    dinv_k<<<(NN + 255)/256, 256, 0, stream>>>(deg, dinv);

    // GCN layer 1 (relu)
    gemm_nh<<<NN, 128, 0, stream>>>(hbuf, g1w, xw);
    gcn_scatter<<<(NE*HD)/256, 256, 0, stream>>>(xw, ei, dinv, agg);
    gcn_combine<<<(NN*HD)/256, 256, 0, stream>>>(agg, xw, dinv, g1b, hbuf,
                                                 (u16*)nullptr, 1);

    // GCN layer 2 (no relu), emit bf16 h
    hipMemsetAsync(agg, 0, (size_t)NN*HD*sizeof(float), stream);
    gemm_nh<<<NN, 128, 0, stream>>>(hbuf, g2w, xw);
    gcn_scatter<<<(NE*HD)/256, 256, 0, stream>>>(xw, ei, dinv, agg);
    gcn_combine<<<(NN*HD)/256, 256, 0, stream>>>(agg, xw, dinv, g2b, hbuf, hbf, 0);

    // global mean pool + graph MLP (emit bf16 gf)
    pool_kernel<<<(NN*HD)/256, 256, 0, stream>>>(hbuf, batch, sums, cnts);
    graph_feat<<<NG, 128, 0, stream>>>(sums, cnts, gp1w, gp1b, gp2w, gp2b,
                                       gpg, gpbb, gfb, gfb16);

    // fused edge encoder + edge-score MLP (MFMA bf16)
    edge_mlp_mfma<<<NE/64, 256, 0, stream>>>(hbf, gfb16, ei, batch, ea,
                                             ee1w, ee1b, ew2p, ee2b, ew3p, ee3b,
                                             eeg, eebb,
                                             p1wp, p1b, p2wp, p2b, p3wp, p3b,
                                             p4w, p4b, out);
}

// Round 3
// 1123.341 us; speedup vs baseline: 4.5718x; 1.5038x over previous
//
#include <hip/hip_runtime.h>
#include <math.h>

#define NN 50000
#define NE 400000
#define NG 64
#define HD 128
#define LN_EPS 1e-5f

typedef unsigned short u16;
typedef unsigned int u32;
typedef __attribute__((ext_vector_type(8))) short short8;
typedef __attribute__((ext_vector_type(4))) float f32x4;

#define MFMA16(a,b,c) __builtin_amdgcn_mfma_f32_16x16x32_bf16((a),(b),(c),0,0,0)

__device__ __forceinline__ u16 f2bf(float f) {
    union { float f; u32 u; } v; v.f = f;
    u32 r = v.u + 0x7FFFu + ((v.u >> 16) & 1u);
    return (u16)(r >> 16);
}
__device__ __forceinline__ float bf2f(u32 hs) {
    union { u32 u; float f; } v; v.u = hs << 16;
    return v.f;
}
__device__ __forceinline__ float fast_rcp(float x) {
    float r; asm("v_rcp_f32 %0, %1" : "=v"(r) : "v"(x)); return r;
}
__device__ __forceinline__ u32 cvtpk(float lo, float hi) {
    u32 r; asm("v_cvt_pk_bf16_f32 %0, %1, %2" : "=v"(r) : "v"(lo), "v"(hi)); return r;
}
__device__ __forceinline__ float fast_tanh(float x) {
    // tanh(x) = 1 - 2/(1+e^{2x}); saturates correctly at +-inf exp
    return fmaf(-2.f, fast_rcp(1.f + __expf(2.f * x)), 1.f);
}
__device__ __forceinline__ float fast_sigmoid(float x) {
    return fast_rcp(1.f + __expf(-x));
}

// A-fragment load from swizzled [64][128] bf16 chunk buffer.
__device__ __forceinline__ short8 loadA(const u16* buf, int mi, int kk, int l) {
    int row = mi*16 + (l & 15);
    int ci  = kk*4 + (l >> 4);
    return *(const short8*)(buf + row*128 + ((ci ^ (row & 7)) << 3));
}
__device__ __forceinline__ short8 loadB(const u16* wp, int nt, int ks, int nk, int l) {
    return *(const short8*)(wp + (((nt*nk + ks)*64 + l) << 3));
}

// Store 4 accumulator values (rows R..R+3, this lane's col c) into a swizzled
// bf16 chunk as packed u32 words via lane-pair exchange + v_cvt_pk_bf16_f32.
__device__ __forceinline__ void storeQuad(u32* buf, int R, int c, int l,
                                          float v0, float v1, float v2, float v3)
{
    int cw = c >> 1;
    int par = l & 1;
    float send = par ? v0 : v1;
    float recv = __shfl_xor(send, 1);
    int row = R + par;
    u32 word = par ? cvtpk(recv, v1) : cvtpk(v0, recv);
    buf[row*64 + (((cw >> 2) ^ (row & 7)) << 2) + (cw & 3)] = word;
    send = par ? v2 : v3;
    recv = __shfl_xor(send, 1);
    row = R + 2 + par;
    word = par ? cvtpk(recv, v3) : cvtpk(v2, recv);
    buf[row*64 + (((cw >> 2) ^ (row & 7)) << 2) + (cw & 3)] = word;
}

// ---------------------------------------------------------------------------
// Pack W[K,N] fp32 -> bf16 MFMA B-fragment order.
// ---------------------------------------------------------------------------
__global__ __launch_bounds__(256)
void pack_w(const float* __restrict__ w, u16* __restrict__ out, int K, int N)
{
    int idx = blockIdx.x*256 + threadIdx.x;
    if (idx >= K*N) return;
    int e = idx & 7, l = (idx >> 3) & 63, r = idx >> 9;
    int nk = K >> 5;
    int nt = r / nk, kk = r % nk;
    int k = kk*32 + ((l >> 4) << 3) + e;
    int n = nt*16 + (l & 15);
    out[idx] = f2bf(w[k*N + n]);
}

// ---------------------------------------------------------------------------
// CSR build: in-degree count, exclusive scan, fill (src-adjacency by dst)
// ---------------------------------------------------------------------------
__global__ __launch_bounds__(256)
void deg_count_int(const int* __restrict__ ei, int* __restrict__ degi)
{
    int e = blockIdx.x*256 + threadIdx.x;
    if (e < NE) atomicAdd(&degi[ei[NE + e]], 1);
}

__global__ __launch_bounds__(256)
void dinv_k(const int* __restrict__ degi, float* __restrict__ dinv)
{
    int n = blockIdx.x*256 + threadIdx.x;
    if (n < NN) dinv[n] = rsqrtf((float)degi[n] + 1.f);
}

__global__ __launch_bounds__(1024)
void scan_excl(const int* __restrict__ cnt, int* __restrict__ rp)
{
    __shared__ int wsum[16];
    __shared__ int carry;
    int t = threadIdx.x, lane = t & 63, w = t >> 6;
    int base = 0;
    for (int off = 0; off < NN; off += 1024) {
        int i = off + t;
        int v = (i < NN) ? cnt[i] : 0;
        int s = v;
#pragma unroll
        for (int d = 1; d < 64; d <<= 1) { int u = __shfl_up(s, d); if (lane >= d) s += u; }
        if (lane == 63) wsum[w] = s;
        __syncthreads();
        if (w == 0) {
            int wv = (lane < 16) ? wsum[lane] : 0;
            int ss = wv;
#pragma unroll
            for (int d = 1; d < 16; d <<= 1) { int u = __shfl_up(ss, d); if (lane >= d) ss += u; }
            if (lane < 16) wsum[lane] = ss - wv;      // exclusive wave offset
            if (lane == 15) carry = ss;
        }
        __syncthreads();
        if (i < NN) rp[i] = base + wsum[w] + s - v;   // exclusive
        base += carry;
        __syncthreads();
    }
    if (t == 0) rp[NN] = base;
}

__global__ __launch_bounds__(256)
void fill_csr(const int* __restrict__ ei, const int* __restrict__ rp,
              int* __restrict__ cursor, int* __restrict__ sadj)
{
    int e = blockIdx.x*256 + threadIdx.x;
    if (e >= NE) return;
    int d = ei[NE + e];
    int slot = atomicAdd(&cursor[d], 1);
    sadj[rp[d] + slot] = ei[e];
}

// ---------------------------------------------------------------------------
// Node encoder fused with GCN1 GEMM: out = (enc(x) @ g1w) * dinv[n]
// ---------------------------------------------------------------------------
__global__ __launch_bounds__(128)
void enc_node_fused(const float* __restrict__ x,
                    const float* __restrict__ w1, const float* __restrict__ b1,
                    const float* __restrict__ w2, const float* __restrict__ b2,
                    const float* __restrict__ w3, const float* __restrict__ b3,
                    const float* __restrict__ gg, const float* __restrict__ bb,
                    const float* __restrict__ g1w, const float* __restrict__ dinv,
                    float* __restrict__ outp)
{
    int node = blockIdx.x;
    int j = threadIdx.x;
    __shared__ float sin0[4];
    __shared__ float s1[HD];
    __shared__ float s2[HD];
    __shared__ float part[4];
    __shared__ float stat[2];
    if (j < 3) sin0[j] = x[node*3 + j];
    __syncthreads();
    float a = b1[j];
#pragma unroll
    for (int i = 0; i < 3; ++i) a = fmaf(sin0[i], w1[i*HD + j], a);
    s1[j] = fmaxf(a, 0.f);
    __syncthreads();
    a = b2[j];
    for (int i = 0; i < HD; ++i) a = fmaf(s1[i], w2[i*HD + j], a);
    s2[j] = fmaxf(a, 0.f);
    __syncthreads();
    a = b3[j];
    for (int i = 0; i < HD; ++i) a = fmaf(s2[i], w3[i*HD + j], a);
    float s = a, q = a*a;
    for (int o = 32; o > 0; o >>= 1) { s += __shfl_down(s, o); q += __shfl_down(q, o); }
    int wid = j >> 6, lane = j & 63;
    if (lane == 0) { part[wid] = s; part[2 + wid] = q; }
    __syncthreads();
    if (j == 0) {
        float S = part[0] + part[1], Q = part[2] + part[3];
        float mu = S * (1.f/HD);
        stat[0] = mu;
        stat[1] = Q * (1.f/HD) - mu*mu;
    }
    __syncthreads();
    float h = (a - stat[0]) * rsqrtf(stat[1] + LN_EPS) * gg[j] + bb[j];
    __syncthreads();
    s1[j] = h;
    __syncthreads();
    float o = 0.f;
    for (int i = 0; i < HD; ++i) o = fmaf(s1[i], g1w[i*HD + j], o);
    outp[node*HD + j] = o * dinv[node];
}

// ---------------------------------------------------------------------------
// GCN layer 1 gather + relu + fused GEMM with g2w, output pre-scaled by dinv:
//   h1 = relu(dinv*(self + sum msgs) + g1b);  out = (h1 @ g2w) * dinv
// ---------------------------------------------------------------------------
__global__ __launch_bounds__(128)
void gcn_agg1(const float* __restrict__ xwp, const int* __restrict__ rp,
              const int* __restrict__ sadj, const float* __restrict__ dinv,
              const float* __restrict__ bias, const float* __restrict__ w2,
              float* __restrict__ outp)
{
    int n = blockIdx.x, j = threadIdx.x;
    __shared__ float sh[HD];
    float di = dinv[n];
    float acc0 = xwp[n*HD + j], acc1 = 0.f;
    int k = rp[n], ke = rp[n+1];
    for (; k + 1 < ke; k += 2) {
        acc0 += xwp[sadj[k]*HD + j];
        acc1 += xwp[sadj[k+1]*HD + j];
    }
    if (k < ke) acc0 += xwp[sadj[k]*HD + j];
    float h1 = fmaxf((acc0 + acc1)*di + bias[j], 0.f);
    sh[j] = h1;
    __syncthreads();
    float o = 0.f;
    for (int i = 0; i < HD; ++i) o = fmaf(sh[i], w2[i*HD + j], o);
    outp[n*HD + j] = o * di;
}

// GCN layer 2 gather (no relu): h2 = dinv*(self + sum) + g2b; emit fp32 + bf16
__global__ __launch_bounds__(128)
void gcn_agg2(const float* __restrict__ xwp, const int* __restrict__ rp,
              const int* __restrict__ sadj, const float* __restrict__ dinv,
              const float* __restrict__ bias, float* __restrict__ h2,
              u16* __restrict__ hb)
{
    int n = blockIdx.x, j = threadIdx.x;
    float di = dinv[n];
    float acc0 = xwp[n*HD + j], acc1 = 0.f;
    int k = rp[n], ke = rp[n+1];
    for (; k + 1 < ke; k += 2) {
        acc0 += xwp[sadj[k]*HD + j];
        acc1 += xwp[sadj[k+1]*HD + j];
    }
    if (k < ke) acc0 += xwp[sadj[k]*HD + j];
    float v = (acc0 + acc1)*di + bias[j];
    h2[n*HD + j] = v;
    hb[n*HD + j] = f2bf(v);
}

// ---------------------------------------------------------------------------
// Pool: batch is sorted -> run-accumulate per strip, few atomics
// ---------------------------------------------------------------------------
#define POOL_B 512
__global__ __launch_bounds__(128)
void pool_sorted(const float* __restrict__ h, const int* __restrict__ batch,
                 float* __restrict__ sums)
{
    int b = blockIdx.x, j = threadIdx.x;
    int n0 = (int)(((long long)NN * b) / POOL_B);
    int n1 = (int)(((long long)NN * (b+1)) / POOL_B);
    int g = -1; float acc = 0.f;
    for (int n = n0; n < n1; ++n) {
        int bg = batch[n];
        if (bg != g) {
            if (g >= 0) atomicAdd(&sums[g*HD + j], acc);
            g = bg; acc = 0.f;
        }
        acc += h[n*HD + j];
    }
    if (g >= 0) atomicAdd(&sums[g*HD + j], acc);
}

__global__ __launch_bounds__(256)
void cnt_k(const int* __restrict__ batch, float* __restrict__ cnts)
{
    int n = blockIdx.x*256 + threadIdx.x;
    if (n < NN) atomicAdd(&cnts[batch[n]], 1.f);
}

__global__ __launch_bounds__(128)
void graph_feat(const float* __restrict__ sums, const float* __restrict__ cnts,
                const float* __restrict__ w1, const float* __restrict__ b1,
                const float* __restrict__ w2, const float* __restrict__ b2,
                const float* __restrict__ gg, const float* __restrict__ bb,
                u16* __restrict__ gf16)
{
    int gi = blockIdx.x, j = threadIdx.x;
    __shared__ float s0[HD];
    __shared__ float s1[HD];
    __shared__ float part[4];
    __shared__ float stat[2];
    float cnt = fmaxf(cnts[gi], 1.f);
    s0[j] = sums[gi*HD + j] / cnt;
    __syncthreads();
    float a = b1[j];
    for (int i = 0; i < HD; ++i) a = fmaf(s0[i], w1[i*HD + j], a);
    s1[j] = fmaxf(a, 0.f);
    __syncthreads();
    a = b2[j];
    for (int i = 0; i < HD; ++i) a = fmaf(s1[i], w2[i*HD + j], a);
    float s = a, q = a*a;
    for (int o = 32; o > 0; o >>= 1) { s += __shfl_down(s, o); q += __shfl_down(q, o); }
    int wid = j >> 6, lane = j & 63;
    if (lane == 0) { part[wid] = s; part[2 + wid] = q; }
    __syncthreads();
    if (j == 0) {
        float S = part[0] + part[1], Q = part[2] + part[3];
        float mu = S * (1.f/HD);
        stat[0] = mu;
        stat[1] = Q * (1.f/HD) - mu*mu;
    }
    __syncthreads();
    float v = (a - stat[0]) * rsqrtf(stat[1] + LN_EPS) * gg[j] + bb[j];
    gf16[gi*HD + j] = f2bf(v);
}

// ---------------------------------------------------------------------------
// Stage 64 gathered bf16 rows into swizzled LDS chunk (4 threads/row)
// ---------------------------------------------------------------------------
__device__ __forceinline__ void stageRows(u16* dst, const u16* __restrict__ srcBase,
                                          const int* ridx, int t)
{
    int e = t >> 2, part = t & 3;
    const u16* src = srcBase + (size_t)ridx[e]*HD + part*32;
    u16* drow = dst + e*128;
    int re = e & 7;
#pragma unroll
    for (int w = 0; w < 4; ++w) {
        int ci = part*4 + w;
        *(short8*)(drow + ((ci ^ re) << 3)) = *(const short8*)(src + w*8);
    }
}

// ---------------------------------------------------------------------------
// Fused edge kernel (MFMA bf16). 64 edges/block, 256 threads (4 waves).
// ---------------------------------------------------------------------------
__global__ __launch_bounds__(256, 2)
void edge_mlp_mfma(const u16* __restrict__ hbf, const u16* __restrict__ gfbf,
                   const int* __restrict__ ei, const int* __restrict__ batch,
                   const float* __restrict__ ea,
                   const float* __restrict__ ew1, const float* __restrict__ eb1,
                   const u16* __restrict__ ew2p, const float* __restrict__ eb2,
                   const u16* __restrict__ ew3p, const float* __restrict__ eb3,
                   const float* __restrict__ egm, const float* __restrict__ ebb,
                   const u16* __restrict__ p1wp, const float* __restrict__ p1b,
                   const u16* __restrict__ p2wp, const float* __restrict__ p2b,
                   const u16* __restrict__ p3wp, const float* __restrict__ p3b,
                   const float* __restrict__ p4w, const float* __restrict__ p4b,
                   float* __restrict__ out)
{
    __shared__ u16 bufChunk[64*128];   // 16KB swizzled A-chunk
    __shared__ u16 bufWide[64*256];    // 32KB (2 chunks / fp32 scratch)
    __shared__ float sEa[192];
    __shared__ int sSrc[64], sDst[64], sGf[64];
    __shared__ float rstat[128];

    const int t = threadIdx.x;
    const int l = t & 63;
    const int wid = t >> 6;
    const int e0 = blockIdx.x * 64;

    if (t < 64) {
        int s = ei[e0 + t];
        sSrc[t] = s;
        sDst[t] = ei[NE + e0 + t];
        sGf[t]  = batch[s];
    }
    if (t < 192) sEa[t] = ea[e0*3 + t];
    __syncthreads();

    // ---- enc1: relu(ea@ew1+b1) -> bufChunk (bf16, swizzled) ----
    for (int it = 0; it < 16; ++it) {
        int dw = it*256 + t;
        int e = dw >> 6, cd = dw & 63;
        int c0 = cd*2;
        float x0 = sEa[e*3], x1 = sEa[e*3+1], x2 = sEa[e*3+2];
        float v0 = eb1[c0]   + x0*ew1[c0]   + x1*ew1[HD+c0]   + x2*ew1[2*HD+c0];
        float v1 = eb1[c0+1] + x0*ew1[c0+1] + x1*ew1[HD+c0+1] + x2*ew1[2*HD+c0+1];
        v0 = fmaxf(v0, 0.f); v1 = fmaxf(v1, 0.f);
        int ci = cd >> 2;
        ((u32*)bufChunk)[e*64 + ((ci ^ (e & 7)) << 2) + (cd & 3)] = cvtpk(v0, v1);
    }
    __syncthreads();

    // ---- enc2: relu(enc1@ew2+b2) -> bufWide chunk0 ----
    {
        f32x4 acc[4][2];
#pragma unroll
        for (int mi = 0; mi < 4; ++mi)
#pragma unroll
            for (int ni = 0; ni < 2; ++ni) acc[mi][ni] = (f32x4){0.f,0.f,0.f,0.f};
#pragma unroll
        for (int kk = 0; kk < 4; ++kk) {
            short8 af[4];
#pragma unroll
            for (int mi = 0; mi < 4; ++mi) af[mi] = loadA(bufChunk, mi, kk, l);
#pragma unroll
            for (int ni = 0; ni < 2; ++ni) {
                short8 bw = loadB(ew2p, 2*wid + ni, kk, 4, l);
#pragma unroll
                for (int mi = 0; mi < 4; ++mi) acc[mi][ni] = MFMA16(af[mi], bw, acc[mi][ni]);
            }
        }
#pragma unroll
        for (int ni = 0; ni < 2; ++ni) {
            int col = (2*wid + ni)*16 + (l & 15);
            float bias = eb2[col];
#pragma unroll
            for (int mi = 0; mi < 4; ++mi) {
                int R = mi*16 + ((l >> 4) << 2);
                storeQuad((u32*)bufWide, R, col, l,
                          fmaxf(acc[mi][ni][0] + bias, 0.f),
                          fmaxf(acc[mi][ni][1] + bias, 0.f),
                          fmaxf(acc[mi][ni][2] + bias, 0.f),
                          fmaxf(acc[mi][ni][3] + bias, 0.f));
            }
        }
    }
    __syncthreads();

    // ---- enc3: enc2@ew3+b3 (pre-LN) -> bufChunk ----
    {
        f32x4 acc[4][2];
#pragma unroll
        for (int mi = 0; mi < 4; ++mi)
#pragma unroll
            for (int ni = 0; ni < 2; ++ni) acc[mi][ni] = (f32x4){0.f,0.f,0.f,0.f};
#pragma unroll
        for (int kk = 0; kk < 4; ++kk) {
            short8 af[4];
#pragma unroll
            for (int mi = 0; mi < 4; ++mi) af[mi] = loadA(bufWide, mi, kk, l);
#pragma unroll
            for (int ni = 0; ni < 2; ++ni) {
                short8 bw = loadB(ew3p, 2*wid + ni, kk, 4, l);
#pragma unroll
                for (int mi = 0; mi < 4; ++mi) acc[mi][ni] = MFMA16(af[mi], bw, acc[mi][ni]);
            }
        }
#pragma unroll
        for (int ni = 0; ni < 2; ++ni) {
            int col = (2*wid + ni)*16 + (l & 15);
            float bias = eb3[col];
#pragma unroll
            for (int mi = 0; mi < 4; ++mi) {
                int R = mi*16 + ((l >> 4) << 2);
                storeQuad((u32*)bufChunk, R, col, l,
                          acc[mi][ni][0] + bias, acc[mi][ni][1] + bias,
                          acc[mi][ni][2] + bias, acc[mi][ni][3] + bias);
            }
        }
    }
    __syncthreads();

    // ---- LN stats: 4 lanes per edge, single pass ----
    {
        int e = wid*16 + (l >> 2);
        int q = l & 3;
        const u32* rowp = (const u32*)bufChunk + e*64;
        float s = 0.f, sq = 0.f;
#pragma unroll
        for (int i = 0; i < 16; ++i) {
            int idx = q*16 + ((i + e) & 15);     // rotation: bank-spread
            u32 pk = rowp[idx];
            float a = bf2f(pk & 0xffffu), b = bf2f(pk >> 16);
            s += a + b;
            sq = fmaf(a, a, fmaf(b, b, sq));
        }
        s  += __shfl_xor(s, 1);  sq += __shfl_xor(sq, 1);
        s  += __shfl_xor(s, 2);  sq += __shfl_xor(sq, 2);
        if (q == 0) {
            float mu = s * (1.f/HD);
            rstat[e] = mu;
            rstat[64 + e] = rsqrtf(sq*(1.f/HD) - mu*mu + LN_EPS);
        }
    }
    __syncthreads();

    // ---- normalize in place: bufChunk = ef ----
    for (int it = 0; it < 16; ++it) {
        int pd = it*256 + t;
        int row = pd >> 6, cwd = pd & 63;
        int ci = (cwd >> 2) ^ (row & 7);
        int col = ci*8 + (cwd & 3)*2;
        u32 pk = ((u32*)bufChunk)[pd];
        float mu = rstat[row], ri = rstat[64 + row];
        float v0 = (bf2f(pk & 0xffffu) - mu)*ri*egm[col]     + ebb[col];
        float v1 = (bf2f(pk >> 16)     - mu)*ri*egm[col + 1] + ebb[col + 1];
        ((u32*)bufChunk)[pd] = cvtpk(v0, v1);
    }
    __syncthreads();

    // ---- ep1: comb[64,512] @ p1w[512,256] + b, tanh -> bufWide ----
    f32x4 acc1[4][4];
#pragma unroll
    for (int mi = 0; mi < 4; ++mi)
#pragma unroll
        for (int ni = 0; ni < 4; ++ni) acc1[mi][ni] = (f32x4){0.f,0.f,0.f,0.f};

    for (int ii = 0; ii < 4; ++ii) {
        int c = (ii == 0) ? 3 : (ii - 1);      // order: ef, h[src], h[dst], gf
        if (ii > 0) {
            __syncthreads();
            const u16* sb = (c == 2) ? gfbf : hbf;
            const int* ridx = (c == 0) ? sSrc : ((c == 1) ? sDst : sGf);
            stageRows(bufChunk, sb, ridx, t);
            __syncthreads();
        }
#pragma unroll
        for (int kk = 0; kk < 4; ++kk) {
            short8 af[4];
#pragma unroll
            for (int mi = 0; mi < 4; ++mi) af[mi] = loadA(bufChunk, mi, kk, l);
            int ks = c*4 + kk;
#pragma unroll
            for (int ni = 0; ni < 4; ++ni) {
                short8 bw = loadB(p1wp, 4*wid + ni, ks, 16, l);
#pragma unroll
                for (int mi = 0; mi < 4; ++mi) acc1[mi][ni] = MFMA16(af[mi], bw, acc1[mi][ni]);
            }
        }
    }
#pragma unroll
    for (int ni = 0; ni < 4; ++ni) {
        int col = (4*wid + ni)*16 + (l & 15);
        float bias = p1b[col];
        u32* dst = (u32*)bufWide + ((col >> 7) << 12);
        int cc = col & 127;
#pragma unroll
        for (int mi = 0; mi < 4; ++mi) {
            int R = mi*16 + ((l >> 4) << 2);
            storeQuad(dst, R, cc, l,
                      fast_tanh(acc1[mi][ni][0] + bias),
                      fast_tanh(acc1[mi][ni][1] + bias),
                      fast_tanh(acc1[mi][ni][2] + bias),
                      fast_tanh(acc1[mi][ni][3] + bias));
        }
    }
    __syncthreads();

    // ---- ep2: [64,256] @ p2w[256,128] + b, tanh -> bufChunk ----
    {
        f32x4 acc[4][2];
#pragma unroll
        for (int mi = 0; mi < 4; ++mi)
#pragma unroll
            for (int ni = 0; ni < 2; ++ni) acc[mi][ni] = (f32x4){0.f,0.f,0.f,0.f};
        for (int kc = 0; kc < 2; ++kc) {
            const u16* abuf = bufWide + (kc << 13);
#pragma unroll
            for (int kk = 0; kk < 4; ++kk) {
                short8 af[4];
#pragma unroll
                for (int mi = 0; mi < 4; ++mi) af[mi] = loadA(abuf, mi, kk, l);
                int ks = kc*4 + kk;
#pragma unroll
                for (int ni = 0; ni < 2; ++ni) {
                    short8 bw = loadB(p2wp, 2*wid + ni, ks, 8, l);
#pragma unroll
                    for (int mi = 0; mi < 4; ++mi) acc[mi][ni] = MFMA16(af[mi], bw, acc[mi][ni]);
                }
            }
        }
#pragma unroll
        for (int ni = 0; ni < 2; ++ni) {
            int col = (2*wid + ni)*16 + (l & 15);
            float bias = p2b[col];
#pragma unroll
            for (int mi = 0; mi < 4; ++mi) {
                int R = mi*16 + ((l >> 4) << 2);
                storeQuad((u32*)bufChunk, R, col, l,
                          fast_tanh(acc[mi][ni][0] + bias),
                          fast_tanh(acc[mi][ni][1] + bias),
                          fast_tanh(acc[mi][ni][2] + bias),
                          fast_tanh(acc[mi][ni][3] + bias));
            }
        }
    }
    __syncthreads();

    // ---- ep3: [64,128] @ p3w[128,64] + b, relu -> bufWide as fp32 ----
    {
        f32x4 acc[4];
#pragma unroll
        for (int mi = 0; mi < 4; ++mi) acc[mi] = (f32x4){0.f,0.f,0.f,0.f};
#pragma unroll
        for (int kk = 0; kk < 4; ++kk) {
            short8 af[4];
#pragma unroll
            for (int mi = 0; mi < 4; ++mi) af[mi] = loadA(bufChunk, mi, kk, l);
            short8 bw = loadB(p3wp, wid, kk, 4, l);
#pragma unroll
            for (int mi = 0; mi < 4; ++mi) acc[mi] = MFMA16(af[mi], bw, acc[mi]);
        }
        float* fb = (float*)bufWide;
        int col = wid*16 + (l & 15);
        float bias = p3b[col];
#pragma unroll
        for (int mi = 0; mi < 4; ++mi)
#pragma unroll
            for (int rr = 0; rr < 4; ++rr) {
                int row = mi*16 + ((l >> 4) << 2) + rr;
                fb[row*64 + col] = fmaxf(acc[mi][rr] + bias, 0.f);
            }
    }
    __syncthreads();

    // ---- ep4: 4 lanes per edge dot-64 + sigmoid ----
    {
        const float* fb = (const float*)bufWide;
        int e = wid*16 + (l >> 2), q = l & 3;
        float v = 0.f;
#pragma unroll
        for (int k = 0; k < 16; ++k) {
            int i = q*16 + ((k + e) & 15);      // rotation: bank-spread
            v = fmaf(fb[e*64 + i], p4w[i], v);
        }
        v += __shfl_xor(v, 1);
        v += __shfl_xor(v, 2);
        if (q == 0) out[e0 + e] = fast_sigmoid(v + p4b[0]);
    }
}

// ---------------------------------------------------------------------------
extern "C" void kernel_launch(void* const* d_in, const int* in_sizes, int n_in,
                              void* d_out, int out_size, void* d_ws, size_t ws_size,
                              hipStream_t stream)
{
    const float* x     = (const float*)d_in[0];
    const int*   ei    = (const int*)  d_in[1];
    const float* ea    = (const float*)d_in[2];
    const int*   batch = (const int*)  d_in[3];
    const float* ne1w = (const float*)d_in[4];  const float* ne1b = (const float*)d_in[5];
    const float* ne2w = (const float*)d_in[6];  const float* ne2b = (const float*)d_in[7];
    const float* ne3w = (const float*)d_in[8];  const float* ne3b = (const float*)d_in[9];
    const float* neg  = (const float*)d_in[10]; const float* nebb = (const float*)d_in[11];
    const float* ee1w = (const float*)d_in[12]; const float* ee1b = (const float*)d_in[13];
    const float* ee2w = (const float*)d_in[14]; const float* ee2b = (const float*)d_in[15];
    const float* ee3w = (const float*)d_in[16]; const float* ee3b = (const float*)d_in[17];
    const float* eeg  = (const float*)d_in[18]; const float* eebb = (const float*)d_in[19];
    const float* g1w  = (const float*)d_in[20]; const float* g1b  = (const float*)d_in[21];
    const float* g2w  = (const float*)d_in[22]; const float* g2b  = (const float*)d_in[23];
    const float* gp1w = (const float*)d_in[24]; const float* gp1b = (const float*)d_in[25];
    const float* gp2w = (const float*)d_in[26]; const float* gp2b = (const float*)d_in[27];
    const float* gpg  = (const float*)d_in[28]; const float* gpbb = (const float*)d_in[29];
    const float* p1w  = (const float*)d_in[30]; const float* p1b  = (const float*)d_in[31];
    const float* p2w  = (const float*)d_in[32]; const float* p2b  = (const float*)d_in[33];
    const float* p3w  = (const float*)d_in[34]; const float* p3b  = (const float*)d_in[35];
    const float* p4w  = (const float*)d_in[36]; const float* p4b  = (const float*)d_in[37];

    float* A    = (float*)d_ws;            // xw1p, later h2 (N*H)
    float* B    = A + (size_t)NN*HD;       // xw2p (N*H)
    float* dinv = B + (size_t)NN*HD;       // N
    float* sums = dinv + NN;               // G*H
    float* cnts = sums + NG*HD;            // G
    int* degi   = (int*)(cnts + NG);       // N
    int* rowptr = degi + NN;               // N+2 (pad)
    int* cursor = rowptr + NN + 2;         // N+2 (pad)
    int* sadj   = cursor + NN + 2;         // E  (totals ints: 4*NN? keep even)
    u16* hbf    = (u16*)(sadj + NE);
    u16* gf16   = hbf + (size_t)NN*HD;
    u16* ew2p   = gf16 + NG*HD;
    u16* ew3p   = ew2p + 128*128;
    u16* p1wp   = ew3p + 128*128;
    u16* p2wp   = p1wp + 512*256;
    u16* p3wp   = p2wp + 256*128;

    float* out = (float*)d_out;

    hipMemsetAsync(degi, 0, (size_t)(3*NN + 4)*sizeof(int), stream);  // degi+rowptr+cursor
    hipMemsetAsync(sums, 0, (size_t)(NG*HD + NG)*sizeof(float), stream);

    // weight packing
    pack_w<<<(128*128 + 255)/256, 256, 0, stream>>>(ee2w, ew2p, 128, 128);
    pack_w<<<(128*128 + 255)/256, 256, 0, stream>>>(ee3w, ew3p, 128, 128);
    pack_w<<<(512*256 + 255)/256, 256, 0, stream>>>(p1w, p1wp, 512, 256);
    pack_w<<<(256*128 + 255)/256, 256, 0, stream>>>(p2w, p2wp, 256, 128);
    pack_w<<<(128*64  + 255)/256, 256, 0, stream>>>(p3w, p3wp, 128, 64);

    // CSR build
    deg_count_int<<<(NE + 255)/256, 256, 0, stream>>>(ei, degi);
    dinv_k<<<(NN + 255)/256, 256, 0, stream>>>(degi, dinv);
    scan_excl<<<1, 1024, 0, stream>>>(degi, rowptr);
    fill_csr<<<(NE + 255)/256, 256, 0, stream>>>(ei, rowptr, cursor, sadj);

    // node encoder + GCN1 GEMM, pre-scaled
    enc_node_fused<<<NN, 128, 0, stream>>>(x, ne1w, ne1b, ne2w, ne2b, ne3w, ne3b,
                                           neg, nebb, g1w, dinv, A);
    // GCN layer 1 gather + relu + GEMM g2w
    gcn_agg1<<<NN, 128, 0, stream>>>(A, rowptr, sadj, dinv, g1b, g2w, B);
    // GCN layer 2 gather, emit fp32 + bf16
    gcn_agg2<<<NN, 128, 0, stream>>>(B, rowptr, sadj, dinv, g2b, A, hbf);

    // pool + graph MLP
    pool_sorted<<<POOL_B, 128, 0, stream>>>(A, batch, sums);
    cnt_k<<<(NN + 255)/256, 256, 0, stream>>>(batch, cnts);
    graph_feat<<<NG, 128, 0, stream>>>(sums, cnts, gp1w, gp1b, gp2w, gp2b,
                                       gpg, gpbb, gf16);

    // fused edge encoder + edge-score MLP (MFMA bf16)
    edge_mlp_mfma<<<NE/64, 256, 0, stream>>>(hbf, gf16, ei, batch, ea,
                                             ee1w, ee1b, ew2p, ee2b, ew3p, ee3b,
                                             eeg, eebb,
                                             p1wp, p1b, p2wp, p2b, p3wp, p3b,
                                             p4w, p4b, out);
}

// Round 4
// 858.314 us; speedup vs baseline: 5.9834x; 1.3088x over previous
//
#include <hip/hip_runtime.h>
#include <math.h>

#define NN 50000
#define NE 400000
#define NG 64
#define HD 128
#define LN_EPS 1e-5f

typedef unsigned short u16;
typedef unsigned int u32;
typedef __attribute__((ext_vector_type(8))) short short8;
typedef __attribute__((ext_vector_type(4))) float f32x4;

#define MFMA16(a,b,c) __builtin_amdgcn_mfma_f32_16x16x32_bf16((a),(b),(c),0,0,0)

__device__ __forceinline__ u16 f2bf(float f) {
    union { float f; u32 u; } v; v.f = f;
    u32 r = v.u + 0x7FFFu + ((v.u >> 16) & 1u);
    return (u16)(r >> 16);
}
__device__ __forceinline__ float bf2f(u32 hs) {
    union { u32 u; float f; } v; v.u = hs << 16;
    return v.f;
}
__device__ __forceinline__ float fast_rcp(float x) {
    float r; asm("v_rcp_f32 %0, %1" : "=v"(r) : "v"(x)); return r;
}
__device__ __forceinline__ u32 cvtpk(float lo, float hi) {
    u32 r; asm("v_cvt_pk_bf16_f32 %0, %1, %2" : "=v"(r) : "v"(lo), "v"(hi)); return r;
}
__device__ __forceinline__ float fast_tanh(float x) {
    return fmaf(-2.f, fast_rcp(1.f + __expf(2.f * x)), 1.f);
}
__device__ __forceinline__ float fast_sigmoid(float x) {
    return fast_rcp(1.f + __expf(-x));
}

// A-fragment load from swizzled [64][128] bf16 chunk buffer.
__device__ __forceinline__ short8 loadA(const u16* buf, int mi, int kk, int l) {
    int row = mi*16 + (l & 15);
    int ci  = (kk*4 + (l >> 4)) ^ (l & 7);     // row&7 == l&7 (mi*16 multiple of 8)
    return *(const short8*)(buf + row*128 + (ci << 3));
}
__device__ __forceinline__ short8 loadB(const u16* wp, int nt, int ks, int nk, int l) {
    return *(const short8*)(wp + (((nt*nk + ks)*64 + l) << 3));
}

// Store 4 accumulator values (rows R..R+3, col c) into swizzled bf16 chunk as
// packed u32 via lane-pair exchange + v_cvt_pk_bf16_f32.
__device__ __forceinline__ void storeQuad(u32* buf, int R, int c, int l,
                                          float v0, float v1, float v2, float v3)
{
    int cw = c >> 1;
    int par = l & 1;
    float send = par ? v0 : v1;
    float recv = __shfl_xor(send, 1);
    int row = R + par;
    u32 word = par ? cvtpk(recv, v1) : cvtpk(v0, recv);
    buf[row*64 + (((cw >> 2) ^ (row & 7)) << 2) + (cw & 3)] = word;
    send = par ? v2 : v3;
    recv = __shfl_xor(send, 1);
    row = R + 2 + par;
    word = par ? cvtpk(recv, v3) : cvtpk(v2, recv);
    buf[row*64 + (((cw >> 2) ^ (row & 7)) << 2) + (cw & 3)] = word;
}

// Unswizzle copy: LDS chunk -> global bf16 [64][128] rows n0..n0+63 (u32 words)
__device__ __forceinline__ void copyChunkOut(const u32* chunk, u32* gout, int n0, int t)
{
    for (int it = 0; it < 16; ++it) {
        int dw = it*256 + t;
        int row = dw >> 6, cw = dw & 63;
        if (n0 + row < NN)
            gout[(size_t)(n0 + row)*64 + cw] =
                chunk[row*64 + ((((cw >> 2) ^ (row & 7)) << 2)) + (cw & 3)];
    }
}

// ---------------------------------------------------------------------------
// One-shot weight packing of all 9 GEMM weights -> bf16 MFMA B-fragment order.
// Segment offsets must match kernel_launch's wpk layout.
// ---------------------------------------------------------------------------
__global__ __launch_bounds__(256)
void pack_all(const float* __restrict__ ee2w, const float* __restrict__ ee3w,
              const float* __restrict__ p1w,  const float* __restrict__ p2w,
              const float* __restrict__ p3w,  const float* __restrict__ ne2w,
              const float* __restrict__ ne3w, const float* __restrict__ g1w,
              const float* __restrict__ g2w,  u16* __restrict__ wpk)
{
    int idx = blockIdx.x*256 + threadIdx.x;
    if (idx >= 270336) return;
    const float* w; int K, N, local;
    if      (idx < 16384)  { w = ee2w; K = 128; N = 128; local = idx; }
    else if (idx < 32768)  { w = ee3w; K = 128; N = 128; local = idx - 16384; }
    else if (idx < 163840) { w = p1w;  K = 512; N = 256; local = idx - 32768; }
    else if (idx < 196608) { w = p2w;  K = 256; N = 128; local = idx - 163840; }
    else if (idx < 204800) { w = p3w;  K = 128; N = 64;  local = idx - 196608; }
    else if (idx < 221184) { w = ne2w; K = 128; N = 128; local = idx - 204800; }
    else if (idx < 237568) { w = ne3w; K = 128; N = 128; local = idx - 221184; }
    else if (idx < 253952) { w = g1w;  K = 128; N = 128; local = idx - 237568; }
    else                   { w = g2w;  K = 128; N = 128; local = idx - 253952; }
    int e = local & 7, l = (local >> 3) & 63, r = local >> 9;
    int nk = K >> 5;
    int nt = r / nk, kk = r % nk;
    int k = kk*32 + ((l >> 4) << 3) + e;
    int n = nt*16 + (l & 15);
    wpk[idx] = f2bf(w[k*N + n]);
}

// ---------------------------------------------------------------------------
// CSR build
// ---------------------------------------------------------------------------
__global__ __launch_bounds__(256)
void deg_count_int(const int* __restrict__ ei, int* __restrict__ degi)
{
    int e = blockIdx.x*256 + threadIdx.x;
    if (e < NE) atomicAdd(&degi[ei[NE + e]], 1);
}

__global__ __launch_bounds__(256)
void dinv_k(const int* __restrict__ degi, float* __restrict__ dinv)
{
    int n = blockIdx.x*256 + threadIdx.x;
    if (n < NN) dinv[n] = rsqrtf((float)degi[n] + 1.f);
}

__global__ __launch_bounds__(1024)
void scan_excl(const int* __restrict__ cnt, int* __restrict__ rp)
{
    __shared__ int wsum[16];
    __shared__ int carry;
    int t = threadIdx.x, lane = t & 63, w = t >> 6;
    int base = 0;
    for (int off = 0; off < NN; off += 4096) {
        int i0 = off + t*4;
        int v0 = (i0   < NN) ? cnt[i0]   : 0;
        int v1 = (i0+1 < NN) ? cnt[i0+1] : 0;
        int v2 = (i0+2 < NN) ? cnt[i0+2] : 0;
        int v3 = (i0+3 < NN) ? cnt[i0+3] : 0;
        int tot = v0 + v1 + v2 + v3;
        int s = tot;
#pragma unroll
        for (int d = 1; d < 64; d <<= 1) { int u = __shfl_up(s, d); if (lane >= d) s += u; }
        if (lane == 63) wsum[w] = s;
        __syncthreads();
        if (w == 0) {
            int wv = (lane < 16) ? wsum[lane] : 0;
            int ss = wv;
#pragma unroll
            for (int d = 1; d < 16; d <<= 1) { int u = __shfl_up(ss, d); if (lane >= d) ss += u; }
            if (lane < 16) wsum[lane] = ss - wv;
            if (lane == 15) carry = ss;
        }
        __syncthreads();
        int excl = base + wsum[w] + s - tot;
        if (i0   < NN) rp[i0]   = excl;
        if (i0+1 < NN) rp[i0+1] = excl + v0;
        if (i0+2 < NN) rp[i0+2] = excl + v0 + v1;
        if (i0+3 < NN) rp[i0+3] = excl + v0 + v1 + v2;
        base += carry;
        __syncthreads();
    }
    if (t == 0) rp[NN] = base;
}

__global__ __launch_bounds__(256)
void fill_csr(const int* __restrict__ ei, const int* __restrict__ rp,
              int* __restrict__ cursor, int* __restrict__ sadj)
{
    int e = blockIdx.x*256 + threadIdx.x;
    if (e >= NE) return;
    int d = ei[NE + e];
    int slot = atomicAdd(&cursor[d], 1);
    sadj[rp[d] + slot] = ei[e];
}

// ---------------------------------------------------------------------------
// Node encoder + g1w GEMM, MFMA. 64 nodes/block, 256 threads.
// out: xw1p = (LN(enc(x)) @ g1w) * dinv   [bf16]
// ---------------------------------------------------------------------------
__global__ __launch_bounds__(256, 4)
void enc_mfma(const float* __restrict__ x,
              const float* __restrict__ w1, const float* __restrict__ b1,
              const u16* __restrict__ w2p, const float* __restrict__ b2,
              const u16* __restrict__ w3p, const float* __restrict__ b3,
              const float* __restrict__ gg, const float* __restrict__ bb,
              const u16* __restrict__ g1p, const float* __restrict__ dinv,
              u32* __restrict__ xw1p)
{
    __shared__ u16 chunkA[64*HD];   // 16KB
    __shared__ u16 chunkB[64*HD];   // 16KB
    __shared__ float sX[192];
    __shared__ float sDi[64];
    __shared__ float rstat[128];

    const int t = threadIdx.x;
    const int l = t & 63;
    const int wid = t >> 6;
    const int n0 = blockIdx.x * 64;

    if (t < 192) sX[t] = (n0*3 + t < NN*3) ? x[n0*3 + t] : 0.f;
    if (t < 64)  sDi[t] = (n0 + t < NN) ? dinv[n0 + t] : 0.f;
    __syncthreads();

    // L1: 3->128 relu (VALU) -> chunkA
    for (int it = 0; it < 16; ++it) {
        int dw = it*256 + t;
        int e = dw >> 6, cd = dw & 63;
        int c0 = cd*2;
        float x0 = sX[e*3], x1 = sX[e*3+1], x2 = sX[e*3+2];
        float v0 = b1[c0]   + x0*w1[c0]   + x1*w1[HD+c0]   + x2*w1[2*HD+c0];
        float v1 = b1[c0+1] + x0*w1[c0+1] + x1*w1[HD+c0+1] + x2*w1[2*HD+c0+1];
        v0 = fmaxf(v0, 0.f); v1 = fmaxf(v1, 0.f);
        int ci = cd >> 2;
        ((u32*)chunkA)[e*64 + ((ci ^ (e & 7)) << 2) + (cd & 3)] = cvtpk(v0, v1);
    }
    __syncthreads();

    // L2 MFMA: relu(A@w2+b2) -> chunkB
    {
        f32x4 acc[4][2];
#pragma unroll
        for (int ni = 0; ni < 2; ++ni) {
            float b = b2[(2*wid + ni)*16 + (l & 15)];
#pragma unroll
            for (int mi = 0; mi < 4; ++mi) acc[mi][ni] = (f32x4){b,b,b,b};
        }
#pragma unroll
        for (int kk = 0; kk < 4; ++kk) {
            short8 af[4];
#pragma unroll
            for (int mi = 0; mi < 4; ++mi) af[mi] = loadA(chunkA, mi, kk, l);
#pragma unroll
            for (int ni = 0; ni < 2; ++ni) {
                short8 bw = loadB(w2p, 2*wid + ni, kk, 4, l);
#pragma unroll
                for (int mi = 0; mi < 4; ++mi) acc[mi][ni] = MFMA16(af[mi], bw, acc[mi][ni]);
            }
        }
#pragma unroll
        for (int ni = 0; ni < 2; ++ni) {
            int col = (2*wid + ni)*16 + (l & 15);
#pragma unroll
            for (int mi = 0; mi < 4; ++mi) {
                int R = mi*16 + ((l >> 4) << 2);
                storeQuad((u32*)chunkB, R, col, l,
                          fmaxf(acc[mi][ni][0], 0.f), fmaxf(acc[mi][ni][1], 0.f),
                          fmaxf(acc[mi][ni][2], 0.f), fmaxf(acc[mi][ni][3], 0.f));
            }
        }
    }
    __syncthreads();

    // L3 MFMA: B@w3+b3 (pre-LN) -> chunkA
    {
        f32x4 acc[4][2];
#pragma unroll
        for (int ni = 0; ni < 2; ++ni) {
            float b = b3[(2*wid + ni)*16 + (l & 15)];
#pragma unroll
            for (int mi = 0; mi < 4; ++mi) acc[mi][ni] = (f32x4){b,b,b,b};
        }
#pragma unroll
        for (int kk = 0; kk < 4; ++kk) {
            short8 af[4];
#pragma unroll
            for (int mi = 0; mi < 4; ++mi) af[mi] = loadA(chunkB, mi, kk, l);
#pragma unroll
            for (int ni = 0; ni < 2; ++ni) {
                short8 bw = loadB(w3p, 2*wid + ni, kk, 4, l);
#pragma unroll
                for (int mi = 0; mi < 4; ++mi) acc[mi][ni] = MFMA16(af[mi], bw, acc[mi][ni]);
            }
        }
#pragma unroll
        for (int ni = 0; ni < 2; ++ni) {
            int col = (2*wid + ni)*16 + (l & 15);
#pragma unroll
            for (int mi = 0; mi < 4; ++mi) {
                int R = mi*16 + ((l >> 4) << 2);
                storeQuad((u32*)chunkA, R, col, l,
                          acc[mi][ni][0], acc[mi][ni][1], acc[mi][ni][2], acc[mi][ni][3]);
            }
        }
    }
    __syncthreads();

    // LN stats: 4 lanes per row
    {
        int e = wid*16 + (l >> 2);
        int q = l & 3;
        const u32* rowp = (const u32*)chunkA + e*64;
        float s = 0.f, sq = 0.f;
#pragma unroll
        for (int i = 0; i < 16; ++i) {
            u32 pk = rowp[q*16 + i];
            float a = bf2f(pk & 0xffffu), b = bf2f(pk >> 16);
            s += a + b;
            sq = fmaf(a, a, fmaf(b, b, sq));
        }
        s  += __shfl_xor(s, 1);  sq += __shfl_xor(sq, 1);
        s  += __shfl_xor(s, 2);  sq += __shfl_xor(sq, 2);
        if (q == 0) {
            float mu = s * (1.f/HD);
            rstat[e] = mu;
            rstat[64 + e] = rsqrtf(sq*(1.f/HD) - mu*mu + LN_EPS);
        }
    }
    __syncthreads();

    // normalize in place
    for (int it = 0; it < 16; ++it) {
        int pd = it*256 + t;
        int row = pd >> 6, cwd = pd & 63;
        int ci = (cwd >> 2) ^ (row & 7);
        int col = ci*8 + (cwd & 3)*2;
        u32 pk = ((u32*)chunkA)[pd];
        float mu = rstat[row], ri = rstat[64 + row];
        float v0 = (bf2f(pk & 0xffffu) - mu)*ri*gg[col]     + bb[col];
        float v1 = (bf2f(pk >> 16)     - mu)*ri*gg[col + 1] + bb[col + 1];
        ((u32*)chunkA)[pd] = cvtpk(v0, v1);
    }
    __syncthreads();

    // GEMM @g1w, scale by dinv -> chunkB -> global
    {
        f32x4 acc[4][2];
#pragma unroll
        for (int mi = 0; mi < 4; ++mi)
#pragma unroll
            for (int ni = 0; ni < 2; ++ni) acc[mi][ni] = (f32x4){0.f,0.f,0.f,0.f};
#pragma unroll
        for (int kk = 0; kk < 4; ++kk) {
            short8 af[4];
#pragma unroll
            for (int mi = 0; mi < 4; ++mi) af[mi] = loadA(chunkA, mi, kk, l);
#pragma unroll
            for (int ni = 0; ni < 2; ++ni) {
                short8 bw = loadB(g1p, 2*wid + ni, kk, 4, l);
#pragma unroll
                for (int mi = 0; mi < 4; ++mi) acc[mi][ni] = MFMA16(af[mi], bw, acc[mi][ni]);
            }
        }
#pragma unroll
        for (int ni = 0; ni < 2; ++ni) {
            int col = (2*wid + ni)*16 + (l & 15);
#pragma unroll
            for (int mi = 0; mi < 4; ++mi) {
                int R = mi*16 + ((l >> 4) << 2);
                storeQuad((u32*)chunkB, R, col, l,
                          acc[mi][ni][0]*sDi[R], acc[mi][ni][1]*sDi[R+1],
                          acc[mi][ni][2]*sDi[R+2], acc[mi][ni][3]*sDi[R+3]);
            }
        }
    }
    __syncthreads();
    copyChunkOut((const u32*)chunkB, xw1p, n0, t);
}

// ---------------------------------------------------------------------------
// GCN layer 1: gather bf16 xw1p (prescaled), relu(+g1b), MFMA @g2w, *dinv -> xw2p
// 64 nodes/block, 4 threads/node for gather.
// ---------------------------------------------------------------------------
__global__ __launch_bounds__(256, 4)
void gcn_agg1_mfma(const u16* __restrict__ xw1p, const int* __restrict__ rp,
                   const int* __restrict__ sadj, const float* __restrict__ dinv,
                   const float* __restrict__ g1b, const u16* __restrict__ g2p,
                   u32* __restrict__ xw2p)
{
    __shared__ u16 chunkA[64*HD];
    __shared__ u16 chunkB[64*HD];
    __shared__ float sDi[64];
    __shared__ float sB[HD];

    const int t = threadIdx.x;
    const int l = t & 63;
    const int wid = t >> 6;
    const int n0 = blockIdx.x * 64;

    if (t < 64)  sDi[t] = (n0 + t < NN) ? dinv[n0 + t] : 0.f;
    if (t < HD)  sB[t] = g1b[t];
    __syncthreads();

    // gather
    {
        int s = t >> 2, part = t & 3, n = n0 + s;
        float acc[32];
#pragma unroll
        for (int j = 0; j < 32; ++j) acc[j] = 0.f;
        float di = 0.f;
        if (n < NN) {
            di = sDi[s];
            const short8* selfp = (const short8*)(xw1p + (size_t)n*HD + part*32);
#pragma unroll
            for (int w = 0; w < 4; ++w) {
                short8 v = selfp[w];
#pragma unroll
                for (int j = 0; j < 8; ++j) acc[w*8+j] += bf2f((u16)v[j]);
            }
            int k1 = rp[n+1];
            for (int k = rp[n]; k < k1; ++k) {
                const short8* rp8 = (const short8*)(xw1p + (size_t)sadj[k]*HD + part*32);
#pragma unroll
                for (int w = 0; w < 4; ++w) {
                    short8 v = rp8[w];
#pragma unroll
                    for (int j = 0; j < 8; ++j) acc[w*8+j] += bf2f((u16)v[j]);
                }
            }
        }
#pragma unroll
        for (int p = 0; p < 16; ++p) {
            float v0 = fmaxf(fmaf(acc[2*p],   di, sB[part*32 + 2*p]),   0.f);
            float v1 = fmaxf(fmaf(acc[2*p+1], di, sB[part*32 + 2*p+1]), 0.f);
            int cw = part*16 + p;
            ((u32*)chunkA)[s*64 + (((cw >> 2) ^ (s & 7)) << 2) + (cw & 3)] = cvtpk(v0, v1);
        }
    }
    __syncthreads();

    // MFMA @g2w, scale dinv -> chunkB
    {
        f32x4 acc[4][2];
#pragma unroll
        for (int mi = 0; mi < 4; ++mi)
#pragma unroll
            for (int ni = 0; ni < 2; ++ni) acc[mi][ni] = (f32x4){0.f,0.f,0.f,0.f};
#pragma unroll
        for (int kk = 0; kk < 4; ++kk) {
            short8 af[4];
#pragma unroll
            for (int mi = 0; mi < 4; ++mi) af[mi] = loadA(chunkA, mi, kk, l);
#pragma unroll
            for (int ni = 0; ni < 2; ++ni) {
                short8 bw = loadB(g2p, 2*wid + ni, kk, 4, l);
#pragma unroll
                for (int mi = 0; mi < 4; ++mi) acc[mi][ni] = MFMA16(af[mi], bw, acc[mi][ni]);
            }
        }
#pragma unroll
        for (int ni = 0; ni < 2; ++ni) {
            int col = (2*wid + ni)*16 + (l & 15);
#pragma unroll
            for (int mi = 0; mi < 4; ++mi) {
                int R = mi*16 + ((l >> 4) << 2);
                storeQuad((u32*)chunkB, R, col, l,
                          acc[mi][ni][0]*sDi[R], acc[mi][ni][1]*sDi[R+1],
                          acc[mi][ni][2]*sDi[R+2], acc[mi][ni][3]*sDi[R+3]);
            }
        }
    }
    __syncthreads();
    copyChunkOut((const u32*)chunkB, xw2p, n0, t);
}

// ---------------------------------------------------------------------------
// GCN layer 2: gather bf16 xw2p, +g2b -> h2 (fp32, for pool) + hbf (bf16)
// ---------------------------------------------------------------------------
__global__ __launch_bounds__(256)
void gcn_agg2_gather(const u16* __restrict__ xw2p, const int* __restrict__ rp,
                     const int* __restrict__ sadj, const float* __restrict__ dinv,
                     const float* __restrict__ g2b, float* __restrict__ h2,
                     u32* __restrict__ hbw)
{
    int t = threadIdx.x;
    int s = t >> 2, part = t & 3;
    int n = blockIdx.x * 64 + s;
    if (n >= NN) return;
    float acc[32];
#pragma unroll
    for (int j = 0; j < 32; ++j) acc[j] = 0.f;
    const short8* selfp = (const short8*)(xw2p + (size_t)n*HD + part*32);
#pragma unroll
    for (int w = 0; w < 4; ++w) {
        short8 v = selfp[w];
#pragma unroll
        for (int j = 0; j < 8; ++j) acc[w*8+j] += bf2f((u16)v[j]);
    }
    int k1 = rp[n+1];
    for (int k = rp[n]; k < k1; ++k) {
        const short8* rp8 = (const short8*)(xw2p + (size_t)sadj[k]*HD + part*32);
#pragma unroll
        for (int w = 0; w < 4; ++w) {
            short8 v = rp8[w];
#pragma unroll
            for (int j = 0; j < 8; ++j) acc[w*8+j] += bf2f((u16)v[j]);
        }
    }
    float di = dinv[n];
    float* ho = h2 + (size_t)n*HD + part*32;
    u32* hb = hbw + (size_t)n*64 + part*16;
#pragma unroll
    for (int p = 0; p < 16; ++p) {
        float v0 = fmaf(acc[2*p],   di, g2b[part*32 + 2*p]);
        float v1 = fmaf(acc[2*p+1], di, g2b[part*32 + 2*p+1]);
        ho[2*p] = v0; ho[2*p+1] = v1;
        hb[p] = cvtpk(v0, v1);
    }
}

// ---------------------------------------------------------------------------
// Pool (batch sorted) + counts + graph MLP
// ---------------------------------------------------------------------------
#define POOL_B 512
__global__ __launch_bounds__(128)
void pool_sorted(const float* __restrict__ h, const int* __restrict__ batch,
                 float* __restrict__ sums)
{
    int b = blockIdx.x, j = threadIdx.x;
    int n0 = (int)(((long long)NN * b) / POOL_B);
    int n1 = (int)(((long long)NN * (b+1)) / POOL_B);
    int g = -1; float acc = 0.f;
    for (int n = n0; n < n1; ++n) {
        int bg = batch[n];
        if (bg != g) {
            if (g >= 0) atomicAdd(&sums[g*HD + j], acc);
            g = bg; acc = 0.f;
        }
        acc += h[n*HD + j];
    }
    if (g >= 0) atomicAdd(&sums[g*HD + j], acc);
}

__global__ __launch_bounds__(256)
void cnt_k(const int* __restrict__ batch, float* __restrict__ cnts)
{
    int n = blockIdx.x*256 + threadIdx.x;
    if (n < NN) atomicAdd(&cnts[batch[n]], 1.f);
}

__global__ __launch_bounds__(128)
void graph_feat(const float* __restrict__ sums, const float* __restrict__ cnts,
                const float* __restrict__ w1, const float* __restrict__ b1,
                const float* __restrict__ w2, const float* __restrict__ b2,
                const float* __restrict__ gg, const float* __restrict__ bb,
                u16* __restrict__ gf16)
{
    int gi = blockIdx.x, j = threadIdx.x;
    __shared__ float s0[HD];
    __shared__ float s1[HD];
    __shared__ float part[4];
    __shared__ float stat[2];
    float cnt = fmaxf(cnts[gi], 1.f);
    s0[j] = sums[gi*HD + j] / cnt;
    __syncthreads();
    float a = b1[j];
    for (int i = 0; i < HD; ++i) a = fmaf(s0[i], w1[i*HD + j], a);
    s1[j] = fmaxf(a, 0.f);
    __syncthreads();
    a = b2[j];
    for (int i = 0; i < HD; ++i) a = fmaf(s1[i], w2[i*HD + j], a);
    float s = a, q = a*a;
    for (int o = 32; o > 0; o >>= 1) { s += __shfl_down(s, o); q += __shfl_down(q, o); }
    int wid = j >> 6, lane = j & 63;
    if (lane == 0) { part[wid] = s; part[2 + wid] = q; }
    __syncthreads();
    if (j == 0) {
        float S = part[0] + part[1], Q = part[2] + part[3];
        float mu = S * (1.f/HD);
        stat[0] = mu;
        stat[1] = Q * (1.f/HD) - mu*mu;
    }
    __syncthreads();
    float v = (a - stat[0]) * rsqrtf(stat[1] + LN_EPS) * gg[j] + bb[j];
    gf16[gi*HD + j] = f2bf(v);
}

// ---------------------------------------------------------------------------
// Stage 64 gathered bf16 rows into swizzled LDS chunk (4 threads/row)
// ---------------------------------------------------------------------------
__device__ __forceinline__ void stageRows(u16* dst, const u16* __restrict__ srcBase,
                                          const int* ridx, int t)
{
    int e = t >> 2, part = t & 3;
    const u16* src = srcBase + (size_t)ridx[e]*HD + part*32;
    u16* drow = dst + e*128;
    int re = e & 7;
#pragma unroll
    for (int w = 0; w < 4; ++w) {
        int ci = part*4 + w;
        *(short8*)(drow + ((ci ^ re) << 3)) = *(const short8*)(src + w*8);
    }
}

// ---------------------------------------------------------------------------
// Fused edge kernel (MFMA bf16). 64 edges/block, 256 threads, 3 blocks/CU.
// ---------------------------------------------------------------------------
__global__ __launch_bounds__(256, 3)
void edge_mlp_mfma(const u16* __restrict__ hbf, const u16* __restrict__ gfbf,
                   const int* __restrict__ ei, const int* __restrict__ batch,
                   const float* __restrict__ ea,
                   const float* __restrict__ ew1, const float* __restrict__ eb1,
                   const u16* __restrict__ ew2p, const float* __restrict__ eb2,
                   const u16* __restrict__ ew3p, const float* __restrict__ eb3,
                   const float* __restrict__ egm, const float* __restrict__ ebb,
                   const u16* __restrict__ p1wp, const float* __restrict__ p1b,
                   const u16* __restrict__ p2wp, const float* __restrict__ p2b,
                   const u16* __restrict__ p3wp, const float* __restrict__ p3b,
                   const float* __restrict__ p4w, const float* __restrict__ p4b,
                   float* __restrict__ out)
{
    __shared__ u16 bufChunk[64*HD];    // 16KB swizzled A-chunk
    __shared__ u16 bufWide[64*256];    // 32KB (2 chunks / fp32 scratch)
    __shared__ float sEa[192];
    __shared__ int sSrc[64], sDst[64], sGf[64];
    __shared__ float rstat[128];

    const int t = threadIdx.x;
    const int l = t & 63;
    const int wid = t >> 6;
    const int e0 = blockIdx.x * 64;

    if (t < 64) {
        int s = ei[e0 + t];
        sSrc[t] = s;
        sDst[t] = ei[NE + e0 + t];
        sGf[t]  = batch[s];
    }
    if (t < 192) sEa[t] = ea[e0*3 + t];
    __syncthreads();

    // ---- enc1: relu(ea@ew1+b1) -> bufChunk ----
    for (int it = 0; it < 16; ++it) {
        int dw = it*256 + t;
        int e = dw >> 6, cd = dw & 63;
        int c0 = cd*2;
        float x0 = sEa[e*3], x1 = sEa[e*3+1], x2 = sEa[e*3+2];
        float v0 = eb1[c0]   + x0*ew1[c0]   + x1*ew1[HD+c0]   + x2*ew1[2*HD+c0];
        float v1 = eb1[c0+1] + x0*ew1[c0+1] + x1*ew1[HD+c0+1] + x2*ew1[2*HD+c0+1];
        v0 = fmaxf(v0, 0.f); v1 = fmaxf(v1, 0.f);
        int ci = cd >> 2;
        ((u32*)bufChunk)[e*64 + ((ci ^ (e & 7)) << 2) + (cd & 3)] = cvtpk(v0, v1);
    }
    __syncthreads();

    // ---- enc2: relu(A@ew2+b2) -> bufWide chunk0 ----
    {
        f32x4 acc[4][2];
#pragma unroll
        for (int ni = 0; ni < 2; ++ni) {
            float b = eb2[(2*wid + ni)*16 + (l & 15)];
#pragma unroll
            for (int mi = 0; mi < 4; ++mi) acc[mi][ni] = (f32x4){b,b,b,b};
        }
#pragma unroll
        for (int kk = 0; kk < 4; ++kk) {
            short8 af[4];
#pragma unroll
            for (int mi = 0; mi < 4; ++mi) af[mi] = loadA(bufChunk, mi, kk, l);
#pragma unroll
            for (int ni = 0; ni < 2; ++ni) {
                short8 bw = loadB(ew2p, 2*wid + ni, kk, 4, l);
#pragma unroll
                for (int mi = 0; mi < 4; ++mi) acc[mi][ni] = MFMA16(af[mi], bw, acc[mi][ni]);
            }
        }
#pragma unroll
        for (int ni = 0; ni < 2; ++ni) {
            int col = (2*wid + ni)*16 + (l & 15);
#pragma unroll
            for (int mi = 0; mi < 4; ++mi) {
                int R = mi*16 + ((l >> 4) << 2);
                storeQuad((u32*)bufWide, R, col, l,
                          fmaxf(acc[mi][ni][0], 0.f), fmaxf(acc[mi][ni][1], 0.f),
                          fmaxf(acc[mi][ni][2], 0.f), fmaxf(acc[mi][ni][3], 0.f));
            }
        }
    }
    __syncthreads();

    // ---- enc3: W0@ew3+b3 (pre-LN) -> bufChunk ----
    {
        f32x4 acc[4][2];
#pragma unroll
        for (int ni = 0; ni < 2; ++ni) {
            float b = eb3[(2*wid + ni)*16 + (l & 15)];
#pragma unroll
            for (int mi = 0; mi < 4; ++mi) acc[mi][ni] = (f32x4){b,b,b,b};
        }
#pragma unroll
        for (int kk = 0; kk < 4; ++kk) {
            short8 af[4];
#pragma unroll
            for (int mi = 0; mi < 4; ++mi) af[mi] = loadA(bufWide, mi, kk, l);
#pragma unroll
            for (int ni = 0; ni < 2; ++ni) {
                short8 bw = loadB(ew3p, 2*wid + ni, kk, 4, l);
#pragma unroll
                for (int mi = 0; mi < 4; ++mi) acc[mi][ni] = MFMA16(af[mi], bw, acc[mi][ni]);
            }
        }
#pragma unroll
        for (int ni = 0; ni < 2; ++ni) {
            int col = (2*wid + ni)*16 + (l & 15);
#pragma unroll
            for (int mi = 0; mi < 4; ++mi) {
                int R = mi*16 + ((l >> 4) << 2);
                storeQuad((u32*)bufChunk, R, col, l,
                          acc[mi][ni][0], acc[mi][ni][1], acc[mi][ni][2], acc[mi][ni][3]);
            }
        }
    }
    __syncthreads();

    // ---- LN stats: 4 lanes per edge ----
    {
        int e = wid*16 + (l >> 2);
        int q = l & 3;
        const u32* rowp = (const u32*)bufChunk + e*64;
        float s = 0.f, sq = 0.f;
#pragma unroll
        for (int i = 0; i < 16; ++i) {
            u32 pk = rowp[q*16 + i];
            float a = bf2f(pk & 0xffffu), b = bf2f(pk >> 16);
            s += a + b;
            sq = fmaf(a, a, fmaf(b, b, sq));
        }
        s  += __shfl_xor(s, 1);  sq += __shfl_xor(sq, 1);
        s  += __shfl_xor(s, 2);  sq += __shfl_xor(sq, 2);
        if (q == 0) {
            float mu = s * (1.f/HD);
            rstat[e] = mu;
            rstat[64 + e] = rsqrtf(sq*(1.f/HD) - mu*mu + LN_EPS);
        }
    }
    __syncthreads();

    // ---- normalize in place: bufChunk = ef ----
    for (int it = 0; it < 16; ++it) {
        int pd = it*256 + t;
        int row = pd >> 6, cwd = pd & 63;
        int ci = (cwd >> 2) ^ (row & 7);
        int col = ci*8 + (cwd & 3)*2;
        u32 pk = ((u32*)bufChunk)[pd];
        float mu = rstat[row], ri = rstat[64 + row];
        float v0 = (bf2f(pk & 0xffffu) - mu)*ri*egm[col]     + ebb[col];
        float v1 = (bf2f(pk >> 16)     - mu)*ri*egm[col + 1] + ebb[col + 1];
        ((u32*)bufChunk)[pd] = cvtpk(v0, v1);
    }
    __syncthreads();

    // ---- stage h[src]->W0, h[dst]->W1 ----
    stageRows(bufWide,        hbf, sSrc, t);
    stageRows(bufWide + 8192, hbf, sDst, t);
    __syncthreads();

    // ---- ep1 MFMA: ef (ks 12..15), hsrc (ks 0..3), hdst (ks 4..7) ----
    f32x4 acc1[4][4];
#pragma unroll
    for (int ni = 0; ni < 4; ++ni) {
        float b = p1b[(4*wid + ni)*16 + (l & 15)];
#pragma unroll
        for (int mi = 0; mi < 4; ++mi) acc1[mi][ni] = (f32x4){b,b,b,b};
    }
#pragma unroll
    for (int kk = 0; kk < 4; ++kk) {
        short8 af[4];
#pragma unroll
        for (int mi = 0; mi < 4; ++mi) af[mi] = loadA(bufChunk, mi, kk, l);
#pragma unroll
        for (int ni = 0; ni < 4; ++ni) {
            short8 bw = loadB(p1wp, 4*wid + ni, 12 + kk, 16, l);
#pragma unroll
            for (int mi = 0; mi < 4; ++mi) acc1[mi][ni] = MFMA16(af[mi], bw, acc1[mi][ni]);
        }
    }
#pragma unroll
    for (int kk = 0; kk < 4; ++kk) {
        short8 af[4];
#pragma unroll
        for (int mi = 0; mi < 4; ++mi) af[mi] = loadA(bufWide, mi, kk, l);
#pragma unroll
        for (int ni = 0; ni < 4; ++ni) {
            short8 bw = loadB(p1wp, 4*wid + ni, kk, 16, l);
#pragma unroll
            for (int mi = 0; mi < 4; ++mi) acc1[mi][ni] = MFMA16(af[mi], bw, acc1[mi][ni]);
        }
    }
#pragma unroll
    for (int kk = 0; kk < 4; ++kk) {
        short8 af[4];
#pragma unroll
        for (int mi = 0; mi < 4; ++mi) af[mi] = loadA(bufWide + 8192, mi, kk, l);
#pragma unroll
        for (int ni = 0; ni < 4; ++ni) {
            short8 bw = loadB(p1wp, 4*wid + ni, 4 + kk, 16, l);
#pragma unroll
            for (int mi = 0; mi < 4; ++mi) acc1[mi][ni] = MFMA16(af[mi], bw, acc1[mi][ni]);
        }
    }
    __syncthreads();

    // ---- stage gf -> bufChunk, MFMA (ks 8..11), epilogue tanh -> bufWide ----
    stageRows(bufChunk, gfbf, sGf, t);
    __syncthreads();
#pragma unroll
    for (int kk = 0; kk < 4; ++kk) {
        short8 af[4];
#pragma unroll
        for (int mi = 0; mi < 4; ++mi) af[mi] = loadA(bufChunk, mi, kk, l);
#pragma unroll
        for (int ni = 0; ni < 4; ++ni) {
            short8 bw = loadB(p1wp, 4*wid + ni, 8 + kk, 16, l);
#pragma unroll
            for (int mi = 0; mi < 4; ++mi) acc1[mi][ni] = MFMA16(af[mi], bw, acc1[mi][ni]);
        }
    }
#pragma unroll
    for (int ni = 0; ni < 4; ++ni) {
        int col = (4*wid + ni)*16 + (l & 15);
        u32* dst = (u32*)bufWide + ((col >> 7) << 12);
        int cc = col & 127;
#pragma unroll
        for (int mi = 0; mi < 4; ++mi) {
            int R = mi*16 + ((l >> 4) << 2);
            storeQuad(dst, R, cc, l,
                      fast_tanh(acc1[mi][ni][0]), fast_tanh(acc1[mi][ni][1]),
                      fast_tanh(acc1[mi][ni][2]), fast_tanh(acc1[mi][ni][3]));
        }
    }
    __syncthreads();

    // ---- ep2: [64,256]@p2w[256,128], tanh -> bufChunk ----
    {
        f32x4 acc[4][2];
#pragma unroll
        for (int ni = 0; ni < 2; ++ni) {
            float b = p2b[(2*wid + ni)*16 + (l & 15)];
#pragma unroll
            for (int mi = 0; mi < 4; ++mi) acc[mi][ni] = (f32x4){b,b,b,b};
        }
        for (int kc = 0; kc < 2; ++kc) {
            const u16* abuf = bufWide + (kc << 13);
#pragma unroll
            for (int kk = 0; kk < 4; ++kk) {
                short8 af[4];
#pragma unroll
                for (int mi = 0; mi < 4; ++mi) af[mi] = loadA(abuf, mi, kk, l);
                int ks = kc*4 + kk;
#pragma unroll
                for (int ni = 0; ni < 2; ++ni) {
                    short8 bw = loadB(p2wp, 2*wid + ni, ks, 8, l);
#pragma unroll
                    for (int mi = 0; mi < 4; ++mi) acc[mi][ni] = MFMA16(af[mi], bw, acc[mi][ni]);
                }
            }
        }
#pragma unroll
        for (int ni = 0; ni < 2; ++ni) {
            int col = (2*wid + ni)*16 + (l & 15);
#pragma unroll
            for (int mi = 0; mi < 4; ++mi) {
                int R = mi*16 + ((l >> 4) << 2);
                storeQuad((u32*)bufChunk, R, col, l,
                          fast_tanh(acc[mi][ni][0]), fast_tanh(acc[mi][ni][1]),
                          fast_tanh(acc[mi][ni][2]), fast_tanh(acc[mi][ni][3]));
            }
        }
    }
    __syncthreads();

    // ---- ep3: [64,128]@p3w[128,64], relu -> bufWide fp32 stride-65 ----
    {
        f32x4 acc[4];
        {
            float b = p3b[wid*16 + (l & 15)];
#pragma unroll
            for (int mi = 0; mi < 4; ++mi) acc[mi] = (f32x4){b,b,b,b};
        }
#pragma unroll
        for (int kk = 0; kk < 4; ++kk) {
            short8 af[4];
#pragma unroll
            for (int mi = 0; mi < 4; ++mi) af[mi] = loadA(bufChunk, mi, kk, l);
            short8 bw = loadB(p3wp, wid, kk, 4, l);
#pragma unroll
            for (int mi = 0; mi < 4; ++mi) acc[mi] = MFMA16(af[mi], bw, acc[mi]);
        }
        float* fb = (float*)bufWide;
        int col = wid*16 + (l & 15);
#pragma unroll
        for (int mi = 0; mi < 4; ++mi)
#pragma unroll
            for (int rr = 0; rr < 4; ++rr) {
                int row = mi*16 + ((l >> 4) << 2) + rr;
                fb[row*65 + col] = fmaxf(acc[mi][rr], 0.f);
            }
    }
    __syncthreads();

    // ---- ep4: 4 lanes/edge dot-64 + sigmoid ----
    {
        const float* fb = (const float*)bufWide;
        int e = wid*16 + (l >> 2), q = l & 3;
        float v = 0.f;
#pragma unroll
        for (int k = 0; k < 16; ++k) {
            int i = q*16 + k;
            v = fmaf(fb[e*65 + i], p4w[i], v);
        }
        v += __shfl_xor(v, 1);
        v += __shfl_xor(v, 2);
        if (q == 0) out[e0 + e] = fast_sigmoid(v + p4b[0]);
    }
}

// ---------------------------------------------------------------------------
extern "C" void kernel_launch(void* const* d_in, const int* in_sizes, int n_in,
                              void* d_out, int out_size, void* d_ws, size_t ws_size,
                              hipStream_t stream)
{
    const float* x     = (const float*)d_in[0];
    const int*   ei    = (const int*)  d_in[1];
    const float* ea    = (const float*)d_in[2];
    const int*   batch = (const int*)  d_in[3];
    const float* ne1w = (const float*)d_in[4];  const float* ne1b = (const float*)d_in[5];
    const float* ne2w = (const float*)d_in[6];  const float* ne2b = (const float*)d_in[7];
    const float* ne3w = (const float*)d_in[8];  const float* ne3b = (const float*)d_in[9];
    const float* neg  = (const float*)d_in[10]; const float* nebb = (const float*)d_in[11];
    const float* ee1w = (const float*)d_in[12]; const float* ee1b = (const float*)d_in[13];
    const float* ee2w = (const float*)d_in[14]; const float* ee2b = (const float*)d_in[15];
    const float* ee3w = (const float*)d_in[16]; const float* ee3b = (const float*)d_in[17];
    const float* eeg  = (const float*)d_in[18]; const float* eebb = (const float*)d_in[19];
    const float* g1w  = (const float*)d_in[20]; const float* g1b  = (const float*)d_in[21];
    const float* g2w  = (const float*)d_in[22]; const float* g2b  = (const float*)d_in[23];
    const float* gp1w = (const float*)d_in[24]; const float* gp1b = (const float*)d_in[25];
    const float* gp2w = (const float*)d_in[26]; const float* gp2b = (const float*)d_in[27];
    const float* gpg  = (const float*)d_in[28]; const float* gpbb = (const float*)d_in[29];
    const float* p1w  = (const float*)d_in[30]; const float* p1b  = (const float*)d_in[31];
    const float* p2w  = (const float*)d_in[32]; const float* p2b  = (const float*)d_in[33];
    const float* p3w  = (const float*)d_in[34]; const float* p3b  = (const float*)d_in[35];
    const float* p4w  = (const float*)d_in[36]; const float* p4b  = (const float*)d_in[37];

    float* h2   = (float*)d_ws;                // NN*HD (fp32, pool input)
    float* dinv = h2 + (size_t)NN*HD;          // NN
    float* sums = dinv + NN;                   // NG*HD
    float* cnts = sums + NG*HD;                // NG
    int* degi   = (int*)(cnts + NG);           // NN
    int* cursor = degi + NN;                   // NN+2
    int* rowptr = cursor + NN + 2;             // NN+2
    int* sadj   = rowptr + NN + 2;             // NE
    u16* xw1p   = (u16*)(sadj + NE);           // NN*HD
    u16* xw2p   = xw1p + (size_t)NN*HD;        // NN*HD
    u16* hbf    = xw2p + (size_t)NN*HD;        // NN*HD
    u16* gf16   = hbf + (size_t)NN*HD;         // NG*HD
    u16* wpk    = gf16 + NG*HD;                // 270336
    u16* ee2p = wpk;
    u16* ee3p = wpk + 16384;
    u16* p1p  = wpk + 32768;
    u16* p2p  = wpk + 163840;
    u16* p3p  = wpk + 196608;
    u16* ne2p = wpk + 204800;
    u16* ne3p = wpk + 221184;
    u16* g1p  = wpk + 237568;
    u16* g2p  = wpk + 253952;

    float* out = (float*)d_out;

    hipMemsetAsync(degi, 0, (size_t)(2*NN + 2)*sizeof(int), stream);   // degi + cursor
    hipMemsetAsync(sums, 0, (size_t)(NG*HD + NG)*sizeof(float), stream);

    pack_all<<<(270336 + 255)/256, 256, 0, stream>>>(ee2w, ee3w, p1w, p2w, p3w,
                                                     ne2w, ne3w, g1w, g2w, wpk);

    // CSR build
    deg_count_int<<<(NE + 255)/256, 256, 0, stream>>>(ei, degi);
    dinv_k<<<(NN + 255)/256, 256, 0, stream>>>(degi, dinv);
    scan_excl<<<1, 1024, 0, stream>>>(degi, rowptr);
    fill_csr<<<(NE + 255)/256, 256, 0, stream>>>(ei, rowptr, cursor, sadj);

    // node encoder + g1 GEMM (bf16 out, prescaled by dinv)
    enc_mfma<<<(NN + 63)/64, 256, 0, stream>>>(x, ne1w, ne1b, ne2p, ne2b, ne3p, ne3b,
                                               neg, nebb, g1p, dinv, (u32*)xw1p);
    // GCN1 gather + relu + g2 GEMM
    gcn_agg1_mfma<<<(NN + 63)/64, 256, 0, stream>>>(xw1p, rowptr, sadj, dinv,
                                                    g1b, g2p, (u32*)xw2p);
    // GCN2 gather -> h2 fp32 + hbf bf16
    gcn_agg2_gather<<<(NN + 63)/64, 256, 0, stream>>>(xw2p, rowptr, sadj, dinv,
                                                      g2b, h2, (u32*)hbf);

    // pool + graph MLP
    pool_sorted<<<POOL_B, 128, 0, stream>>>(h2, batch, sums);
    cnt_k<<<(NN + 255)/256, 256, 0, stream>>>(batch, cnts);
    graph_feat<<<NG, 128, 0, stream>>>(sums, cnts, gp1w, gp1b, gp2w, gp2b,
                                       gpg, gpbb, gf16);

    // fused edge encoder + edge-score MLP
    edge_mlp_mfma<<<NE/64, 256, 0, stream>>>(hbf, gf16, ei, batch, ea,
                                             ee1w, ee1b, ee2p, ee2b, ee3p, ee3b,
                                             eeg, eebb,
                                             p1p, p1b, p2p, p2b, p3p, p3b,
                                             p4w, p4b, out);
}

// Round 5
// 759.507 us; speedup vs baseline: 6.7618x; 1.1301x over previous
//
#include <hip/hip_runtime.h>
#include <math.h>

#define NN 50000
#define NE 400000
#define NG 64
#define HD 128
#define LN_EPS 1e-5f

typedef unsigned short u16;
typedef unsigned int u32;
typedef __attribute__((ext_vector_type(8))) short short8;
typedef __attribute__((ext_vector_type(4))) float f32x4;

#define MFMA16(a,b,c) __builtin_amdgcn_mfma_f32_16x16x32_bf16((a),(b),(c),0,0,0)

__device__ __forceinline__ u16 f2bf(float f) {
    union { float f; u32 u; } v; v.f = f;
    u32 r = v.u + 0x7FFFu + ((v.u >> 16) & 1u);
    return (u16)(r >> 16);
}
__device__ __forceinline__ float bf2f(u32 hs) {
    union { u32 u; float f; } v; v.u = hs << 16;
    return v.f;
}
__device__ __forceinline__ float fast_rcp(float x) {
    float r; asm("v_rcp_f32 %0, %1" : "=v"(r) : "v"(x)); return r;
}
__device__ __forceinline__ u32 cvtpk(float lo, float hi) {
    u32 r; asm("v_cvt_pk_bf16_f32 %0, %1, %2" : "=v"(r) : "v"(lo), "v"(hi)); return r;
}
__device__ __forceinline__ float fast_tanh(float x) {
    return fmaf(-2.f, fast_rcp(1.f + __expf(2.f * x)), 1.f);
}
__device__ __forceinline__ float fast_sigmoid(float x) {
    return fast_rcp(1.f + __expf(-x));
}

// A-fragment load from swizzled [64][128] bf16 chunk buffer.
__device__ __forceinline__ short8 loadA(const u16* buf, int mi, int kk, int l) {
    int row = mi*16 + (l & 15);
    int ci  = (kk*4 + (l >> 4)) ^ (l & 7);     // row&7 == l&7 (mi*16 multiple of 8)
    return *(const short8*)(buf + row*128 + (ci << 3));
}
__device__ __forceinline__ short8 loadB(const u16* wp, int nt, int ks, int nk, int l) {
    return *(const short8*)(wp + (((nt*nk + ks)*64 + l) << 3));
}

// Store 4 accumulator values (rows R..R+3, col c) into swizzled bf16 chunk as
// packed u32 via lane-pair exchange + v_cvt_pk_bf16_f32.
__device__ __forceinline__ void storeQuad(u32* buf, int R, int c, int l,
                                          float v0, float v1, float v2, float v3)
{
    int cw = c >> 1;
    int par = l & 1;
    float send = par ? v0 : v1;
    float recv = __shfl_xor(send, 1);
    int row = R + par;
    u32 word = par ? cvtpk(recv, v1) : cvtpk(v0, recv);
    buf[row*64 + (((cw >> 2) ^ (row & 7)) << 2) + (cw & 3)] = word;
    send = par ? v2 : v3;
    recv = __shfl_xor(send, 1);
    row = R + 2 + par;
    word = par ? cvtpk(recv, v3) : cvtpk(v2, recv);
    buf[row*64 + (((cw >> 2) ^ (row & 7)) << 2) + (cw & 3)] = word;
}

// Unswizzle copy: LDS chunk -> global bf16 [64][128] rows n0..n0+63 (u32 words)
__device__ __forceinline__ void copyChunkOut(const u32* chunk, u32* gout, int n0, int t)
{
    for (int it = 0; it < 16; ++it) {
        int dw = it*256 + t;
        int row = dw >> 6, cw = dw & 63;
        if (n0 + row < NN)
            gout[(size_t)(n0 + row)*64 + cw] =
                chunk[row*64 + ((((cw >> 2) ^ (row & 7)) << 2)) + (cw & 3)];
    }
}

// ---------------------------------------------------------------------------
// One-shot weight packing of all 9 GEMM weights -> bf16 MFMA B-fragment order.
// ---------------------------------------------------------------------------
__global__ __launch_bounds__(256)
void pack_all(const float* __restrict__ ee2w, const float* __restrict__ ee3w,
              const float* __restrict__ p1w,  const float* __restrict__ p2w,
              const float* __restrict__ p3w,  const float* __restrict__ ne2w,
              const float* __restrict__ ne3w, const float* __restrict__ g1w,
              const float* __restrict__ g2w,  u16* __restrict__ wpk)
{
    int idx = blockIdx.x*256 + threadIdx.x;
    if (idx >= 270336) return;
    const float* w; int K, N, local;
    if      (idx < 16384)  { w = ee2w; K = 128; N = 128; local = idx; }
    else if (idx < 32768)  { w = ee3w; K = 128; N = 128; local = idx - 16384; }
    else if (idx < 163840) { w = p1w;  K = 512; N = 256; local = idx - 32768; }
    else if (idx < 196608) { w = p2w;  K = 256; N = 128; local = idx - 163840; }
    else if (idx < 204800) { w = p3w;  K = 128; N = 64;  local = idx - 196608; }
    else if (idx < 221184) { w = ne2w; K = 128; N = 128; local = idx - 204800; }
    else if (idx < 237568) { w = ne3w; K = 128; N = 128; local = idx - 221184; }
    else if (idx < 253952) { w = g1w;  K = 128; N = 128; local = idx - 237568; }
    else                   { w = g2w;  K = 128; N = 128; local = idx - 253952; }
    int e = local & 7, l = (local >> 3) & 63, r = local >> 9;
    int nk = K >> 5;
    int nt = r / nk, kk = r % nk;
    int k = kk*32 + ((l >> 4) << 3) + e;
    int n = nt*16 + (l & 15);
    wpk[idx] = f2bf(w[k*N + n]);
}

// ---------------------------------------------------------------------------
// CSR build
// ---------------------------------------------------------------------------
__global__ __launch_bounds__(256)
void deg_count_int(const int* __restrict__ ei, int* __restrict__ degi)
{
    int e = blockIdx.x*256 + threadIdx.x;
    if (e < NE) atomicAdd(&degi[ei[NE + e]], 1);
}

__global__ __launch_bounds__(256)
void dinv_k(const int* __restrict__ degi, float* __restrict__ dinv)
{
    int n = blockIdx.x*256 + threadIdx.x;
    if (n < NN) dinv[n] = rsqrtf((float)degi[n] + 1.f);
}

__global__ __launch_bounds__(1024)
void scan_excl(const int* __restrict__ cnt, int* __restrict__ rp)
{
    __shared__ int wsum[16];
    __shared__ int carry;
    int t = threadIdx.x, lane = t & 63, w = t >> 6;
    int base = 0;
    for (int off = 0; off < NN; off += 4096) {
        int i0 = off + t*4;
        int v0 = (i0   < NN) ? cnt[i0]   : 0;
        int v1 = (i0+1 < NN) ? cnt[i0+1] : 0;
        int v2 = (i0+2 < NN) ? cnt[i0+2] : 0;
        int v3 = (i0+3 < NN) ? cnt[i0+3] : 0;
        int tot = v0 + v1 + v2 + v3;
        int s = tot;
#pragma unroll
        for (int d = 1; d < 64; d <<= 1) { int u = __shfl_up(s, d); if (lane >= d) s += u; }
        if (lane == 63) wsum[w] = s;
        __syncthreads();
        if (w == 0) {
            int wv = (lane < 16) ? wsum[lane] : 0;
            int ss = wv;
#pragma unroll
            for (int d = 1; d < 16; d <<= 1) { int u = __shfl_up(ss, d); if (lane >= d) ss += u; }
            if (lane < 16) wsum[lane] = ss - wv;
            if (lane == 15) carry = ss;
        }
        __syncthreads();
        int excl = base + wsum[w] + s - tot;
        if (i0   < NN) rp[i0]   = excl;
        if (i0+1 < NN) rp[i0+1] = excl + v0;
        if (i0+2 < NN) rp[i0+2] = excl + v0 + v1;
        if (i0+3 < NN) rp[i0+3] = excl + v0 + v1 + v2;
        base += carry;
        __syncthreads();
    }
    if (t == 0) rp[NN] = base;
}

__global__ __launch_bounds__(256)
void fill_csr(const int* __restrict__ ei, const int* __restrict__ rp,
              int* __restrict__ cursor, int* __restrict__ sadj)
{
    int e = blockIdx.x*256 + threadIdx.x;
    if (e >= NE) return;
    int d = ei[NE + e];
    int slot = atomicAdd(&cursor[d], 1);
    sadj[rp[d] + slot] = ei[e];
}

// ---------------------------------------------------------------------------
// Node encoder + g1w GEMM, MFMA. 64 nodes/block, 256 threads.
// ---------------------------------------------------------------------------
__global__ __launch_bounds__(256, 4)
void enc_mfma(const float* __restrict__ x,
              const float* __restrict__ w1, const float* __restrict__ b1,
              const u16* __restrict__ w2p, const float* __restrict__ b2,
              const u16* __restrict__ w3p, const float* __restrict__ b3,
              const float* __restrict__ gg, const float* __restrict__ bb,
              const u16* __restrict__ g1p, const float* __restrict__ dinv,
              u32* __restrict__ xw1p)
{
    __shared__ u16 chunkA[64*HD];
    __shared__ u16 chunkB[64*HD];
    __shared__ float sX[192];
    __shared__ float sDi[64];
    __shared__ float rstat[128];

    const int t = threadIdx.x;
    const int l = t & 63;
    const int wid = t >> 6;
    const int n0 = blockIdx.x * 64;

    if (t < 192) sX[t] = (n0*3 + t < NN*3) ? x[n0*3 + t] : 0.f;
    if (t < 64)  sDi[t] = (n0 + t < NN) ? dinv[n0 + t] : 0.f;
    __syncthreads();

    // L1: 3->128 relu (VALU) -> chunkA
    for (int it = 0; it < 16; ++it) {
        int dw = it*256 + t;
        int e = dw >> 6, cd = dw & 63;
        int c0 = cd*2;
        float x0 = sX[e*3], x1 = sX[e*3+1], x2 = sX[e*3+2];
        float v0 = b1[c0]   + x0*w1[c0]   + x1*w1[HD+c0]   + x2*w1[2*HD+c0];
        float v1 = b1[c0+1] + x0*w1[c0+1] + x1*w1[HD+c0+1] + x2*w1[2*HD+c0+1];
        v0 = fmaxf(v0, 0.f); v1 = fmaxf(v1, 0.f);
        int ci = cd >> 2;
        ((u32*)chunkA)[e*64 + ((ci ^ (e & 7)) << 2) + (cd & 3)] = cvtpk(v0, v1);
    }
    __syncthreads();

    // L2 MFMA: relu(A@w2+b2) -> chunkB
    {
        f32x4 acc[4][2];
#pragma unroll
        for (int ni = 0; ni < 2; ++ni) {
            float b = b2[(2*wid + ni)*16 + (l & 15)];
#pragma unroll
            for (int mi = 0; mi < 4; ++mi) acc[mi][ni] = (f32x4){b,b,b,b};
        }
#pragma unroll
        for (int kk = 0; kk < 4; ++kk) {
            short8 af[4];
#pragma unroll
            for (int mi = 0; mi < 4; ++mi) af[mi] = loadA(chunkA, mi, kk, l);
#pragma unroll
            for (int ni = 0; ni < 2; ++ni) {
                short8 bw = loadB(w2p, 2*wid + ni, kk, 4, l);
#pragma unroll
                for (int mi = 0; mi < 4; ++mi) acc[mi][ni] = MFMA16(af[mi], bw, acc[mi][ni]);
            }
        }
#pragma unroll
        for (int ni = 0; ni < 2; ++ni) {
            int col = (2*wid + ni)*16 + (l & 15);
#pragma unroll
            for (int mi = 0; mi < 4; ++mi) {
                int R = mi*16 + ((l >> 4) << 2);
                storeQuad((u32*)chunkB, R, col, l,
                          fmaxf(acc[mi][ni][0], 0.f), fmaxf(acc[mi][ni][1], 0.f),
                          fmaxf(acc[mi][ni][2], 0.f), fmaxf(acc[mi][ni][3], 0.f));
            }
        }
    }
    __syncthreads();

    // L3 MFMA: B@w3+b3 (pre-LN) -> chunkA
    {
        f32x4 acc[4][2];
#pragma unroll
        for (int ni = 0; ni < 2; ++ni) {
            float b = b3[(2*wid + ni)*16 + (l & 15)];
#pragma unroll
            for (int mi = 0; mi < 4; ++mi) acc[mi][ni] = (f32x4){b,b,b,b};
        }
#pragma unroll
        for (int kk = 0; kk < 4; ++kk) {
            short8 af[4];
#pragma unroll
            for (int mi = 0; mi < 4; ++mi) af[mi] = loadA(chunkB, mi, kk, l);
#pragma unroll
            for (int ni = 0; ni < 2; ++ni) {
                short8 bw = loadB(w3p, 2*wid + ni, kk, 4, l);
#pragma unroll
                for (int mi = 0; mi < 4; ++mi) acc[mi][ni] = MFMA16(af[mi], bw, acc[mi][ni]);
            }
        }
#pragma unroll
        for (int ni = 0; ni < 2; ++ni) {
            int col = (2*wid + ni)*16 + (l & 15);
#pragma unroll
            for (int mi = 0; mi < 4; ++mi) {
                int R = mi*16 + ((l >> 4) << 2);
                storeQuad((u32*)chunkA, R, col, l,
                          acc[mi][ni][0], acc[mi][ni][1], acc[mi][ni][2], acc[mi][ni][3]);
            }
        }
    }
    __syncthreads();

    // LN stats: 4 lanes per row, rotated read (bank-spread)
    {
        int e = wid*16 + (l >> 2);
        int q = l & 3;
        const u32* rowp = (const u32*)chunkA + e*64;
        float s = 0.f, sq = 0.f;
#pragma unroll
        for (int i = 0; i < 16; ++i) {
            u32 pk = rowp[q*16 + ((i + e) & 15)];
            float a = bf2f(pk & 0xffffu), b = bf2f(pk >> 16);
            s += a + b;
            sq = fmaf(a, a, fmaf(b, b, sq));
        }
        s  += __shfl_xor(s, 1);  sq += __shfl_xor(sq, 1);
        s  += __shfl_xor(s, 2);  sq += __shfl_xor(sq, 2);
        if (q == 0) {
            float mu = s * (1.f/HD);
            rstat[e] = mu;
            rstat[64 + e] = rsqrtf(sq*(1.f/HD) - mu*mu + LN_EPS);
        }
    }
    __syncthreads();

    // normalize in place
    for (int it = 0; it < 16; ++it) {
        int pd = it*256 + t;
        int row = pd >> 6, cwd = pd & 63;
        int ci = (cwd >> 2) ^ (row & 7);
        int col = ci*8 + (cwd & 3)*2;
        u32 pk = ((u32*)chunkA)[pd];
        float mu = rstat[row], ri = rstat[64 + row];
        float v0 = (bf2f(pk & 0xffffu) - mu)*ri*gg[col]     + bb[col];
        float v1 = (bf2f(pk >> 16)     - mu)*ri*gg[col + 1] + bb[col + 1];
        ((u32*)chunkA)[pd] = cvtpk(v0, v1);
    }
    __syncthreads();

    // GEMM @g1w, scale by dinv -> chunkB -> global
    {
        f32x4 acc[4][2];
#pragma unroll
        for (int mi = 0; mi < 4; ++mi)
#pragma unroll
            for (int ni = 0; ni < 2; ++ni) acc[mi][ni] = (f32x4){0.f,0.f,0.f,0.f};
#pragma unroll
        for (int kk = 0; kk < 4; ++kk) {
            short8 af[4];
#pragma unroll
            for (int mi = 0; mi < 4; ++mi) af[mi] = loadA(chunkA, mi, kk, l);
#pragma unroll
            for (int ni = 0; ni < 2; ++ni) {
                short8 bw = loadB(g1p, 2*wid + ni, kk, 4, l);
#pragma unroll
                for (int mi = 0; mi < 4; ++mi) acc[mi][ni] = MFMA16(af[mi], bw, acc[mi][ni]);
            }
        }
#pragma unroll
        for (int ni = 0; ni < 2; ++ni) {
            int col = (2*wid + ni)*16 + (l & 15);
#pragma unroll
            for (int mi = 0; mi < 4; ++mi) {
                int R = mi*16 + ((l >> 4) << 2);
                storeQuad((u32*)chunkB, R, col, l,
                          acc[mi][ni][0]*sDi[R], acc[mi][ni][1]*sDi[R+1],
                          acc[mi][ni][2]*sDi[R+2], acc[mi][ni][3]*sDi[R+3]);
            }
        }
    }
    __syncthreads();
    copyChunkOut((const u32*)chunkB, xw1p, n0, t);
}

// ---------------------------------------------------------------------------
// GCN layer 1: gather bf16 xw1p (prescaled), relu(+g1b), MFMA @g2w, *dinv -> xw2p
// ---------------------------------------------------------------------------
__global__ __launch_bounds__(256, 4)
void gcn_agg1_mfma(const u16* __restrict__ xw1p, const int* __restrict__ rp,
                   const int* __restrict__ sadj, const float* __restrict__ dinv,
                   const float* __restrict__ g1b, const u16* __restrict__ g2p,
                   u32* __restrict__ xw2p)
{
    __shared__ u16 chunkA[64*HD];
    __shared__ u16 chunkB[64*HD];
    __shared__ float sDi[64];
    __shared__ float sB[HD];

    const int t = threadIdx.x;
    const int l = t & 63;
    const int wid = t >> 6;
    const int n0 = blockIdx.x * 64;

    if (t < 64)  sDi[t] = (n0 + t < NN) ? dinv[n0 + t] : 0.f;
    if (t < HD)  sB[t] = g1b[t];
    __syncthreads();

    {
        int s = t >> 2, part = t & 3, n = n0 + s;
        float acc[32];
#pragma unroll
        for (int j = 0; j < 32; ++j) acc[j] = 0.f;
        float di = 0.f;
        if (n < NN) {
            di = sDi[s];
            const short8* selfp = (const short8*)(xw1p + (size_t)n*HD + part*32);
#pragma unroll
            for (int w = 0; w < 4; ++w) {
                short8 v = selfp[w];
#pragma unroll
                for (int j = 0; j < 8; ++j) acc[w*8+j] += bf2f((u16)v[j]);
            }
            int k1 = rp[n+1];
            for (int k = rp[n]; k < k1; ++k) {
                const short8* rp8 = (const short8*)(xw1p + (size_t)sadj[k]*HD + part*32);
#pragma unroll
                for (int w = 0; w < 4; ++w) {
                    short8 v = rp8[w];
#pragma unroll
                    for (int j = 0; j < 8; ++j) acc[w*8+j] += bf2f((u16)v[j]);
                }
            }
        }
#pragma unroll
        for (int p = 0; p < 16; ++p) {
            float v0 = fmaxf(fmaf(acc[2*p],   di, sB[part*32 + 2*p]),   0.f);
            float v1 = fmaxf(fmaf(acc[2*p+1], di, sB[part*32 + 2*p+1]), 0.f);
            int cw = part*16 + p;
            ((u32*)chunkA)[s*64 + (((cw >> 2) ^ (s & 7)) << 2) + (cw & 3)] = cvtpk(v0, v1);
        }
    }
    __syncthreads();

    {
        f32x4 acc[4][2];
#pragma unroll
        for (int mi = 0; mi < 4; ++mi)
#pragma unroll
            for (int ni = 0; ni < 2; ++ni) acc[mi][ni] = (f32x4){0.f,0.f,0.f,0.f};
#pragma unroll
        for (int kk = 0; kk < 4; ++kk) {
            short8 af[4];
#pragma unroll
            for (int mi = 0; mi < 4; ++mi) af[mi] = loadA(chunkA, mi, kk, l);
#pragma unroll
            for (int ni = 0; ni < 2; ++ni) {
                short8 bw = loadB(g2p, 2*wid + ni, kk, 4, l);
#pragma unroll
                for (int mi = 0; mi < 4; ++mi) acc[mi][ni] = MFMA16(af[mi], bw, acc[mi][ni]);
            }
        }
#pragma unroll
        for (int ni = 0; ni < 2; ++ni) {
            int col = (2*wid + ni)*16 + (l & 15);
#pragma unroll
            for (int mi = 0; mi < 4; ++mi) {
                int R = mi*16 + ((l >> 4) << 2);
                storeQuad((u32*)chunkB, R, col, l,
                          acc[mi][ni][0]*sDi[R], acc[mi][ni][1]*sDi[R+1],
                          acc[mi][ni][2]*sDi[R+2], acc[mi][ni][3]*sDi[R+3]);
            }
        }
    }
    __syncthreads();
    copyChunkOut((const u32*)chunkB, xw2p, n0, t);
}

// ---------------------------------------------------------------------------
// GCN layer 2: gather bf16 xw2p, +g2b -> h2 (fp32) + hbf (bf16)
// ---------------------------------------------------------------------------
__global__ __launch_bounds__(256)
void gcn_agg2_gather(const u16* __restrict__ xw2p, const int* __restrict__ rp,
                     const int* __restrict__ sadj, const float* __restrict__ dinv,
                     const float* __restrict__ g2b, float* __restrict__ h2,
                     u32* __restrict__ hbw)
{
    int t = threadIdx.x;
    int s = t >> 2, part = t & 3;
    int n = blockIdx.x * 64 + s;
    if (n >= NN) return;
    float acc[32];
#pragma unroll
    for (int j = 0; j < 32; ++j) acc[j] = 0.f;
    const short8* selfp = (const short8*)(xw2p + (size_t)n*HD + part*32);
#pragma unroll
    for (int w = 0; w < 4; ++w) {
        short8 v = selfp[w];
#pragma unroll
        for (int j = 0; j < 8; ++j) acc[w*8+j] += bf2f((u16)v[j]);
    }
    int k1 = rp[n+1];
    for (int k = rp[n]; k < k1; ++k) {
        const short8* rp8 = (const short8*)(xw2p + (size_t)sadj[k]*HD + part*32);
#pragma unroll
        for (int w = 0; w < 4; ++w) {
            short8 v = rp8[w];
#pragma unroll
            for (int j = 0; j < 8; ++j) acc[w*8+j] += bf2f((u16)v[j]);
        }
    }
    float di = dinv[n];
    float* ho = h2 + (size_t)n*HD + part*32;
    u32* hb = hbw + (size_t)n*64 + part*16;
#pragma unroll
    for (int p = 0; p < 16; ++p) {
        float v0 = fmaf(acc[2*p],   di, g2b[part*32 + 2*p]);
        float v1 = fmaf(acc[2*p+1], di, g2b[part*32 + 2*p+1]);
        ho[2*p] = v0; ho[2*p+1] = v1;
        hb[p] = cvtpk(v0, v1);
    }
}

// ---------------------------------------------------------------------------
// Pool + counts + graph MLP
// ---------------------------------------------------------------------------
#define POOL_B 512
__global__ __launch_bounds__(128)
void pool_sorted(const float* __restrict__ h, const int* __restrict__ batch,
                 float* __restrict__ sums)
{
    int b = blockIdx.x, j = threadIdx.x;
    int n0 = (int)(((long long)NN * b) / POOL_B);
    int n1 = (int)(((long long)NN * (b+1)) / POOL_B);
    int g = -1; float acc = 0.f;
    for (int n = n0; n < n1; ++n) {
        int bg = batch[n];
        if (bg != g) {
            if (g >= 0) atomicAdd(&sums[g*HD + j], acc);
            g = bg; acc = 0.f;
        }
        acc += h[n*HD + j];
    }
    if (g >= 0) atomicAdd(&sums[g*HD + j], acc);
}

__global__ __launch_bounds__(256)
void cnt_k(const int* __restrict__ batch, float* __restrict__ cnts)
{
    int n = blockIdx.x*256 + threadIdx.x;
    if (n < NN) atomicAdd(&cnts[batch[n]], 1.f);
}

__global__ __launch_bounds__(128)
void graph_feat(const float* __restrict__ sums, const float* __restrict__ cnts,
                const float* __restrict__ w1, const float* __restrict__ b1,
                const float* __restrict__ w2, const float* __restrict__ b2,
                const float* __restrict__ gg, const float* __restrict__ bb,
                u16* __restrict__ gf16)
{
    int gi = blockIdx.x, j = threadIdx.x;
    __shared__ float s0[HD];
    __shared__ float s1[HD];
    __shared__ float part[4];
    __shared__ float stat[2];
    float cnt = fmaxf(cnts[gi], 1.f);
    s0[j] = sums[gi*HD + j] / cnt;
    __syncthreads();
    float a = b1[j];
    for (int i = 0; i < HD; ++i) a = fmaf(s0[i], w1[i*HD + j], a);
    s1[j] = fmaxf(a, 0.f);
    __syncthreads();
    a = b2[j];
    for (int i = 0; i < HD; ++i) a = fmaf(s1[i], w2[i*HD + j], a);
    float s = a, q = a*a;
    for (int o = 32; o > 0; o >>= 1) { s += __shfl_down(s, o); q += __shfl_down(q, o); }
    int wid = j >> 6, lane = j & 63;
    if (lane == 0) { part[wid] = s; part[2 + wid] = q; }
    __syncthreads();
    if (j == 0) {
        float S = part[0] + part[1], Q = part[2] + part[3];
        float mu = S * (1.f/HD);
        stat[0] = mu;
        stat[1] = Q * (1.f/HD) - mu*mu;
    }
    __syncthreads();
    float v = (a - stat[0]) * rsqrtf(stat[1] + LN_EPS) * gg[j] + bb[j];
    gf16[gi*HD + j] = f2bf(v);
}

// ---------------------------------------------------------------------------
// Fused edge kernel (MFMA bf16). 64 edges/block, 256 threads, 2 blocks/CU.
// Gathers prefetched into registers at kernel start (T14).
// ---------------------------------------------------------------------------
__global__ __launch_bounds__(256, 2)
void edge_mlp_mfma(const u16* __restrict__ hbf, const u16* __restrict__ gfbf,
                   const int* __restrict__ ei, const int* __restrict__ batch,
                   const float* __restrict__ ea,
                   const float* __restrict__ ew1, const float* __restrict__ eb1,
                   const u16* __restrict__ ew2p, const float* __restrict__ eb2,
                   const u16* __restrict__ ew3p, const float* __restrict__ eb3,
                   const float* __restrict__ egm, const float* __restrict__ ebb,
                   const u16* __restrict__ p1wp, const float* __restrict__ p1b,
                   const u16* __restrict__ p2wp, const float* __restrict__ p2b,
                   const u16* __restrict__ p3wp, const float* __restrict__ p3b,
                   const float* __restrict__ p4w, const float* __restrict__ p4b,
                   float* __restrict__ out)
{
    __shared__ u16 bufChunk[64*HD];    // 16KB swizzled A-chunk
    __shared__ u16 bufWide[64*256];    // 32KB (2 chunks / fp32 scratch)
    __shared__ float sEa[192];
    __shared__ float rstat[128];

    const int t = threadIdx.x;
    const int l = t & 63;
    const int wid = t >> 6;
    const int e0 = blockIdx.x * 64;

    // ---- prefetch gathers into registers (hidden under encoder compute) ----
    const int eRow = t >> 2, part = t & 3;
    int srcN = ei[e0 + eRow];
    int dstN = ei[NE + e0 + eRow];
    int gfN  = batch[srcN];
    short8 rs[4], rd[4], rg[4];
    {
        const short8* ps = (const short8*)(hbf  + (size_t)srcN*HD + part*32);
        const short8* pd = (const short8*)(hbf  + (size_t)dstN*HD + part*32);
        const short8* pg = (const short8*)(gfbf + (size_t)gfN *HD + part*32);
#pragma unroll
        for (int w = 0; w < 4; ++w) { rs[w] = ps[w]; rd[w] = pd[w]; rg[w] = pg[w]; }
    }

    if (t < 192) sEa[t] = ea[e0*3 + t];
    __syncthreads();

    // ---- enc1: relu(ea@ew1+b1) -> bufChunk ----
    for (int it = 0; it < 16; ++it) {
        int dw = it*256 + t;
        int e = dw >> 6, cd = dw & 63;
        int c0 = cd*2;
        float x0 = sEa[e*3], x1 = sEa[e*3+1], x2 = sEa[e*3+2];
        float v0 = eb1[c0]   + x0*ew1[c0]   + x1*ew1[HD+c0]   + x2*ew1[2*HD+c0];
        float v1 = eb1[c0+1] + x0*ew1[c0+1] + x1*ew1[HD+c0+1] + x2*ew1[2*HD+c0+1];
        v0 = fmaxf(v0, 0.f); v1 = fmaxf(v1, 0.f);
        int ci = cd >> 2;
        ((u32*)bufChunk)[e*64 + ((ci ^ (e & 7)) << 2) + (cd & 3)] = cvtpk(v0, v1);
    }
    __syncthreads();

    // ---- enc2: relu(A@ew2+b2) -> bufWide chunk0 ----
    {
        f32x4 acc[4][2];
#pragma unroll
        for (int ni = 0; ni < 2; ++ni) {
            float b = eb2[(2*wid + ni)*16 + (l & 15)];
#pragma unroll
            for (int mi = 0; mi < 4; ++mi) acc[mi][ni] = (f32x4){b,b,b,b};
        }
#pragma unroll
        for (int kk = 0; kk < 4; ++kk) {
            short8 af[4];
#pragma unroll
            for (int mi = 0; mi < 4; ++mi) af[mi] = loadA(bufChunk, mi, kk, l);
#pragma unroll
            for (int ni = 0; ni < 2; ++ni) {
                short8 bw = loadB(ew2p, 2*wid + ni, kk, 4, l);
#pragma unroll
                for (int mi = 0; mi < 4; ++mi) acc[mi][ni] = MFMA16(af[mi], bw, acc[mi][ni]);
            }
        }
#pragma unroll
        for (int ni = 0; ni < 2; ++ni) {
            int col = (2*wid + ni)*16 + (l & 15);
#pragma unroll
            for (int mi = 0; mi < 4; ++mi) {
                int R = mi*16 + ((l >> 4) << 2);
                storeQuad((u32*)bufWide, R, col, l,
                          fmaxf(acc[mi][ni][0], 0.f), fmaxf(acc[mi][ni][1], 0.f),
                          fmaxf(acc[mi][ni][2], 0.f), fmaxf(acc[mi][ni][3], 0.f));
            }
        }
    }
    __syncthreads();

    // ---- enc3: W0@ew3+b3 (pre-LN) -> bufChunk ----
    {
        f32x4 acc[4][2];
#pragma unroll
        for (int ni = 0; ni < 2; ++ni) {
            float b = eb3[(2*wid + ni)*16 + (l & 15)];
#pragma unroll
            for (int mi = 0; mi < 4; ++mi) acc[mi][ni] = (f32x4){b,b,b,b};
        }
#pragma unroll
        for (int kk = 0; kk < 4; ++kk) {
            short8 af[4];
#pragma unroll
            for (int mi = 0; mi < 4; ++mi) af[mi] = loadA(bufWide, mi, kk, l);
#pragma unroll
            for (int ni = 0; ni < 2; ++ni) {
                short8 bw = loadB(ew3p, 2*wid + ni, kk, 4, l);
#pragma unroll
                for (int mi = 0; mi < 4; ++mi) acc[mi][ni] = MFMA16(af[mi], bw, acc[mi][ni]);
            }
        }
#pragma unroll
        for (int ni = 0; ni < 2; ++ni) {
            int col = (2*wid + ni)*16 + (l & 15);
#pragma unroll
            for (int mi = 0; mi < 4; ++mi) {
                int R = mi*16 + ((l >> 4) << 2);
                storeQuad((u32*)bufChunk, R, col, l,
                          acc[mi][ni][0], acc[mi][ni][1], acc[mi][ni][2], acc[mi][ni][3]);
            }
        }
    }
    __syncthreads();

    // ---- write prefetched h[src]/h[dst] to bufWide (enc2 data dead) ----
    {
        u16* drow0 = bufWide + eRow*128;
        u16* drow1 = bufWide + 8192 + eRow*128;
        int re = eRow & 7;
#pragma unroll
        for (int w = 0; w < 4; ++w) {
            int ci = (part*4 + w) ^ re;
            *(short8*)(drow0 + (ci << 3)) = rs[w];
            *(short8*)(drow1 + (ci << 3)) = rd[w];
        }
    }

    // ---- LN stats: 4 lanes per edge, rotated read (bank-spread) ----
    {
        int e = wid*16 + (l >> 2);
        int q = l & 3;
        const u32* rowp = (const u32*)bufChunk + e*64;
        float s = 0.f, sq = 0.f;
#pragma unroll
        for (int i = 0; i < 16; ++i) {
            u32 pk = rowp[q*16 + ((i + e) & 15)];
            float a = bf2f(pk & 0xffffu), b = bf2f(pk >> 16);
            s += a + b;
            sq = fmaf(a, a, fmaf(b, b, sq));
        }
        s  += __shfl_xor(s, 1);  sq += __shfl_xor(sq, 1);
        s  += __shfl_xor(s, 2);  sq += __shfl_xor(sq, 2);
        if (q == 0) {
            float mu = s * (1.f/HD);
            rstat[e] = mu;
            rstat[64 + e] = rsqrtf(sq*(1.f/HD) - mu*mu + LN_EPS);
        }
    }
    __syncthreads();

    // ---- normalize in place: bufChunk = ef ----
    for (int it = 0; it < 16; ++it) {
        int pd = it*256 + t;
        int row = pd >> 6, cwd = pd & 63;
        int ci = (cwd >> 2) ^ (row & 7);
        int col = ci*8 + (cwd & 3)*2;
        u32 pk = ((u32*)bufChunk)[pd];
        float mu = rstat[row], ri = rstat[64 + row];
        float v0 = (bf2f(pk & 0xffffu) - mu)*ri*egm[col]     + ebb[col];
        float v1 = (bf2f(pk >> 16)     - mu)*ri*egm[col + 1] + ebb[col + 1];
        ((u32*)bufChunk)[pd] = cvtpk(v0, v1);
    }
    __syncthreads();

    // ---- ep1 MFMA: ef (ks 12..15), hsrc (ks 0..3), hdst (ks 4..7) ----
    f32x4 acc1[4][4];
#pragma unroll
    for (int ni = 0; ni < 4; ++ni) {
        float b = p1b[(4*wid + ni)*16 + (l & 15)];
#pragma unroll
        for (int mi = 0; mi < 4; ++mi) acc1[mi][ni] = (f32x4){b,b,b,b};
    }
#pragma unroll
    for (int kk = 0; kk < 4; ++kk) {
        short8 af[4];
#pragma unroll
        for (int mi = 0; mi < 4; ++mi) af[mi] = loadA(bufChunk, mi, kk, l);
#pragma unroll
        for (int ni = 0; ni < 4; ++ni) {
            short8 bw = loadB(p1wp, 4*wid + ni, 12 + kk, 16, l);
#pragma unroll
            for (int mi = 0; mi < 4; ++mi) acc1[mi][ni] = MFMA16(af[mi], bw, acc1[mi][ni]);
        }
    }
#pragma unroll
    for (int kk = 0; kk < 4; ++kk) {
        short8 af[4];
#pragma unroll
        for (int mi = 0; mi < 4; ++mi) af[mi] = loadA(bufWide, mi, kk, l);
#pragma unroll
        for (int ni = 0; ni < 4; ++ni) {
            short8 bw = loadB(p1wp, 4*wid + ni, kk, 16, l);
#pragma unroll
            for (int mi = 0; mi < 4; ++mi) acc1[mi][ni] = MFMA16(af[mi], bw, acc1[mi][ni]);
        }
    }
#pragma unroll
    for (int kk = 0; kk < 4; ++kk) {
        short8 af[4];
#pragma unroll
        for (int mi = 0; mi < 4; ++mi) af[mi] = loadA(bufWide + 8192, mi, kk, l);
#pragma unroll
        for (int ni = 0; ni < 4; ++ni) {
            short8 bw = loadB(p1wp, 4*wid + ni, 4 + kk, 16, l);
#pragma unroll
            for (int mi = 0; mi < 4; ++mi) acc1[mi][ni] = MFMA16(af[mi], bw, acc1[mi][ni]);
        }
    }
    __syncthreads();

    // ---- write prefetched gf -> bufChunk (ef dead), MFMA (ks 8..11) ----
    {
        u16* drow = bufChunk + eRow*128;
        int re = eRow & 7;
#pragma unroll
        for (int w = 0; w < 4; ++w) {
            int ci = (part*4 + w) ^ re;
            *(short8*)(drow + (ci << 3)) = rg[w];
        }
    }
    __syncthreads();
#pragma unroll
    for (int kk = 0; kk < 4; ++kk) {
        short8 af[4];
#pragma unroll
        for (int mi = 0; mi < 4; ++mi) af[mi] = loadA(bufChunk, mi, kk, l);
#pragma unroll
        for (int ni = 0; ni < 4; ++ni) {
            short8 bw = loadB(p1wp, 4*wid + ni, 8 + kk, 16, l);
#pragma unroll
            for (int mi = 0; mi < 4; ++mi) acc1[mi][ni] = MFMA16(af[mi], bw, acc1[mi][ni]);
        }
    }
#pragma unroll
    for (int ni = 0; ni < 4; ++ni) {
        int col = (4*wid + ni)*16 + (l & 15);
        u32* dst = (u32*)bufWide + ((col >> 7) << 12);
        int cc = col & 127;
#pragma unroll
        for (int mi = 0; mi < 4; ++mi) {
            int R = mi*16 + ((l >> 4) << 2);
            storeQuad(dst, R, cc, l,
                      fast_tanh(acc1[mi][ni][0]), fast_tanh(acc1[mi][ni][1]),
                      fast_tanh(acc1[mi][ni][2]), fast_tanh(acc1[mi][ni][3]));
        }
    }
    __syncthreads();

    // ---- ep2: [64,256]@p2w[256,128], tanh -> bufChunk ----
    {
        f32x4 acc[4][2];
#pragma unroll
        for (int ni = 0; ni < 2; ++ni) {
            float b = p2b[(2*wid + ni)*16 + (l & 15)];
#pragma unroll
            for (int mi = 0; mi < 4; ++mi) acc[mi][ni] = (f32x4){b,b,b,b};
        }
        for (int kc = 0; kc < 2; ++kc) {
            const u16* abuf = bufWide + (kc << 13);
#pragma unroll
            for (int kk = 0; kk < 4; ++kk) {
                short8 af[4];
#pragma unroll
                for (int mi = 0; mi < 4; ++mi) af[mi] = loadA(abuf, mi, kk, l);
                int ks = kc*4 + kk;
#pragma unroll
                for (int ni = 0; ni < 2; ++ni) {
                    short8 bw = loadB(p2wp, 2*wid + ni, ks, 8, l);
#pragma unroll
                    for (int mi = 0; mi < 4; ++mi) acc[mi][ni] = MFMA16(af[mi], bw, acc[mi][ni]);
                }
            }
        }
#pragma unroll
        for (int ni = 0; ni < 2; ++ni) {
            int col = (2*wid + ni)*16 + (l & 15);
#pragma unroll
            for (int mi = 0; mi < 4; ++mi) {
                int R = mi*16 + ((l >> 4) << 2);
                storeQuad((u32*)bufChunk, R, col, l,
                          fast_tanh(acc[mi][ni][0]), fast_tanh(acc[mi][ni][1]),
                          fast_tanh(acc[mi][ni][2]), fast_tanh(acc[mi][ni][3]));
            }
        }
    }
    __syncthreads();

    // ---- ep3: [64,128]@p3w[128,64], relu -> bufWide fp32 stride-65 ----
    {
        f32x4 acc[4];
        {
            float b = p3b[wid*16 + (l & 15)];
#pragma unroll
            for (int mi = 0; mi < 4; ++mi) acc[mi] = (f32x4){b,b,b,b};
        }
#pragma unroll
        for (int kk = 0; kk < 4; ++kk) {
            short8 af[4];
#pragma unroll
            for (int mi = 0; mi < 4; ++mi) af[mi] = loadA(bufChunk, mi, kk, l);
            short8 bw = loadB(p3wp, wid, kk, 4, l);
#pragma unroll
            for (int mi = 0; mi < 4; ++mi) acc[mi] = MFMA16(af[mi], bw, acc[mi]);
        }
        float* fb = (float*)bufWide;
        int col = wid*16 + (l & 15);
#pragma unroll
        for (int mi = 0; mi < 4; ++mi)
#pragma unroll
            for (int rr = 0; rr < 4; ++rr) {
                int row = mi*16 + ((l >> 4) << 2) + rr;
                fb[row*65 + col] = fmaxf(acc[mi][rr], 0.f);
            }
    }
    __syncthreads();

    // ---- ep4: 4 lanes/edge dot-64 + sigmoid ----
    {
        const float* fb = (const float*)bufWide;
        int e = wid*16 + (l >> 2), q = l & 3;
        float v = 0.f;
#pragma unroll
        for (int k = 0; k < 16; ++k) {
            int i = q*16 + k;
            v = fmaf(fb[e*65 + i], p4w[i], v);
        }
        v += __shfl_xor(v, 1);
        v += __shfl_xor(v, 2);
        if (q == 0) out[e0 + e] = fast_sigmoid(v + p4b[0]);
    }
}

// ---------------------------------------------------------------------------
extern "C" void kernel_launch(void* const* d_in, const int* in_sizes, int n_in,
                              void* d_out, int out_size, void* d_ws, size_t ws_size,
                              hipStream_t stream)
{
    const float* x     = (const float*)d_in[0];
    const int*   ei    = (const int*)  d_in[1];
    const float* ea    = (const float*)d_in[2];
    const int*   batch = (const int*)  d_in[3];
    const float* ne1w = (const float*)d_in[4];  const float* ne1b = (const float*)d_in[5];
    const float* ne2w = (const float*)d_in[6];  const float* ne2b = (const float*)d_in[7];
    const float* ne3w = (const float*)d_in[8];  const float* ne3b = (const float*)d_in[9];
    const float* neg  = (const float*)d_in[10]; const float* nebb = (const float*)d_in[11];
    const float* ee1w = (const float*)d_in[12]; const float* ee1b = (const float*)d_in[13];
    const float* ee2w = (const float*)d_in[14]; const float* ee2b = (const float*)d_in[15];
    const float* ee3w = (const float*)d_in[16]; const float* ee3b = (const float*)d_in[17];
    const float* eeg  = (const float*)d_in[18]; const float* eebb = (const float*)d_in[19];
    const float* g1w  = (const float*)d_in[20]; const float* g1b  = (const float*)d_in[21];
    const float* g2w  = (const float*)d_in[22]; const float* g2b  = (const float*)d_in[23];
    const float* gp1w = (const float*)d_in[24]; const float* gp1b = (const float*)d_in[25];
    const float* gp2w = (const float*)d_in[26]; const float* gp2b = (const float*)d_in[27];
    const float* gpg  = (const float*)d_in[28]; const float* gpbb = (const float*)d_in[29];
    const float* p1w  = (const float*)d_in[30]; const float* p1b  = (const float*)d_in[31];
    const float* p2w  = (const float*)d_in[32]; const float* p2b  = (const float*)d_in[33];
    const float* p3w  = (const float*)d_in[34]; const float* p3b  = (const float*)d_in[35];
    const float* p4w  = (const float*)d_in[36]; const float* p4b  = (const float*)d_in[37];

    float* h2   = (float*)d_ws;                // NN*HD fp32
    float* dinv = h2 + (size_t)NN*HD;          // NN
    float* sums = dinv + NN;                   // NG*HD
    float* cnts = sums + NG*HD;                // NG
    int* degi   = (int*)(cnts + NG);           // NN
    int* cursor = degi + NN;                   // NN+2
    int* rowptr = cursor + NN + 2;             // NN+2
    int* sadj   = rowptr + NN + 2;             // NE
    u16* xw1p   = (u16*)(sadj + NE);           // NN*HD
    u16* xw2p   = xw1p + (size_t)NN*HD;        // NN*HD
    u16* hbf    = xw2p + (size_t)NN*HD;        // NN*HD
    u16* gf16   = hbf + (size_t)NN*HD;         // NG*HD
    u16* wpk    = gf16 + NG*HD;                // 270336
    u16* ee2p = wpk;
    u16* ee3p = wpk + 16384;
    u16* p1p  = wpk + 32768;
    u16* p2p  = wpk + 163840;
    u16* p3p  = wpk + 196608;
    u16* ne2p = wpk + 204800;
    u16* ne3p = wpk + 221184;
    u16* g1p  = wpk + 237568;
    u16* g2p  = wpk + 253952;

    float* out = (float*)d_out;

    hipMemsetAsync(degi, 0, (size_t)(2*NN + 2)*sizeof(int), stream);
    hipMemsetAsync(sums, 0, (size_t)(NG*HD + NG)*sizeof(float), stream);

    pack_all<<<(270336 + 255)/256, 256, 0, stream>>>(ee2w, ee3w, p1w, p2w, p3w,
                                                     ne2w, ne3w, g1w, g2w, wpk);

    // CSR build
    deg_count_int<<<(NE + 255)/256, 256, 0, stream>>>(ei, degi);
    dinv_k<<<(NN + 255)/256, 256, 0, stream>>>(degi, dinv);
    scan_excl<<<1, 1024, 0, stream>>>(degi, rowptr);
    fill_csr<<<(NE + 255)/256, 256, 0, stream>>>(ei, rowptr, cursor, sadj);

    // node encoder + g1 GEMM (bf16 out, prescaled by dinv)
    enc_mfma<<<(NN + 63)/64, 256, 0, stream>>>(x, ne1w, ne1b, ne2p, ne2b, ne3p, ne3b,
                                               neg, nebb, g1p, dinv, (u32*)xw1p);
    // GCN1 gather + relu + g2 GEMM
    gcn_agg1_mfma<<<(NN + 63)/64, 256, 0, stream>>>(xw1p, rowptr, sadj, dinv,
                                                    g1b, g2p, (u32*)xw2p);
    // GCN2 gather -> h2 fp32 + hbf bf16
    gcn_agg2_gather<<<(NN + 63)/64, 256, 0, stream>>>(xw2p, rowptr, sadj, dinv,
                                                      g2b, h2, (u32*)hbf);

    // pool + graph MLP
    pool_sorted<<<POOL_B, 128, 0, stream>>>(h2, batch, sums);
    cnt_k<<<(NN + 255)/256, 256, 0, stream>>>(batch, cnts);
    graph_feat<<<NG, 128, 0, stream>>>(sums, cnts, gp1w, gp1b, gp2w, gp2b,
                                       gpg, gpbb, gf16);

    // fused edge encoder + edge-score MLP
    edge_mlp_mfma<<<NE/64, 256, 0, stream>>>(hbf, gf16, ei, batch, ea,
                                             ee1w, ee1b, ee2p, ee2b, ee3p, ee3b,
                                             eeg, eebb,
                                             p1p, p1b, p2p, p2b, p3p, p3b,
                                             p4w, p4b, out);
}

// Round 6
// 665.597 us; speedup vs baseline: 7.7158x; 1.1411x over previous
//
#include <hip/hip_runtime.h>
#include <math.h>

#define NN 50000
#define NE 400000
#define NG 64
#define HD 128
#define LN_EPS 1e-5f

typedef unsigned short u16;
typedef unsigned int u32;
typedef __attribute__((ext_vector_type(8))) short short8;
typedef __attribute__((ext_vector_type(4))) float f32x4;

#define MFMA16(a,b,c) __builtin_amdgcn_mfma_f32_16x16x32_bf16((a),(b),(c),0,0,0)

__device__ __forceinline__ u16 f2bf(float f) {
    union { float f; u32 u; } v; v.f = f;
    u32 r = v.u + 0x7FFFu + ((v.u >> 16) & 1u);
    return (u16)(r >> 16);
}
__device__ __forceinline__ float bf2f(u32 hs) {
    union { u32 u; float f; } v; v.u = hs << 16;
    return v.f;
}
__device__ __forceinline__ float fast_rcp(float x) {
    float r; asm("v_rcp_f32 %0, %1" : "=v"(r) : "v"(x)); return r;
}
__device__ __forceinline__ float fast_exp2(float x) {
    float r; asm("v_exp_f32 %0, %1" : "=v"(r) : "v"(x)); return r;
}
__device__ __forceinline__ u32 cvtpk(float lo, float hi) {
    u32 r; asm("v_cvt_pk_bf16_f32 %0, %1, %2" : "=v"(r) : "v"(lo), "v"(hi)); return r;
}
// tanh(x) = 1 - 2/(1+2^(2*log2e*x)); exp2 saturates correctly at +-inf
__device__ __forceinline__ float fast_tanh(float x) {
    return fmaf(-2.f, fast_rcp(1.f + fast_exp2(2.885390082f * x)), 1.f);
}
__device__ __forceinline__ float fast_sigmoid(float x) {
    return fast_rcp(1.f + fast_exp2(-1.442695041f * x));
}

// swizzle term: bits {row&7} ^ bit1-from-row-bit3 -> spreads storeQuad writes
// across all 32 banks (2-way) while keeping loadA at 2-way.
__device__ __forceinline__ int swzr(int row) {
    return (row & 7) ^ ((row & 8) >> 2);
}

// A-fragment load from swizzled [64][128] bf16 chunk buffer.
__device__ __forceinline__ short8 loadA(const u16* buf, int mi, int kk, int l) {
    int row = mi*16 + (l & 15);
    int ci  = (kk*4 + (l >> 4)) ^ swzr(l & 15);   // row&15 == l&15 here
    return *(const short8*)(buf + row*128 + (ci << 3));
}
__device__ __forceinline__ short8 loadB(const u16* wp, int nt, int ks, int nk, int l) {
    return *(const short8*)(wp + (((nt*nk + ks)*64 + l) << 3));
}

// Store 4 accumulator values (rows R..R+3, col c) into swizzled bf16 chunk as
// packed u32 via lane-pair exchange + v_cvt_pk_bf16_f32.
__device__ __forceinline__ void storeQuad(u32* buf, int R, int c, int l,
                                          float v0, float v1, float v2, float v3)
{
    int cw = c >> 1;
    int par = l & 1;
    float send = par ? v0 : v1;
    float recv = __shfl_xor(send, 1);
    int row = R + par;
    u32 word = par ? cvtpk(recv, v1) : cvtpk(v0, recv);
    buf[row*64 + (((cw >> 2) ^ swzr(row & 15)) << 2) + (cw & 3)] = word;
    send = par ? v2 : v3;
    recv = __shfl_xor(send, 1);
    row = R + 2 + par;
    word = par ? cvtpk(recv, v3) : cvtpk(v2, recv);
    buf[row*64 + (((cw >> 2) ^ swzr(row & 15)) << 2) + (cw & 3)] = word;
}

// Unswizzle copy: LDS chunk -> global bf16 [64][128] rows n0..n0+63 (u32 words)
__device__ __forceinline__ void copyChunkOut(const u32* chunk, u32* gout, int n0, int t)
{
    for (int it = 0; it < 16; ++it) {
        int dw = it*256 + t;
        int row = dw >> 6, cw = dw & 63;
        if (n0 + row < NN)
            gout[(size_t)(n0 + row)*64 + cw] =
                chunk[row*64 + (((cw >> 2) ^ swzr(row & 15)) << 2) + (cw & 3)];
    }
}

// ---------------------------------------------------------------------------
// One-shot weight packing of all 9 GEMM weights -> bf16 MFMA B-fragment order.
// ---------------------------------------------------------------------------
__global__ __launch_bounds__(256)
void pack_all(const float* __restrict__ ee2w, const float* __restrict__ ee3w,
              const float* __restrict__ p1w,  const float* __restrict__ p2w,
              const float* __restrict__ p3w,  const float* __restrict__ ne2w,
              const float* __restrict__ ne3w, const float* __restrict__ g1w,
              const float* __restrict__ g2w,  u16* __restrict__ wpk)
{
    int idx = blockIdx.x*256 + threadIdx.x;
    if (idx >= 270336) return;
    const float* w; int K, N, local;
    if      (idx < 16384)  { w = ee2w; K = 128; N = 128; local = idx; }
    else if (idx < 32768)  { w = ee3w; K = 128; N = 128; local = idx - 16384; }
    else if (idx < 163840) { w = p1w;  K = 512; N = 256; local = idx - 32768; }
    else if (idx < 196608) { w = p2w;  K = 256; N = 128; local = idx - 163840; }
    else if (idx < 204800) { w = p3w;  K = 128; N = 64;  local = idx - 196608; }
    else if (idx < 221184) { w = ne2w; K = 128; N = 128; local = idx - 204800; }
    else if (idx < 237568) { w = ne3w; K = 128; N = 128; local = idx - 221184; }
    else if (idx < 253952) { w = g1w;  K = 128; N = 128; local = idx - 237568; }
    else                   { w = g2w;  K = 128; N = 128; local = idx - 253952; }
    int e = local & 7, l = (local >> 3) & 63, r = local >> 9;
    int nk = K >> 5;
    int nt = r / nk, kk = r % nk;
    int k = kk*32 + ((l >> 4) << 3) + e;
    int n = nt*16 + (l & 15);
    wpk[idx] = f2bf(w[k*N + n]);
}

// ---------------------------------------------------------------------------
// CSR build
// ---------------------------------------------------------------------------
__global__ __launch_bounds__(256)
void deg_count_int(const int* __restrict__ ei, int* __restrict__ degi)
{
    int e = blockIdx.x*256 + threadIdx.x;
    if (e < NE) atomicAdd(&degi[ei[NE + e]], 1);
}

__global__ __launch_bounds__(1024)
void scan_excl(const int* __restrict__ cnt, int* __restrict__ rp,
               float* __restrict__ dinv)
{
    __shared__ int wsum[16];
    __shared__ int carry;
    int t = threadIdx.x, lane = t & 63, w = t >> 6;
    int base = 0;
    for (int off = 0; off < NN; off += 4096) {
        int i0 = off + t*4;
        int v0 = (i0   < NN) ? cnt[i0]   : 0;
        int v1 = (i0+1 < NN) ? cnt[i0+1] : 0;
        int v2 = (i0+2 < NN) ? cnt[i0+2] : 0;
        int v3 = (i0+3 < NN) ? cnt[i0+3] : 0;
        int tot = v0 + v1 + v2 + v3;
        int s = tot;
#pragma unroll
        for (int d = 1; d < 64; d <<= 1) { int u = __shfl_up(s, d); if (lane >= d) s += u; }
        if (lane == 63) wsum[w] = s;
        __syncthreads();
        if (w == 0) {
            int wv = (lane < 16) ? wsum[lane] : 0;
            int ss = wv;
#pragma unroll
            for (int d = 1; d < 16; d <<= 1) { int u = __shfl_up(ss, d); if (lane >= d) ss += u; }
            if (lane < 16) wsum[lane] = ss - wv;
            if (lane == 15) carry = ss;
        }
        __syncthreads();
        int excl = base + wsum[w] + s - tot;
        if (i0   < NN) { rp[i0]   = excl;              dinv[i0]   = rsqrtf((float)v0 + 1.f); }
        if (i0+1 < NN) { rp[i0+1] = excl + v0;         dinv[i0+1] = rsqrtf((float)v1 + 1.f); }
        if (i0+2 < NN) { rp[i0+2] = excl + v0 + v1;    dinv[i0+2] = rsqrtf((float)v2 + 1.f); }
        if (i0+3 < NN) { rp[i0+3] = excl + v0 + v1 + v2; dinv[i0+3] = rsqrtf((float)v3 + 1.f); }
        base += carry;
        __syncthreads();
    }
    if (t == 0) rp[NN] = base;
}

__global__ __launch_bounds__(256)
void fill_csr(const int* __restrict__ ei, const int* __restrict__ rp,
              int* __restrict__ cursor, int* __restrict__ sadj)
{
    int e = blockIdx.x*256 + threadIdx.x;
    if (e >= NE) return;
    int d = ei[NE + e];
    int slot = atomicAdd(&cursor[d], 1);
    sadj[rp[d] + slot] = ei[e];
}

// ---------------------------------------------------------------------------
// Node encoder + g1w GEMM, MFMA. 64 nodes/block, 256 threads.
// ---------------------------------------------------------------------------
__global__ __launch_bounds__(256, 4)
void enc_mfma(const float* __restrict__ x,
              const float* __restrict__ w1, const float* __restrict__ b1,
              const u16* __restrict__ w2p, const float* __restrict__ b2,
              const u16* __restrict__ w3p, const float* __restrict__ b3,
              const float* __restrict__ gg, const float* __restrict__ bb,
              const u16* __restrict__ g1p, const float* __restrict__ dinv,
              u32* __restrict__ xw1p)
{
    __shared__ u16 chunkA[64*HD];
    __shared__ u16 chunkB[64*HD];
    __shared__ float sX[192];
    __shared__ float sDi[64];
    __shared__ float rstat[128];

    const int t = threadIdx.x;
    const int l = t & 63;
    const int wid = t >> 6;
    const int n0 = blockIdx.x * 64;

    if (t < 192) sX[t] = (n0*3 + t < NN*3) ? x[n0*3 + t] : 0.f;
    if (t < 64)  sDi[t] = (n0 + t < NN) ? dinv[n0 + t] : 0.f;
    __syncthreads();

    // L1: 3->128 relu (VALU) -> chunkA
    for (int it = 0; it < 16; ++it) {
        int dw = it*256 + t;
        int e = dw >> 6, cd = dw & 63;
        int c0 = cd*2;
        float x0 = sX[e*3], x1 = sX[e*3+1], x2 = sX[e*3+2];
        float v0 = b1[c0]   + x0*w1[c0]   + x1*w1[HD+c0]   + x2*w1[2*HD+c0];
        float v1 = b1[c0+1] + x0*w1[c0+1] + x1*w1[HD+c0+1] + x2*w1[2*HD+c0+1];
        v0 = fmaxf(v0, 0.f); v1 = fmaxf(v1, 0.f);
        int ci = cd >> 2;
        ((u32*)chunkA)[e*64 + ((ci ^ swzr(e & 15)) << 2) + (cd & 3)] = cvtpk(v0, v1);
    }
    __syncthreads();

    // L2 MFMA: relu(A@w2+b2) -> chunkB
    {
        f32x4 acc[4][2];
#pragma unroll
        for (int ni = 0; ni < 2; ++ni) {
            float b = b2[(2*wid + ni)*16 + (l & 15)];
#pragma unroll
            for (int mi = 0; mi < 4; ++mi) acc[mi][ni] = (f32x4){b,b,b,b};
        }
#pragma unroll
        for (int kk = 0; kk < 4; ++kk) {
            short8 af[4];
#pragma unroll
            for (int mi = 0; mi < 4; ++mi) af[mi] = loadA(chunkA, mi, kk, l);
#pragma unroll
            for (int ni = 0; ni < 2; ++ni) {
                short8 bw = loadB(w2p, 2*wid + ni, kk, 4, l);
#pragma unroll
                for (int mi = 0; mi < 4; ++mi) acc[mi][ni] = MFMA16(af[mi], bw, acc[mi][ni]);
            }
        }
#pragma unroll
        for (int ni = 0; ni < 2; ++ni) {
            int col = (2*wid + ni)*16 + (l & 15);
#pragma unroll
            for (int mi = 0; mi < 4; ++mi) {
                int R = mi*16 + ((l >> 4) << 2);
                storeQuad((u32*)chunkB, R, col, l,
                          fmaxf(acc[mi][ni][0], 0.f), fmaxf(acc[mi][ni][1], 0.f),
                          fmaxf(acc[mi][ni][2], 0.f), fmaxf(acc[mi][ni][3], 0.f));
            }
        }
    }
    __syncthreads();

    // L3 MFMA: B@w3+b3 (pre-LN) -> chunkA
    {
        f32x4 acc[4][2];
#pragma unroll
        for (int ni = 0; ni < 2; ++ni) {
            float b = b3[(2*wid + ni)*16 + (l & 15)];
#pragma unroll
            for (int mi = 0; mi < 4; ++mi) acc[mi][ni] = (f32x4){b,b,b,b};
        }
#pragma unroll
        for (int kk = 0; kk < 4; ++kk) {
            short8 af[4];
#pragma unroll
            for (int mi = 0; mi < 4; ++mi) af[mi] = loadA(chunkB, mi, kk, l);
#pragma unroll
            for (int ni = 0; ni < 2; ++ni) {
                short8 bw = loadB(w3p, 2*wid + ni, kk, 4, l);
#pragma unroll
                for (int mi = 0; mi < 4; ++mi) acc[mi][ni] = MFMA16(af[mi], bw, acc[mi][ni]);
            }
        }
#pragma unroll
        for (int ni = 0; ni < 2; ++ni) {
            int col = (2*wid + ni)*16 + (l & 15);
#pragma unroll
            for (int mi = 0; mi < 4; ++mi) {
                int R = mi*16 + ((l >> 4) << 2);
                storeQuad((u32*)chunkA, R, col, l,
                          acc[mi][ni][0], acc[mi][ni][1], acc[mi][ni][2], acc[mi][ni][3]);
            }
        }
    }
    __syncthreads();

    // LN stats: 4 lanes per row
    {
        int e = wid*16 + (l >> 2);
        int q = l & 3;
        const u32* rowp = (const u32*)chunkA + e*64;
        float s = 0.f, sq = 0.f;
#pragma unroll
        for (int i = 0; i < 16; ++i) {
            u32 pk = rowp[q*16 + ((i + e) & 15)];
            float a = bf2f(pk & 0xffffu), b = bf2f(pk >> 16);
            s += a + b;
            sq = fmaf(a, a, fmaf(b, b, sq));
        }
        s  += __shfl_xor(s, 1);  sq += __shfl_xor(sq, 1);
        s  += __shfl_xor(s, 2);  sq += __shfl_xor(sq, 2);
        if (q == 0) {
            float mu = s * (1.f/HD);
            rstat[e] = mu;
            rstat[64 + e] = rsqrtf(sq*(1.f/HD) - mu*mu + LN_EPS);
        }
    }
    __syncthreads();

    // normalize in place
    for (int it = 0; it < 16; ++it) {
        int pd = it*256 + t;
        int row = pd >> 6, cwd = pd & 63;
        int ci = (cwd >> 2) ^ swzr(row & 15);
        int col = ci*8 + (cwd & 3)*2;
        u32 pk = ((u32*)chunkA)[pd];
        float mu = rstat[row], ri = rstat[64 + row];
        float v0 = (bf2f(pk & 0xffffu) - mu)*ri*gg[col]     + bb[col];
        float v1 = (bf2f(pk >> 16)     - mu)*ri*gg[col + 1] + bb[col + 1];
        ((u32*)chunkA)[pd] = cvtpk(v0, v1);
    }
    __syncthreads();

    // GEMM @g1w, scale by dinv -> chunkB -> global
    {
        f32x4 acc[4][2];
#pragma unroll
        for (int mi = 0; mi < 4; ++mi)
#pragma unroll
            for (int ni = 0; ni < 2; ++ni) acc[mi][ni] = (f32x4){0.f,0.f,0.f,0.f};
#pragma unroll
        for (int kk = 0; kk < 4; ++kk) {
            short8 af[4];
#pragma unroll
            for (int mi = 0; mi < 4; ++mi) af[mi] = loadA(chunkA, mi, kk, l);
#pragma unroll
            for (int ni = 0; ni < 2; ++ni) {
                short8 bw = loadB(g1p, 2*wid + ni, kk, 4, l);
#pragma unroll
                for (int mi = 0; mi < 4; ++mi) acc[mi][ni] = MFMA16(af[mi], bw, acc[mi][ni]);
            }
        }
#pragma unroll
        for (int ni = 0; ni < 2; ++ni) {
            int col = (2*wid + ni)*16 + (l & 15);
#pragma unroll
            for (int mi = 0; mi < 4; ++mi) {
                int R = mi*16 + ((l >> 4) << 2);
                storeQuad((u32*)chunkB, R, col, l,
                          acc[mi][ni][0]*sDi[R], acc[mi][ni][1]*sDi[R+1],
                          acc[mi][ni][2]*sDi[R+2], acc[mi][ni][3]*sDi[R+3]);
            }
        }
    }
    __syncthreads();
    copyChunkOut((const u32*)chunkB, xw1p, n0, t);
}

// ---------------------------------------------------------------------------
// GCN layer 1: gather bf16 xw1p (prescaled), relu(+g1b), MFMA @g2w, *dinv -> xw2p
// ---------------------------------------------------------------------------
__global__ __launch_bounds__(256, 4)
void gcn_agg1_mfma(const u16* __restrict__ xw1p, const int* __restrict__ rp,
                   const int* __restrict__ sadj, const float* __restrict__ dinv,
                   const float* __restrict__ g1b, const u16* __restrict__ g2p,
                   u32* __restrict__ xw2p)
{
    __shared__ u16 chunkA[64*HD];
    __shared__ u16 chunkB[64*HD];
    __shared__ float sDi[64];
    __shared__ float sB[HD];

    const int t = threadIdx.x;
    const int l = t & 63;
    const int wid = t >> 6;
    const int n0 = blockIdx.x * 64;

    if (t < 64)  sDi[t] = (n0 + t < NN) ? dinv[n0 + t] : 0.f;
    if (t < HD)  sB[t] = g1b[t];
    __syncthreads();

    {
        int s = t >> 2, part = t & 3, n = n0 + s;
        float acc[32];
#pragma unroll
        for (int j = 0; j < 32; ++j) acc[j] = 0.f;
        float di = 0.f;
        if (n < NN) {
            di = sDi[s];
            const short8* selfp = (const short8*)(xw1p + (size_t)n*HD + part*32);
#pragma unroll
            for (int w = 0; w < 4; ++w) {
                short8 v = selfp[w];
#pragma unroll
                for (int j = 0; j < 8; ++j) acc[w*8+j] += bf2f((u16)v[j]);
            }
            int k1 = rp[n+1];
            for (int k = rp[n]; k < k1; ++k) {
                const short8* rp8 = (const short8*)(xw1p + (size_t)sadj[k]*HD + part*32);
#pragma unroll
                for (int w = 0; w < 4; ++w) {
                    short8 v = rp8[w];
#pragma unroll
                    for (int j = 0; j < 8; ++j) acc[w*8+j] += bf2f((u16)v[j]);
                }
            }
        }
#pragma unroll
        for (int p = 0; p < 16; ++p) {
            float v0 = fmaxf(fmaf(acc[2*p],   di, sB[part*32 + 2*p]),   0.f);
            float v1 = fmaxf(fmaf(acc[2*p+1], di, sB[part*32 + 2*p+1]), 0.f);
            int cw = part*16 + p;
            ((u32*)chunkA)[s*64 + (((cw >> 2) ^ swzr(s & 15)) << 2) + (cw & 3)] = cvtpk(v0, v1);
        }
    }
    __syncthreads();

    {
        f32x4 acc[4][2];
#pragma unroll
        for (int mi = 0; mi < 4; ++mi)
#pragma unroll
            for (int ni = 0; ni < 2; ++ni) acc[mi][ni] = (f32x4){0.f,0.f,0.f,0.f};
#pragma unroll
        for (int kk = 0; kk < 4; ++kk) {
            short8 af[4];
#pragma unroll
            for (int mi = 0; mi < 4; ++mi) af[mi] = loadA(chunkA, mi, kk, l);
#pragma unroll
            for (int ni = 0; ni < 2; ++ni) {
                short8 bw = loadB(g2p, 2*wid + ni, kk, 4, l);
#pragma unroll
                for (int mi = 0; mi < 4; ++mi) acc[mi][ni] = MFMA16(af[mi], bw, acc[mi][ni]);
            }
        }
#pragma unroll
        for (int ni = 0; ni < 2; ++ni) {
            int col = (2*wid + ni)*16 + (l & 15);
#pragma unroll
            for (int mi = 0; mi < 4; ++mi) {
                int R = mi*16 + ((l >> 4) << 2);
                storeQuad((u32*)chunkB, R, col, l,
                          acc[mi][ni][0]*sDi[R], acc[mi][ni][1]*sDi[R+1],
                          acc[mi][ni][2]*sDi[R+2], acc[mi][ni][3]*sDi[R+3]);
            }
        }
    }
    __syncthreads();
    copyChunkOut((const u32*)chunkB, xw2p, n0, t);
}

// ---------------------------------------------------------------------------
// GCN layer 2: gather bf16 xw2p, +g2b -> hbf (bf16 only)
// ---------------------------------------------------------------------------
__global__ __launch_bounds__(256)
void gcn_agg2_gather(const u16* __restrict__ xw2p, const int* __restrict__ rp,
                     const int* __restrict__ sadj, const float* __restrict__ dinv,
                     const float* __restrict__ g2b, u32* __restrict__ hbw)
{
    int t = threadIdx.x;
    int s = t >> 2, part = t & 3;
    int n = blockIdx.x * 64 + s;
    if (n >= NN) return;
    float acc[32];
#pragma unroll
    for (int j = 0; j < 32; ++j) acc[j] = 0.f;
    const short8* selfp = (const short8*)(xw2p + (size_t)n*HD + part*32);
#pragma unroll
    for (int w = 0; w < 4; ++w) {
        short8 v = selfp[w];
#pragma unroll
        for (int j = 0; j < 8; ++j) acc[w*8+j] += bf2f((u16)v[j]);
    }
    int k1 = rp[n+1];
    for (int k = rp[n]; k < k1; ++k) {
        const short8* rp8 = (const short8*)(xw2p + (size_t)sadj[k]*HD + part*32);
#pragma unroll
        for (int w = 0; w < 4; ++w) {
            short8 v = rp8[w];
#pragma unroll
            for (int j = 0; j < 8; ++j) acc[w*8+j] += bf2f((u16)v[j]);
        }
    }
    float di = dinv[n];
    u32* hb = hbw + (size_t)n*64 + part*16;
#pragma unroll
    for (int p = 0; p < 16; ++p) {
        float v0 = fmaf(acc[2*p],   di, g2b[part*32 + 2*p]);
        float v1 = fmaf(acc[2*p+1], di, g2b[part*32 + 2*p+1]);
        hb[p] = cvtpk(v0, v1);
    }
}

// ---------------------------------------------------------------------------
// Pool (batch sorted, bf16 input) + fused counts + graph MLP
// ---------------------------------------------------------------------------
#define POOL_B 512
__global__ __launch_bounds__(128)
void pool_sorted(const u16* __restrict__ h, const int* __restrict__ batch,
                 float* __restrict__ sums, float* __restrict__ cnts)
{
    int b = blockIdx.x, j = threadIdx.x;
    int n0 = (int)(((long long)NN * b) / POOL_B);
    int n1 = (int)(((long long)NN * (b+1)) / POOL_B);
    int g = -1; float acc = 0.f, cl = 0.f;
    for (int n = n0; n < n1; ++n) {
        int bg = batch[n];
        if (bg != g) {
            if (g >= 0) {
                atomicAdd(&sums[g*HD + j], acc);
                if (j == 0) atomicAdd(&cnts[g], cl);
            }
            g = bg; acc = 0.f; cl = 0.f;
        }
        acc += bf2f(h[(size_t)n*HD + j]);
        cl += 1.f;
    }
    if (g >= 0) {
        atomicAdd(&sums[g*HD + j], acc);
        if (j == 0) atomicAdd(&cnts[g], cl);
    }
}

__global__ __launch_bounds__(128)
void graph_feat(const float* __restrict__ sums, const float* __restrict__ cnts,
                const float* __restrict__ w1, const float* __restrict__ b1,
                const float* __restrict__ w2, const float* __restrict__ b2,
                const float* __restrict__ gg, const float* __restrict__ bb,
                u16* __restrict__ gf16)
{
    int gi = blockIdx.x, j = threadIdx.x;
    __shared__ float s0[HD];
    __shared__ float s1[HD];
    __shared__ float part[4];
    __shared__ float stat[2];
    float cnt = fmaxf(cnts[gi], 1.f);
    s0[j] = sums[gi*HD + j] / cnt;
    __syncthreads();
    float a = b1[j];
    for (int i = 0; i < HD; ++i) a = fmaf(s0[i], w1[i*HD + j], a);
    s1[j] = fmaxf(a, 0.f);
    __syncthreads();
    a = b2[j];
    for (int i = 0; i < HD; ++i) a = fmaf(s1[i], w2[i*HD + j], a);
    float s = a, q = a*a;
    for (int o = 32; o > 0; o >>= 1) { s += __shfl_down(s, o); q += __shfl_down(q, o); }
    int wid = j >> 6, lane = j & 63;
    if (lane == 0) { part[wid] = s; part[2 + wid] = q; }
    __syncthreads();
    if (j == 0) {
        float S = part[0] + part[1], Q = part[2] + part[3];
        float mu = S * (1.f/HD);
        stat[0] = mu;
        stat[1] = Q * (1.f/HD) - mu*mu;
    }
    __syncthreads();
    float v = (a - stat[0]) * rsqrtf(stat[1] + LN_EPS) * gg[j] + bb[j];
    gf16[gi*HD + j] = f2bf(v);
}

// ---------------------------------------------------------------------------
// Stage 64 gathered bf16 rows into swizzled LDS chunk (4 threads/row)
// ---------------------------------------------------------------------------
__device__ __forceinline__ void stageRows(u16* dst, const u16* __restrict__ srcBase,
                                          const int* ridx, int t)
{
    int e = t >> 2, part = t & 3;
    const u16* src = srcBase + (size_t)ridx[e]*HD + part*32;
    u16* drow = dst + e*128;
    int re = swzr(e & 15);
#pragma unroll
    for (int w = 0; w < 4; ++w) {
        int ci = (part*4 + w) ^ re;
        *(short8*)(drow + (ci << 3)) = *(const short8*)(src + w*8);
    }
}

// ---------------------------------------------------------------------------
// Fused edge kernel (MFMA bf16). 64 edges/block, 256 threads, 3 blocks/CU.
// h[src]/h[dst] prefetched into registers; gf staged late (L2-hot, 16KB).
// ---------------------------------------------------------------------------
__global__ __launch_bounds__(256, 3)
void edge_mlp_mfma(const u16* __restrict__ hbf, const u16* __restrict__ gfbf,
                   const int* __restrict__ ei, const int* __restrict__ batch,
                   const float* __restrict__ ea,
                   const float* __restrict__ ew1, const float* __restrict__ eb1,
                   const u16* __restrict__ ew2p, const float* __restrict__ eb2,
                   const u16* __restrict__ ew3p, const float* __restrict__ eb3,
                   const float* __restrict__ egm, const float* __restrict__ ebb,
                   const u16* __restrict__ p1wp, const float* __restrict__ p1b,
                   const u16* __restrict__ p2wp, const float* __restrict__ p2b,
                   const u16* __restrict__ p3wp, const float* __restrict__ p3b,
                   const float* __restrict__ p4w, const float* __restrict__ p4b,
                   float* __restrict__ out)
{
    __shared__ u16 bufChunk[64*HD];    // 16KB swizzled A-chunk
    __shared__ u16 bufWide[64*256];    // 32KB (2 chunks / fp32 scratch)
    __shared__ float sEa[192];
    __shared__ int sGf[64];
    __shared__ float rstat[128];

    const int t = threadIdx.x;
    const int l = t & 63;
    const int wid = t >> 6;
    const int e0 = blockIdx.x * 64;

    // ---- prefetch h[src]/h[dst] into registers (hidden under encoder) ----
    const int eRow = t >> 2, part = t & 3;
    int srcN = ei[e0 + eRow];
    int dstN = ei[NE + e0 + eRow];
    if (part == 0) sGf[eRow] = batch[srcN];
    short8 rs[4], rd[4];
    {
        const short8* ps = (const short8*)(hbf + (size_t)srcN*HD + part*32);
        const short8* pd = (const short8*)(hbf + (size_t)dstN*HD + part*32);
#pragma unroll
        for (int w = 0; w < 4; ++w) { rs[w] = ps[w]; rd[w] = pd[w]; }
    }

    if (t < 192) sEa[t] = ea[e0*3 + t];
    __syncthreads();

    // ---- enc1: relu(ea@ew1+b1) -> bufChunk ----
    for (int it = 0; it < 16; ++it) {
        int dw = it*256 + t;
        int e = dw >> 6, cd = dw & 63;
        int c0 = cd*2;
        float x0 = sEa[e*3], x1 = sEa[e*3+1], x2 = sEa[e*3+2];
        float v0 = eb1[c0]   + x0*ew1[c0]   + x1*ew1[HD+c0]   + x2*ew1[2*HD+c0];
        float v1 = eb1[c0+1] + x0*ew1[c0+1] + x1*ew1[HD+c0+1] + x2*ew1[2*HD+c0+1];
        v0 = fmaxf(v0, 0.f); v1 = fmaxf(v1, 0.f);
        int ci = cd >> 2;
        ((u32*)bufChunk)[e*64 + ((ci ^ swzr(e & 15)) << 2) + (cd & 3)] = cvtpk(v0, v1);
    }
    __syncthreads();

    // ---- enc2: relu(A@ew2+b2) -> bufWide chunk0 ----
    {
        f32x4 acc[4][2];
#pragma unroll
        for (int ni = 0; ni < 2; ++ni) {
            float b = eb2[(2*wid + ni)*16 + (l & 15)];
#pragma unroll
            for (int mi = 0; mi < 4; ++mi) acc[mi][ni] = (f32x4){b,b,b,b};
        }
#pragma unroll
        for (int kk = 0; kk < 4; ++kk) {
            short8 af[4];
#pragma unroll
            for (int mi = 0; mi < 4; ++mi) af[mi] = loadA(bufChunk, mi, kk, l);
#pragma unroll
            for (int ni = 0; ni < 2; ++ni) {
                short8 bw = loadB(ew2p, 2*wid + ni, kk, 4, l);
#pragma unroll
                for (int mi = 0; mi < 4; ++mi) acc[mi][ni] = MFMA16(af[mi], bw, acc[mi][ni]);
            }
        }
#pragma unroll
        for (int ni = 0; ni < 2; ++ni) {
            int col = (2*wid + ni)*16 + (l & 15);
#pragma unroll
            for (int mi = 0; mi < 4; ++mi) {
                int R = mi*16 + ((l >> 4) << 2);
                storeQuad((u32*)bufWide, R, col, l,
                          fmaxf(acc[mi][ni][0], 0.f), fmaxf(acc[mi][ni][1], 0.f),
                          fmaxf(acc[mi][ni][2], 0.f), fmaxf(acc[mi][ni][3], 0.f));
            }
        }
    }
    __syncthreads();

    // ---- enc3: W0@ew3+b3 (pre-LN) -> bufChunk ----
    {
        f32x4 acc[4][2];
#pragma unroll
        for (int ni = 0; ni < 2; ++ni) {
            float b = eb3[(2*wid + ni)*16 + (l & 15)];
#pragma unroll
            for (int mi = 0; mi < 4; ++mi) acc[mi][ni] = (f32x4){b,b,b,b};
        }
#pragma unroll
        for (int kk = 0; kk < 4; ++kk) {
            short8 af[4];
#pragma unroll
            for (int mi = 0; mi < 4; ++mi) af[mi] = loadA(bufWide, mi, kk, l);
#pragma unroll
            for (int ni = 0; ni < 2; ++ni) {
                short8 bw = loadB(ew3p, 2*wid + ni, kk, 4, l);
#pragma unroll
                for (int mi = 0; mi < 4; ++mi) acc[mi][ni] = MFMA16(af[mi], bw, acc[mi][ni]);
            }
        }
#pragma unroll
        for (int ni = 0; ni < 2; ++ni) {
            int col = (2*wid + ni)*16 + (l & 15);
#pragma unroll
            for (int mi = 0; mi < 4; ++mi) {
                int R = mi*16 + ((l >> 4) << 2);
                storeQuad((u32*)bufChunk, R, col, l,
                          acc[mi][ni][0], acc[mi][ni][1], acc[mi][ni][2], acc[mi][ni][3]);
            }
        }
    }
    __syncthreads();

    // ---- write prefetched h[src]/h[dst] to bufWide (enc2 data dead) ----
    {
        u16* drow0 = bufWide + eRow*128;
        u16* drow1 = bufWide + 8192 + eRow*128;
        int re = swzr(eRow & 15);
#pragma unroll
        for (int w = 0; w < 4; ++w) {
            int ci = (part*4 + w) ^ re;
            *(short8*)(drow0 + (ci << 3)) = rs[w];
            *(short8*)(drow1 + (ci << 3)) = rd[w];
        }
    }

    // ---- LN stats: 4 lanes per edge ----
    {
        int e = wid*16 + (l >> 2);
        int q = l & 3;
        const u32* rowp = (const u32*)bufChunk + e*64;
        float s = 0.f, sq = 0.f;
#pragma unroll
        for (int i = 0; i < 16; ++i) {
            u32 pk = rowp[q*16 + ((i + e) & 15)];
            float a = bf2f(pk & 0xffffu), b = bf2f(pk >> 16);
            s += a + b;
            sq = fmaf(a, a, fmaf(b, b, sq));
        }
        s  += __shfl_xor(s, 1);  sq += __shfl_xor(sq, 1);
        s  += __shfl_xor(s, 2);  sq += __shfl_xor(sq, 2);
        if (q == 0) {
            float mu = s * (1.f/HD);
            rstat[e] = mu;
            rstat[64 + e] = rsqrtf(sq*(1.f/HD) - mu*mu + LN_EPS);
        }
    }
    __syncthreads();

    // ---- normalize in place: bufChunk = ef ----
    for (int it = 0; it < 16; ++it) {
        int pd = it*256 + t;
        int row = pd >> 6, cwd = pd & 63;
        int ci = (cwd >> 2) ^ swzr(row & 15);
        int col = ci*8 + (cwd & 3)*2;
        u32 pk = ((u32*)bufChunk)[pd];
        float mu = rstat[row], ri = rstat[64 + row];
        float v0 = (bf2f(pk & 0xffffu) - mu)*ri*egm[col]     + ebb[col];
        float v1 = (bf2f(pk >> 16)     - mu)*ri*egm[col + 1] + ebb[col + 1];
        ((u32*)bufChunk)[pd] = cvtpk(v0, v1);
    }
    __syncthreads();

    // ---- ep1 MFMA: ef (ks 12..15), hsrc (ks 0..3), hdst (ks 4..7) ----
    f32x4 acc1[4][4];
#pragma unroll
    for (int ni = 0; ni < 4; ++ni) {
        float b = p1b[(4*wid + ni)*16 + (l & 15)];
#pragma unroll
        for (int mi = 0; mi < 4; ++mi) acc1[mi][ni] = (f32x4){b,b,b,b};
    }
#pragma unroll
    for (int kk = 0; kk < 4; ++kk) {
        short8 af[4];
#pragma unroll
        for (int mi = 0; mi < 4; ++mi) af[mi] = loadA(bufChunk, mi, kk, l);
#pragma unroll
        for (int ni = 0; ni < 4; ++ni) {
            short8 bw = loadB(p1wp, 4*wid + ni, 12 + kk, 16, l);
#pragma unroll
            for (int mi = 0; mi < 4; ++mi) acc1[mi][ni] = MFMA16(af[mi], bw, acc1[mi][ni]);
        }
    }
#pragma unroll
    for (int kk = 0; kk < 4; ++kk) {
        short8 af[4];
#pragma unroll
        for (int mi = 0; mi < 4; ++mi) af[mi] = loadA(bufWide, mi, kk, l);
#pragma unroll
        for (int ni = 0; ni < 4; ++ni) {
            short8 bw = loadB(p1wp, 4*wid + ni, kk, 16, l);
#pragma unroll
            for (int mi = 0; mi < 4; ++mi) acc1[mi][ni] = MFMA16(af[mi], bw, acc1[mi][ni]);
        }
    }
#pragma unroll
    for (int kk = 0; kk < 4; ++kk) {
        short8 af[4];
#pragma unroll
        for (int mi = 0; mi < 4; ++mi) af[mi] = loadA(bufWide + 8192, mi, kk, l);
#pragma unroll
        for (int ni = 0; ni < 4; ++ni) {
            short8 bw = loadB(p1wp, 4*wid + ni, 4 + kk, 16, l);
#pragma unroll
            for (int mi = 0; mi < 4; ++mi) acc1[mi][ni] = MFMA16(af[mi], bw, acc1[mi][ni]);
        }
    }
    __syncthreads();

    // ---- stage gf -> bufChunk (ef dead), MFMA (ks 8..11), tanh -> bufWide ----
    stageRows(bufChunk, gfbf, sGf, t);
    __syncthreads();
#pragma unroll
    for (int kk = 0; kk < 4; ++kk) {
        short8 af[4];
#pragma unroll
        for (int mi = 0; mi < 4; ++mi) af[mi] = loadA(bufChunk, mi, kk, l);
#pragma unroll
        for (int ni = 0; ni < 4; ++ni) {
            short8 bw = loadB(p1wp, 4*wid + ni, 8 + kk, 16, l);
#pragma unroll
            for (int mi = 0; mi < 4; ++mi) acc1[mi][ni] = MFMA16(af[mi], bw, acc1[mi][ni]);
        }
    }
#pragma unroll
    for (int ni = 0; ni < 4; ++ni) {
        int col = (4*wid + ni)*16 + (l & 15);
        u32* dst = (u32*)bufWide + ((col >> 7) << 12);
        int cc = col & 127;
#pragma unroll
        for (int mi = 0; mi < 4; ++mi) {
            int R = mi*16 + ((l >> 4) << 2);
            storeQuad(dst, R, cc, l,
                      fast_tanh(acc1[mi][ni][0]), fast_tanh(acc1[mi][ni][1]),
                      fast_tanh(acc1[mi][ni][2]), fast_tanh(acc1[mi][ni][3]));
        }
    }
    __syncthreads();

    // ---- ep2: [64,256]@p2w[256,128], tanh -> bufChunk ----
    {
        f32x4 acc[4][2];
#pragma unroll
        for (int ni = 0; ni < 2; ++ni) {
            float b = p2b[(2*wid + ni)*16 + (l & 15)];
#pragma unroll
            for (int mi = 0; mi < 4; ++mi) acc[mi][ni] = (f32x4){b,b,b,b};
        }
        for (int kc = 0; kc < 2; ++kc) {
            const u16* abuf = bufWide + (kc << 13);
#pragma unroll
            for (int kk = 0; kk < 4; ++kk) {
                short8 af[4];
#pragma unroll
                for (int mi = 0; mi < 4; ++mi) af[mi] = loadA(abuf, mi, kk, l);
                int ks = kc*4 + kk;
#pragma unroll
                for (int ni = 0; ni < 2; ++ni) {
                    short8 bw = loadB(p2wp, 2*wid + ni, ks, 8, l);
#pragma unroll
                    for (int mi = 0; mi < 4; ++mi) acc[mi][ni] = MFMA16(af[mi], bw, acc[mi][ni]);
                }
            }
        }
#pragma unroll
        for (int ni = 0; ni < 2; ++ni) {
            int col = (2*wid + ni)*16 + (l & 15);
#pragma unroll
            for (int mi = 0; mi < 4; ++mi) {
                int R = mi*16 + ((l >> 4) << 2);
                storeQuad((u32*)bufChunk, R, col, l,
                          fast_tanh(acc[mi][ni][0]), fast_tanh(acc[mi][ni][1]),
                          fast_tanh(acc[mi][ni][2]), fast_tanh(acc[mi][ni][3]));
            }
        }
    }
    __syncthreads();

    // ---- ep3: [64,128]@p3w[128,64], relu -> bufWide fp32 stride-65 ----
    {
        f32x4 acc[4];
        {
            float b = p3b[wid*16 + (l & 15)];
#pragma unroll
            for (int mi = 0; mi < 4; ++mi) acc[mi] = (f32x4){b,b,b,b};
        }
#pragma unroll
        for (int kk = 0; kk < 4; ++kk) {
            short8 af[4];
#pragma unroll
            for (int mi = 0; mi < 4; ++mi) af[mi] = loadA(bufChunk, mi, kk, l);
            short8 bw = loadB(p3wp, wid, kk, 4, l);
#pragma unroll
            for (int mi = 0; mi < 4; ++mi) acc[mi] = MFMA16(af[mi], bw, acc[mi]);
        }
        float* fb = (float*)bufWide;
        int col = wid*16 + (l & 15);
#pragma unroll
        for (int mi = 0; mi < 4; ++mi)
#pragma unroll
            for (int rr = 0; rr < 4; ++rr) {
                int row = mi*16 + ((l >> 4) << 2) + rr;
                fb[row*65 + col] = fmaxf(acc[mi][rr], 0.f);
            }
    }
    __syncthreads();

    // ---- ep4: 4 lanes/edge dot-64 + sigmoid ----
    {
        const float* fb = (const float*)bufWide;
        int e = wid*16 + (l >> 2), q = l & 3;
        float v = 0.f;
#pragma unroll
        for (int k = 0; k < 16; ++k) {
            int i = q*16 + k;
            v = fmaf(fb[e*65 + i], p4w[i], v);
        }
        v += __shfl_xor(v, 1);
        v += __shfl_xor(v, 2);
        if (q == 0) out[e0 + e] = fast_sigmoid(v + p4b[0]);
    }
}

// ---------------------------------------------------------------------------
extern "C" void kernel_launch(void* const* d_in, const int* in_sizes, int n_in,
                              void* d_out, int out_size, void* d_ws, size_t ws_size,
                              hipStream_t stream)
{
    const float* x     = (const float*)d_in[0];
    const int*   ei    = (const int*)  d_in[1];
    const float* ea    = (const float*)d_in[2];
    const int*   batch = (const int*)  d_in[3];
    const float* ne1w = (const float*)d_in[4];  const float* ne1b = (const float*)d_in[5];
    const float* ne2w = (const float*)d_in[6];  const float* ne2b = (const float*)d_in[7];
    const float* ne3w = (const float*)d_in[8];  const float* ne3b = (const float*)d_in[9];
    const float* neg  = (const float*)d_in[10]; const float* nebb = (const float*)d_in[11];
    const float* ee1w = (const float*)d_in[12]; const float* ee1b = (const float*)d_in[13];
    const float* ee2w = (const float*)d_in[14]; const float* ee2b = (const float*)d_in[15];
    const float* ee3w = (const float*)d_in[16]; const float* ee3b = (const float*)d_in[17];
    const float* eeg  = (const float*)d_in[18]; const float* eebb = (const float*)d_in[19];
    const float* g1w  = (const float*)d_in[20]; const float* g1b  = (const float*)d_in[21];
    const float* g2w  = (const float*)d_in[22]; const float* g2b  = (const float*)d_in[23];
    const float* gp1w = (const float*)d_in[24]; const float* gp1b = (const float*)d_in[25];
    const float* gp2w = (const float*)d_in[26]; const float* gp2b = (const float*)d_in[27];
    const float* gpg  = (const float*)d_in[28]; const float* gpbb = (const float*)d_in[29];
    const float* p1w  = (const float*)d_in[30]; const float* p1b  = (const float*)d_in[31];
    const float* p2w  = (const float*)d_in[32]; const float* p2b  = (const float*)d_in[33];
    const float* p3w  = (const float*)d_in[34]; const float* p3b  = (const float*)d_in[35];
    const float* p4w  = (const float*)d_in[36]; const float* p4b  = (const float*)d_in[37];

    float* dinv = (float*)d_ws;                // NN
    float* sums = dinv + NN;                   // NG*HD
    float* cnts = sums + NG*HD;                // NG
    int* degi   = (int*)(cnts + NG);           // NN
    int* cursor = degi + NN;                   // NN+2
    int* rowptr = cursor + NN + 2;             // NN+2
    int* sadj   = rowptr + NN + 2;             // NE
    u16* xw1p   = (u16*)(sadj + NE);           // NN*HD
    u16* xw2p   = xw1p + (size_t)NN*HD;        // NN*HD
    u16* hbf    = xw2p + (size_t)NN*HD;        // NN*HD
    u16* gf16   = hbf + (size_t)NN*HD;         // NG*HD
    u16* wpk    = gf16 + NG*HD;                // 270336
    u16* ee2p = wpk;
    u16* ee3p = wpk + 16384;
    u16* p1p  = wpk + 32768;
    u16* p2p  = wpk + 163840;
    u16* p3p  = wpk + 196608;
    u16* ne2p = wpk + 204800;
    u16* ne3p = wpk + 221184;
    u16* g1p  = wpk + 237568;
    u16* g2p  = wpk + 253952;

    float* out = (float*)d_out;

    hipMemsetAsync(degi, 0, (size_t)(2*NN + 2)*sizeof(int), stream);
    hipMemsetAsync(sums, 0, (size_t)(NG*HD + NG)*sizeof(float), stream);

    pack_all<<<(270336 + 255)/256, 256, 0, stream>>>(ee2w, ee3w, p1w, p2w, p3w,
                                                     ne2w, ne3w, g1w, g2w, wpk);

    // CSR build (+dinv fused into scan)
    deg_count_int<<<(NE + 255)/256, 256, 0, stream>>>(ei, degi);
    scan_excl<<<1, 1024, 0, stream>>>(degi, rowptr, dinv);
    fill_csr<<<(NE + 255)/256, 256, 0, stream>>>(ei, rowptr, cursor, sadj);

    // node encoder + g1 GEMM (bf16 out, prescaled by dinv)
    enc_mfma<<<(NN + 63)/64, 256, 0, stream>>>(x, ne1w, ne1b, ne2p, ne2b, ne3p, ne3b,
                                               neg, nebb, g1p, dinv, (u32*)xw1p);
    // GCN1 gather + relu + g2 GEMM
    gcn_agg1_mfma<<<(NN + 63)/64, 256, 0, stream>>>(xw1p, rowptr, sadj, dinv,
                                                    g1b, g2p, (u32*)xw2p);
    // GCN2 gather -> hbf bf16
    gcn_agg2_gather<<<(NN + 63)/64, 256, 0, stream>>>(xw2p, rowptr, sadj, dinv,
                                                      g2b, (u32*)hbf);

    // pool (+counts fused) + graph MLP
    pool_sorted<<<POOL_B, 128, 0, stream>>>(hbf, batch, sums, cnts);
    graph_feat<<<NG, 128, 0, stream>>>(sums, cnts, gp1w, gp1b, gp2w, gp2b,
                                       gpg, gpbb, gf16);

    // fused edge encoder + edge-score MLP
    edge_mlp_mfma<<<NE/64, 256, 0, stream>>>(hbf, gf16, ei, batch, ea,
                                             ee1w, ee1b, ee2p, ee2b, ee3p, ee3b,
                                             eeg, eebb,
                                             p1p, p1b, p2p, p2b, p3p, p3b,
                                             p4w, p4b, out);
}

// Round 7
// 641.721 us; speedup vs baseline: 8.0029x; 1.0372x over previous
//
#include <hip/hip_runtime.h>
#include <math.h>

#define NN 50000
#define NE 400000
#define NG 64
#define HD 128
#define LN_EPS 1e-5f

typedef unsigned short u16;
typedef unsigned int u32;
typedef __attribute__((ext_vector_type(8))) short short8;
typedef __attribute__((ext_vector_type(4))) float f32x4;

#define MFMA16(a,b,c) __builtin_amdgcn_mfma_f32_16x16x32_bf16((a),(b),(c),0,0,0)

__device__ __forceinline__ u16 f2bf(float f) {
    union { float f; u32 u; } v; v.f = f;
    u32 r = v.u + 0x7FFFu + ((v.u >> 16) & 1u);
    return (u16)(r >> 16);
}
__device__ __forceinline__ float bf2f(u32 hs) {
    union { u32 u; float f; } v; v.u = hs << 16;
    return v.f;
}
__device__ __forceinline__ float fast_rcp(float x) {
    float r; asm("v_rcp_f32 %0, %1" : "=v"(r) : "v"(x)); return r;
}
__device__ __forceinline__ float fast_exp2(float x) {
    float r; asm("v_exp_f32 %0, %1" : "=v"(r) : "v"(x)); return r;
}
__device__ __forceinline__ u32 cvtpk(float lo, float hi) {
    u32 r; asm("v_cvt_pk_bf16_f32 %0, %1, %2" : "=v"(r) : "v"(lo), "v"(hi)); return r;
}
// tanh(x) = 1 - 2/(1+2^(2*log2e*x)); exp2 saturates correctly at +-inf
__device__ __forceinline__ float fast_tanh(float x) {
    return fmaf(-2.f, fast_rcp(1.f + fast_exp2(2.885390082f * x)), 1.f);
}
__device__ __forceinline__ float fast_sigmoid(float x) {
    return fast_rcp(1.f + fast_exp2(-1.442695041f * x));
}

// swizzle term for row within 16-row group
__device__ __forceinline__ int swzr(int row) {
    return (row & 7) ^ ((row & 8) >> 2);
}

// A-fragment load from swizzled [64][128] bf16 chunk buffer.
__device__ __forceinline__ short8 loadA(const u16* buf, int mi, int kk, int l) {
    int row = mi*16 + (l & 15);
    int ci  = (kk*4 + (l >> 4)) ^ swzr(l & 15);
    return *(const short8*)(buf + row*128 + (ci << 3));
}
__device__ __forceinline__ short8 loadB(const u16* wp, int nt, int ks, int nk, int l) {
    return *(const short8*)(wp + (((nt*nk + ks)*64 + l) << 3));
}

// Store 4 accumulator values (rows R..R+3, col c) into swizzled bf16 chunk as
// packed u32 via lane-pair exchange + v_cvt_pk_bf16_f32.
__device__ __forceinline__ void storeQuad(u32* buf, int R, int c, int l,
                                          float v0, float v1, float v2, float v3)
{
    int cw = c >> 1;
    int par = l & 1;
    float send = par ? v0 : v1;
    float recv = __shfl_xor(send, 1);
    int row = R + par;
    u32 word = par ? cvtpk(recv, v1) : cvtpk(v0, recv);
    buf[row*64 + (((cw >> 2) ^ swzr(row & 15)) << 2) + (cw & 3)] = word;
    send = par ? v2 : v3;
    recv = __shfl_xor(send, 1);
    row = R + 2 + par;
    word = par ? cvtpk(recv, v3) : cvtpk(v2, recv);
    buf[row*64 + (((cw >> 2) ^ swzr(row & 15)) << 2) + (cw & 3)] = word;
}

// Unswizzle copy: LDS chunk -> global bf16 [64][128] rows n0..n0+63 (u32 words)
__device__ __forceinline__ void copyChunkOut(const u32* chunk, u32* gout, int n0, int t)
{
    for (int it = 0; it < 16; ++it) {
        int dw = it*256 + t;
        int row = dw >> 6, cw = dw & 63;
        if (n0 + row < NN)
            gout[(size_t)(n0 + row)*64 + cw] =
                chunk[row*64 + (((cw >> 2) ^ swzr(row & 15)) << 2) + (cw & 3)];
    }
}

// ---------------------------------------------------------------------------
// One-shot weight packing of all 9 GEMM weights -> bf16 MFMA B-fragment order.
// ---------------------------------------------------------------------------
__global__ __launch_bounds__(256)
void pack_all(const float* __restrict__ ee2w, const float* __restrict__ ee3w,
              const float* __restrict__ p1w,  const float* __restrict__ p2w,
              const float* __restrict__ p3w,  const float* __restrict__ ne2w,
              const float* __restrict__ ne3w, const float* __restrict__ g1w,
              const float* __restrict__ g2w,  u16* __restrict__ wpk)
{
    int idx = blockIdx.x*256 + threadIdx.x;
    if (idx >= 270336) return;
    const float* w; int K, N, local;
    if      (idx < 16384)  { w = ee2w; K = 128; N = 128; local = idx; }
    else if (idx < 32768)  { w = ee3w; K = 128; N = 128; local = idx - 16384; }
    else if (idx < 163840) { w = p1w;  K = 512; N = 256; local = idx - 32768; }
    else if (idx < 196608) { w = p2w;  K = 256; N = 128; local = idx - 163840; }
    else if (idx < 204800) { w = p3w;  K = 128; N = 64;  local = idx - 196608; }
    else if (idx < 221184) { w = ne2w; K = 128; N = 128; local = idx - 204800; }
    else if (idx < 237568) { w = ne3w; K = 128; N = 128; local = idx - 221184; }
    else if (idx < 253952) { w = g1w;  K = 128; N = 128; local = idx - 237568; }
    else                   { w = g2w;  K = 128; N = 128; local = idx - 253952; }
    int e = local & 7, l = (local >> 3) & 63, r = local >> 9;
    int nk = K >> 5;
    int nt = r / nk, kk = r % nk;
    int k = kk*32 + ((l >> 4) << 3) + e;
    int n = nt*16 + (l & 15);
    wpk[idx] = f2bf(w[k*N + n]);
}

// ---------------------------------------------------------------------------
// CSR build
// ---------------------------------------------------------------------------
__global__ __launch_bounds__(256)
void deg_count_int(const int* __restrict__ ei, int* __restrict__ degi)
{
    int e = blockIdx.x*256 + threadIdx.x;
    if (e < NE) atomicAdd(&degi[ei[NE + e]], 1);
}

__global__ __launch_bounds__(1024)
void scan_excl(const int* __restrict__ cnt, int* __restrict__ rp,
               float* __restrict__ dinv)
{
    __shared__ int wsum[16];
    __shared__ int carry;
    int t = threadIdx.x, lane = t & 63, w = t >> 6;
    int base = 0;
    for (int off = 0; off < NN; off += 4096) {
        int i0 = off + t*4;
        int v0 = (i0   < NN) ? cnt[i0]   : 0;
        int v1 = (i0+1 < NN) ? cnt[i0+1] : 0;
        int v2 = (i0+2 < NN) ? cnt[i0+2] : 0;
        int v3 = (i0+3 < NN) ? cnt[i0+3] : 0;
        int tot = v0 + v1 + v2 + v3;
        int s = tot;
#pragma unroll
        for (int d = 1; d < 64; d <<= 1) { int u = __shfl_up(s, d); if (lane >= d) s += u; }
        if (lane == 63) wsum[w] = s;
        __syncthreads();
        if (w == 0) {
            int wv = (lane < 16) ? wsum[lane] : 0;
            int ss = wv;
#pragma unroll
            for (int d = 1; d < 16; d <<= 1) { int u = __shfl_up(ss, d); if (lane >= d) ss += u; }
            if (lane < 16) wsum[lane] = ss - wv;
            if (lane == 15) carry = ss;
        }
        __syncthreads();
        int excl = base + wsum[w] + s - tot;
        if (i0   < NN) { rp[i0]   = excl;              dinv[i0]   = rsqrtf((float)v0 + 1.f); }
        if (i0+1 < NN) { rp[i0+1] = excl + v0;         dinv[i0+1] = rsqrtf((float)v1 + 1.f); }
        if (i0+2 < NN) { rp[i0+2] = excl + v0 + v1;    dinv[i0+2] = rsqrtf((float)v2 + 1.f); }
        if (i0+3 < NN) { rp[i0+3] = excl + v0 + v1 + v2; dinv[i0+3] = rsqrtf((float)v3 + 1.f); }
        base += carry;
        __syncthreads();
    }
    if (t == 0) rp[NN] = base;
}

__global__ __launch_bounds__(256)
void fill_csr(const int* __restrict__ ei, const int* __restrict__ rp,
              int* __restrict__ cursor, int* __restrict__ sadj)
{
    int e = blockIdx.x*256 + threadIdx.x;
    if (e >= NE) return;
    int d = ei[NE + e];
    int slot = atomicAdd(&cursor[d], 1);
    sadj[rp[d] + slot] = ei[e];
}

// ---------------------------------------------------------------------------
// Node encoder + g1w GEMM, MFMA. 64 nodes/block, 256 threads.
// ---------------------------------------------------------------------------
__global__ __launch_bounds__(256, 4)
void enc_mfma(const float* __restrict__ x,
              const float* __restrict__ w1, const float* __restrict__ b1,
              const u16* __restrict__ w2p, const float* __restrict__ b2,
              const u16* __restrict__ w3p, const float* __restrict__ b3,
              const float* __restrict__ gg, const float* __restrict__ bb,
              const u16* __restrict__ g1p, const float* __restrict__ dinv,
              u32* __restrict__ xw1p)
{
    __shared__ u16 chunkA[64*HD];
    __shared__ u16 chunkB[64*HD];
    __shared__ float sX[192];
    __shared__ float sDi[64];
    __shared__ float rstat[128];

    const int t = threadIdx.x;
    const int l = t & 63;
    const int wid = t >> 6;
    const int n0 = blockIdx.x * 64;

    if (t < 192) sX[t] = (n0*3 + t < NN*3) ? x[n0*3 + t] : 0.f;
    if (t < 64)  sDi[t] = (n0 + t < NN) ? dinv[n0 + t] : 0.f;
    __syncthreads();

    // L1: 3->128 relu (VALU) -> chunkA
    for (int it = 0; it < 16; ++it) {
        int dw = it*256 + t;
        int e = dw >> 6, cd = dw & 63;
        int c0 = cd*2;
        float x0 = sX[e*3], x1 = sX[e*3+1], x2 = sX[e*3+2];
        float v0 = b1[c0]   + x0*w1[c0]   + x1*w1[HD+c0]   + x2*w1[2*HD+c0];
        float v1 = b1[c0+1] + x0*w1[c0+1] + x1*w1[HD+c0+1] + x2*w1[2*HD+c0+1];
        v0 = fmaxf(v0, 0.f); v1 = fmaxf(v1, 0.f);
        int ci = cd >> 2;
        ((u32*)chunkA)[e*64 + ((ci ^ swzr(e & 15)) << 2) + (cd & 3)] = cvtpk(v0, v1);
    }
    __syncthreads();

    // L2 MFMA: relu(A@w2+b2) -> chunkB
    {
        f32x4 acc[4][2];
#pragma unroll
        for (int ni = 0; ni < 2; ++ni) {
            float b = b2[(2*wid + ni)*16 + (l & 15)];
#pragma unroll
            for (int mi = 0; mi < 4; ++mi) acc[mi][ni] = (f32x4){b,b,b,b};
        }
#pragma unroll
        for (int kk = 0; kk < 4; ++kk) {
            short8 af[4];
#pragma unroll
            for (int mi = 0; mi < 4; ++mi) af[mi] = loadA(chunkA, mi, kk, l);
#pragma unroll
            for (int ni = 0; ni < 2; ++ni) {
                short8 bw = loadB(w2p, 2*wid + ni, kk, 4, l);
#pragma unroll
                for (int mi = 0; mi < 4; ++mi) acc[mi][ni] = MFMA16(af[mi], bw, acc[mi][ni]);
            }
        }
#pragma unroll
        for (int ni = 0; ni < 2; ++ni) {
            int col = (2*wid + ni)*16 + (l & 15);
#pragma unroll
            for (int mi = 0; mi < 4; ++mi) {
                int R = mi*16 + ((l >> 4) << 2);
                storeQuad((u32*)chunkB, R, col, l,
                          fmaxf(acc[mi][ni][0], 0.f), fmaxf(acc[mi][ni][1], 0.f),
                          fmaxf(acc[mi][ni][2], 0.f), fmaxf(acc[mi][ni][3], 0.f));
            }
        }
    }
    __syncthreads();

    // L3 MFMA: B@w3+b3 (pre-LN) -> chunkA
    {
        f32x4 acc[4][2];
#pragma unroll
        for (int ni = 0; ni < 2; ++ni) {
            float b = b3[(2*wid + ni)*16 + (l & 15)];
#pragma unroll
            for (int mi = 0; mi < 4; ++mi) acc[mi][ni] = (f32x4){b,b,b,b};
        }
#pragma unroll
        for (int kk = 0; kk < 4; ++kk) {
            short8 af[4];
#pragma unroll
            for (int mi = 0; mi < 4; ++mi) af[mi] = loadA(chunkB, mi, kk, l);
#pragma unroll
            for (int ni = 0; ni < 2; ++ni) {
                short8 bw = loadB(w3p, 2*wid + ni, kk, 4, l);
#pragma unroll
                for (int mi = 0; mi < 4; ++mi) acc[mi][ni] = MFMA16(af[mi], bw, acc[mi][ni]);
            }
        }
#pragma unroll
        for (int ni = 0; ni < 2; ++ni) {
            int col = (2*wid + ni)*16 + (l & 15);
#pragma unroll
            for (int mi = 0; mi < 4; ++mi) {
                int R = mi*16 + ((l >> 4) << 2);
                storeQuad((u32*)chunkA, R, col, l,
                          acc[mi][ni][0], acc[mi][ni][1], acc[mi][ni][2], acc[mi][ni][3]);
            }
        }
    }
    __syncthreads();

    // LN stats: 4 lanes per row
    {
        int e = wid*16 + (l >> 2);
        int q = l & 3;
        const u32* rowp = (const u32*)chunkA + e*64;
        float s = 0.f, sq = 0.f;
#pragma unroll
        for (int i = 0; i < 16; ++i) {
            u32 pk = rowp[q*16 + ((i + e) & 15)];
            float a = bf2f(pk & 0xffffu), b = bf2f(pk >> 16);
            s += a + b;
            sq = fmaf(a, a, fmaf(b, b, sq));
        }
        s  += __shfl_xor(s, 1);  sq += __shfl_xor(sq, 1);
        s  += __shfl_xor(s, 2);  sq += __shfl_xor(sq, 2);
        if (q == 0) {
            float mu = s * (1.f/HD);
            rstat[e] = mu;
            rstat[64 + e] = rsqrtf(sq*(1.f/HD) - mu*mu + LN_EPS);
        }
    }
    __syncthreads();

    // normalize in place
    for (int it = 0; it < 16; ++it) {
        int pd = it*256 + t;
        int row = pd >> 6, cwd = pd & 63;
        int ci = (cwd >> 2) ^ swzr(row & 15);
        int col = ci*8 + (cwd & 3)*2;
        u32 pk = ((u32*)chunkA)[pd];
        float mu = rstat[row], ri = rstat[64 + row];
        float v0 = (bf2f(pk & 0xffffu) - mu)*ri*gg[col]     + bb[col];
        float v1 = (bf2f(pk >> 16)     - mu)*ri*gg[col + 1] + bb[col + 1];
        ((u32*)chunkA)[pd] = cvtpk(v0, v1);
    }
    __syncthreads();

    // GEMM @g1w, scale by dinv -> chunkB -> global
    {
        f32x4 acc[4][2];
#pragma unroll
        for (int mi = 0; mi < 4; ++mi)
#pragma unroll
            for (int ni = 0; ni < 2; ++ni) acc[mi][ni] = (f32x4){0.f,0.f,0.f,0.f};
#pragma unroll
        for (int kk = 0; kk < 4; ++kk) {
            short8 af[4];
#pragma unroll
            for (int mi = 0; mi < 4; ++mi) af[mi] = loadA(chunkA, mi, kk, l);
#pragma unroll
            for (int ni = 0; ni < 2; ++ni) {
                short8 bw = loadB(g1p, 2*wid + ni, kk, 4, l);
#pragma unroll
                for (int mi = 0; mi < 4; ++mi) acc[mi][ni] = MFMA16(af[mi], bw, acc[mi][ni]);
            }
        }
#pragma unroll
        for (int ni = 0; ni < 2; ++ni) {
            int col = (2*wid + ni)*16 + (l & 15);
#pragma unroll
            for (int mi = 0; mi < 4; ++mi) {
                int R = mi*16 + ((l >> 4) << 2);
                storeQuad((u32*)chunkB, R, col, l,
                          acc[mi][ni][0]*sDi[R], acc[mi][ni][1]*sDi[R+1],
                          acc[mi][ni][2]*sDi[R+2], acc[mi][ni][3]*sDi[R+3]);
            }
        }
    }
    __syncthreads();
    copyChunkOut((const u32*)chunkB, xw1p, n0, t);
}

// ---------------------------------------------------------------------------
// GCN layer 1: gather bf16 xw1p (prescaled), relu(+g1b), MFMA @g2w, *dinv -> xw2p
// ---------------------------------------------------------------------------
__global__ __launch_bounds__(256, 4)
void gcn_agg1_mfma(const u16* __restrict__ xw1p, const int* __restrict__ rp,
                   const int* __restrict__ sadj, const float* __restrict__ dinv,
                   const float* __restrict__ g1b, const u16* __restrict__ g2p,
                   u32* __restrict__ xw2p)
{
    __shared__ u16 chunkA[64*HD];
    __shared__ u16 chunkB[64*HD];
    __shared__ float sDi[64];
    __shared__ float sB[HD];

    const int t = threadIdx.x;
    const int l = t & 63;
    const int wid = t >> 6;
    const int n0 = blockIdx.x * 64;

    if (t < 64)  sDi[t] = (n0 + t < NN) ? dinv[n0 + t] : 0.f;
    if (t < HD)  sB[t] = g1b[t];
    __syncthreads();

    {
        int s = t >> 2, part = t & 3, n = n0 + s;
        float acc[32];
#pragma unroll
        for (int j = 0; j < 32; ++j) acc[j] = 0.f;
        float di = 0.f;
        if (n < NN) {
            di = sDi[s];
            const short8* selfp = (const short8*)(xw1p + (size_t)n*HD + part*32);
#pragma unroll
            for (int w = 0; w < 4; ++w) {
                short8 v = selfp[w];
#pragma unroll
                for (int j = 0; j < 8; ++j) acc[w*8+j] += bf2f((u16)v[j]);
            }
            int k1 = rp[n+1];
            for (int k = rp[n]; k < k1; ++k) {
                const short8* rp8 = (const short8*)(xw1p + (size_t)sadj[k]*HD + part*32);
#pragma unroll
                for (int w = 0; w < 4; ++w) {
                    short8 v = rp8[w];
#pragma unroll
                    for (int j = 0; j < 8; ++j) acc[w*8+j] += bf2f((u16)v[j]);
                }
            }
        }
#pragma unroll
        for (int p = 0; p < 16; ++p) {
            float v0 = fmaxf(fmaf(acc[2*p],   di, sB[part*32 + 2*p]),   0.f);
            float v1 = fmaxf(fmaf(acc[2*p+1], di, sB[part*32 + 2*p+1]), 0.f);
            int cw = part*16 + p;
            ((u32*)chunkA)[s*64 + (((cw >> 2) ^ swzr(s & 15)) << 2) + (cw & 3)] = cvtpk(v0, v1);
        }
    }
    __syncthreads();

    {
        f32x4 acc[4][2];
#pragma unroll
        for (int mi = 0; mi < 4; ++mi)
#pragma unroll
            for (int ni = 0; ni < 2; ++ni) acc[mi][ni] = (f32x4){0.f,0.f,0.f,0.f};
#pragma unroll
        for (int kk = 0; kk < 4; ++kk) {
            short8 af[4];
#pragma unroll
            for (int mi = 0; mi < 4; ++mi) af[mi] = loadA(chunkA, mi, kk, l);
#pragma unroll
            for (int ni = 0; ni < 2; ++ni) {
                short8 bw = loadB(g2p, 2*wid + ni, kk, 4, l);
#pragma unroll
                for (int mi = 0; mi < 4; ++mi) acc[mi][ni] = MFMA16(af[mi], bw, acc[mi][ni]);
            }
        }
#pragma unroll
        for (int ni = 0; ni < 2; ++ni) {
            int col = (2*wid + ni)*16 + (l & 15);
#pragma unroll
            for (int mi = 0; mi < 4; ++mi) {
                int R = mi*16 + ((l >> 4) << 2);
                storeQuad((u32*)chunkB, R, col, l,
                          acc[mi][ni][0]*sDi[R], acc[mi][ni][1]*sDi[R+1],
                          acc[mi][ni][2]*sDi[R+2], acc[mi][ni][3]*sDi[R+3]);
            }
        }
    }
    __syncthreads();
    copyChunkOut((const u32*)chunkB, xw2p, n0, t);
}

// ---------------------------------------------------------------------------
// GCN layer 2: gather bf16 xw2p, +g2b -> hbf (bf16 only)
// ---------------------------------------------------------------------------
__global__ __launch_bounds__(256)
void gcn_agg2_gather(const u16* __restrict__ xw2p, const int* __restrict__ rp,
                     const int* __restrict__ sadj, const float* __restrict__ dinv,
                     const float* __restrict__ g2b, u32* __restrict__ hbw)
{
    int t = threadIdx.x;
    int s = t >> 2, part = t & 3;
    int n = blockIdx.x * 64 + s;
    if (n >= NN) return;
    float acc[32];
#pragma unroll
    for (int j = 0; j < 32; ++j) acc[j] = 0.f;
    const short8* selfp = (const short8*)(xw2p + (size_t)n*HD + part*32);
#pragma unroll
    for (int w = 0; w < 4; ++w) {
        short8 v = selfp[w];
#pragma unroll
        for (int j = 0; j < 8; ++j) acc[w*8+j] += bf2f((u16)v[j]);
    }
    int k1 = rp[n+1];
    for (int k = rp[n]; k < k1; ++k) {
        const short8* rp8 = (const short8*)(xw2p + (size_t)sadj[k]*HD + part*32);
#pragma unroll
        for (int w = 0; w < 4; ++w) {
            short8 v = rp8[w];
#pragma unroll
            for (int j = 0; j < 8; ++j) acc[w*8+j] += bf2f((u16)v[j]);
        }
    }
    float di = dinv[n];
    u32* hb = hbw + (size_t)n*64 + part*16;
#pragma unroll
    for (int p = 0; p < 16; ++p) {
        float v0 = fmaf(acc[2*p],   di, g2b[part*32 + 2*p]);
        float v1 = fmaf(acc[2*p+1], di, g2b[part*32 + 2*p+1]);
        hb[p] = cvtpk(v0, v1);
    }
}

// ---------------------------------------------------------------------------
// Pool (batch sorted, bf16 input) + fused counts + graph MLP
// ---------------------------------------------------------------------------
#define POOL_B 512
__global__ __launch_bounds__(128)
void pool_sorted(const u16* __restrict__ h, const int* __restrict__ batch,
                 float* __restrict__ sums, float* __restrict__ cnts)
{
    int b = blockIdx.x, j = threadIdx.x;
    int n0 = (int)(((long long)NN * b) / POOL_B);
    int n1 = (int)(((long long)NN * (b+1)) / POOL_B);
    int g = -1; float acc = 0.f, cl = 0.f;
    for (int n = n0; n < n1; ++n) {
        int bg = batch[n];
        if (bg != g) {
            if (g >= 0) {
                atomicAdd(&sums[g*HD + j], acc);
                if (j == 0) atomicAdd(&cnts[g], cl);
            }
            g = bg; acc = 0.f; cl = 0.f;
        }
        acc += bf2f(h[(size_t)n*HD + j]);
        cl += 1.f;
    }
    if (g >= 0) {
        atomicAdd(&sums[g*HD + j], acc);
        if (j == 0) atomicAdd(&cnts[g], cl);
    }
}

__global__ __launch_bounds__(128)
void graph_feat(const float* __restrict__ sums, const float* __restrict__ cnts,
                const float* __restrict__ w1, const float* __restrict__ b1,
                const float* __restrict__ w2, const float* __restrict__ b2,
                const float* __restrict__ gg, const float* __restrict__ bb,
                u16* __restrict__ gf16)
{
    int gi = blockIdx.x, j = threadIdx.x;
    __shared__ float s0[HD];
    __shared__ float s1[HD];
    __shared__ float part[4];
    __shared__ float stat[2];
    float cnt = fmaxf(cnts[gi], 1.f);
    s0[j] = sums[gi*HD + j] / cnt;
    __syncthreads();
    float a = b1[j];
    for (int i = 0; i < HD; ++i) a = fmaf(s0[i], w1[i*HD + j], a);
    s1[j] = fmaxf(a, 0.f);
    __syncthreads();
    a = b2[j];
    for (int i = 0; i < HD; ++i) a = fmaf(s1[i], w2[i*HD + j], a);
    float s = a, q = a*a;
    for (int o = 32; o > 0; o >>= 1) { s += __shfl_down(s, o); q += __shfl_down(q, o); }
    int wid = j >> 6, lane = j & 63;
    if (lane == 0) { part[wid] = s; part[2 + wid] = q; }
    __syncthreads();
    if (j == 0) {
        float S = part[0] + part[1], Q = part[2] + part[3];
        float mu = S * (1.f/HD);
        stat[0] = mu;
        stat[1] = Q * (1.f/HD) - mu*mu;
    }
    __syncthreads();
    float v = (a - stat[0]) * rsqrtf(stat[1] + LN_EPS) * gg[j] + bb[j];
    gf16[gi*HD + j] = f2bf(v);
}

// ---------------------------------------------------------------------------
// Stage 64 gathered bf16 rows into swizzled LDS chunk (4 threads/row)
// ---------------------------------------------------------------------------
__device__ __forceinline__ void stageRows(u16* dst, const u16* __restrict__ srcBase,
                                          const int* ridx, int t)
{
    int e = t >> 2, part = t & 3;
    const u16* src = srcBase + (size_t)ridx[e]*HD + part*32;
    u16* drow = dst + e*128;
    int re = swzr(e & 15);
#pragma unroll
    for (int w = 0; w < 4; ++w) {
        int ci = (part*4 + w) ^ re;
        *(short8*)(drow + (ci << 3)) = *(const short8*)(src + w*8);
    }
}

// ---------------------------------------------------------------------------
// Fused edge kernel (MFMA bf16). 64 edges/block, 256 threads, 3 blocks/CU.
// No register prefetch (it was neutral at 2 blk/CU and spills at 3 blk/CU);
// all gathers staged through LDS.
// ---------------------------------------------------------------------------
__global__ __launch_bounds__(256, 3)
void edge_mlp_mfma(const u16* __restrict__ hbf, const u16* __restrict__ gfbf,
                   const int* __restrict__ ei, const int* __restrict__ batch,
                   const float* __restrict__ ea,
                   const float* __restrict__ ew1, const float* __restrict__ eb1,
                   const u16* __restrict__ ew2p, const float* __restrict__ eb2,
                   const u16* __restrict__ ew3p, const float* __restrict__ eb3,
                   const float* __restrict__ egm, const float* __restrict__ ebb,
                   const u16* __restrict__ p1wp, const float* __restrict__ p1b,
                   const u16* __restrict__ p2wp, const float* __restrict__ p2b,
                   const u16* __restrict__ p3wp, const float* __restrict__ p3b,
                   const float* __restrict__ p4w, const float* __restrict__ p4b,
                   float* __restrict__ out)
{
    __shared__ u16 bufChunk[64*HD];    // 16KB swizzled A-chunk
    __shared__ u16 bufWide[64*256];    // 32KB (2 chunks / fp32 scratch)
    __shared__ float sEa[192];
    __shared__ int sSrc[64], sDst[64], sGf[64];
    __shared__ float rstat[128];

    const int t = threadIdx.x;
    const int l = t & 63;
    const int wid = t >> 6;
    const int e0 = blockIdx.x * 64;

    if (t < 64) {
        int s = ei[e0 + t];
        sSrc[t] = s;
        sDst[t] = ei[NE + e0 + t];
        sGf[t]  = batch[s];
    }
    if (t < 192) sEa[t] = ea[e0*3 + t];
    __syncthreads();

    // ---- enc1: relu(ea@ew1+b1) -> bufChunk ----
    for (int it = 0; it < 16; ++it) {
        int dw = it*256 + t;
        int e = dw >> 6, cd = dw & 63;
        int c0 = cd*2;
        float x0 = sEa[e*3], x1 = sEa[e*3+1], x2 = sEa[e*3+2];
        float v0 = eb1[c0]   + x0*ew1[c0]   + x1*ew1[HD+c0]   + x2*ew1[2*HD+c0];
        float v1 = eb1[c0+1] + x0*ew1[c0+1] + x1*ew1[HD+c0+1] + x2*ew1[2*HD+c0+1];
        v0 = fmaxf(v0, 0.f); v1 = fmaxf(v1, 0.f);
        int ci = cd >> 2;
        ((u32*)bufChunk)[e*64 + ((ci ^ swzr(e & 15)) << 2) + (cd & 3)] = cvtpk(v0, v1);
    }
    __syncthreads();

    // ---- enc2: relu(A@ew2+b2) -> bufWide chunk0 ----
    {
        f32x4 acc[4][2];
#pragma unroll
        for (int ni = 0; ni < 2; ++ni) {
            float b = eb2[(2*wid + ni)*16 + (l & 15)];
#pragma unroll
            for (int mi = 0; mi < 4; ++mi) acc[mi][ni] = (f32x4){b,b,b,b};
        }
#pragma unroll
        for (int kk = 0; kk < 4; ++kk) {
            short8 af[4];
#pragma unroll
            for (int mi = 0; mi < 4; ++mi) af[mi] = loadA(bufChunk, mi, kk, l);
#pragma unroll
            for (int ni = 0; ni < 2; ++ni) {
                short8 bw = loadB(ew2p, 2*wid + ni, kk, 4, l);
#pragma unroll
                for (int mi = 0; mi < 4; ++mi) acc[mi][ni] = MFMA16(af[mi], bw, acc[mi][ni]);
            }
        }
#pragma unroll
        for (int ni = 0; ni < 2; ++ni) {
            int col = (2*wid + ni)*16 + (l & 15);
#pragma unroll
            for (int mi = 0; mi < 4; ++mi) {
                int R = mi*16 + ((l >> 4) << 2);
                storeQuad((u32*)bufWide, R, col, l,
                          fmaxf(acc[mi][ni][0], 0.f), fmaxf(acc[mi][ni][1], 0.f),
                          fmaxf(acc[mi][ni][2], 0.f), fmaxf(acc[mi][ni][3], 0.f));
            }
        }
    }
    __syncthreads();

    // ---- enc3: W0@ew3+b3 (pre-LN) -> bufChunk ----
    {
        f32x4 acc[4][2];
#pragma unroll
        for (int ni = 0; ni < 2; ++ni) {
            float b = eb3[(2*wid + ni)*16 + (l & 15)];
#pragma unroll
            for (int mi = 0; mi < 4; ++mi) acc[mi][ni] = (f32x4){b,b,b,b};
        }
#pragma unroll
        for (int kk = 0; kk < 4; ++kk) {
            short8 af[4];
#pragma unroll
            for (int mi = 0; mi < 4; ++mi) af[mi] = loadA(bufWide, mi, kk, l);
#pragma unroll
            for (int ni = 0; ni < 2; ++ni) {
                short8 bw = loadB(ew3p, 2*wid + ni, kk, 4, l);
#pragma unroll
                for (int mi = 0; mi < 4; ++mi) acc[mi][ni] = MFMA16(af[mi], bw, acc[mi][ni]);
            }
        }
#pragma unroll
        for (int ni = 0; ni < 2; ++ni) {
            int col = (2*wid + ni)*16 + (l & 15);
#pragma unroll
            for (int mi = 0; mi < 4; ++mi) {
                int R = mi*16 + ((l >> 4) << 2);
                storeQuad((u32*)bufChunk, R, col, l,
                          acc[mi][ni][0], acc[mi][ni][1], acc[mi][ni][2], acc[mi][ni][3]);
            }
        }
    }
    __syncthreads();

    // ---- stage h[src]->bufWide[0], h[dst]->bufWide[1] (enc2 data dead) ----
    stageRows(bufWide,        hbf, sSrc, t);
    stageRows(bufWide + 8192, hbf, sDst, t);

    // ---- LN stats: 4 lanes per edge ----
    {
        int e = wid*16 + (l >> 2);
        int q = l & 3;
        const u32* rowp = (const u32*)bufChunk + e*64;
        float s = 0.f, sq = 0.f;
#pragma unroll
        for (int i = 0; i < 16; ++i) {
            u32 pk = rowp[q*16 + ((i + e) & 15)];
            float a = bf2f(pk & 0xffffu), b = bf2f(pk >> 16);
            s += a + b;
            sq = fmaf(a, a, fmaf(b, b, sq));
        }
        s  += __shfl_xor(s, 1);  sq += __shfl_xor(sq, 1);
        s  += __shfl_xor(s, 2);  sq += __shfl_xor(sq, 2);
        if (q == 0) {
            float mu = s * (1.f/HD);
            rstat[e] = mu;
            rstat[64 + e] = rsqrtf(sq*(1.f/HD) - mu*mu + LN_EPS);
        }
    }
    __syncthreads();

    // ---- normalize in place: bufChunk = ef ----
    for (int it = 0; it < 16; ++it) {
        int pd = it*256 + t;
        int row = pd >> 6, cwd = pd & 63;
        int ci = (cwd >> 2) ^ swzr(row & 15);
        int col = ci*8 + (cwd & 3)*2;
        u32 pk = ((u32*)bufChunk)[pd];
        float mu = rstat[row], ri = rstat[64 + row];
        float v0 = (bf2f(pk & 0xffffu) - mu)*ri*egm[col]     + ebb[col];
        float v1 = (bf2f(pk >> 16)     - mu)*ri*egm[col + 1] + ebb[col + 1];
        ((u32*)bufChunk)[pd] = cvtpk(v0, v1);
    }
    __syncthreads();

    // ---- ep1 MFMA: ef (ks 12..15), hsrc (ks 0..3), hdst (ks 4..7) ----
    f32x4 acc1[4][4];
#pragma unroll
    for (int ni = 0; ni < 4; ++ni) {
        float b = p1b[(4*wid + ni)*16 + (l & 15)];
#pragma unroll
        for (int mi = 0; mi < 4; ++mi) acc1[mi][ni] = (f32x4){b,b,b,b};
    }
#pragma unroll
    for (int kk = 0; kk < 4; ++kk) {
        short8 af[4];
#pragma unroll
        for (int mi = 0; mi < 4; ++mi) af[mi] = loadA(bufChunk, mi, kk, l);
#pragma unroll
        for (int ni = 0; ni < 4; ++ni) {
            short8 bw = loadB(p1wp, 4*wid + ni, 12 + kk, 16, l);
#pragma unroll
            for (int mi = 0; mi < 4; ++mi) acc1[mi][ni] = MFMA16(af[mi], bw, acc1[mi][ni]);
        }
    }
#pragma unroll
    for (int kk = 0; kk < 4; ++kk) {
        short8 af[4];
#pragma unroll
        for (int mi = 0; mi < 4; ++mi) af[mi] = loadA(bufWide, mi, kk, l);
#pragma unroll
        for (int ni = 0; ni < 4; ++ni) {
            short8 bw = loadB(p1wp, 4*wid + ni, kk, 16, l);
#pragma unroll
            for (int mi = 0; mi < 4; ++mi) acc1[mi][ni] = MFMA16(af[mi], bw, acc1[mi][ni]);
        }
    }
#pragma unroll
    for (int kk = 0; kk < 4; ++kk) {
        short8 af[4];
#pragma unroll
        for (int mi = 0; mi < 4; ++mi) af[mi] = loadA(bufWide + 8192, mi, kk, l);
#pragma unroll
        for (int ni = 0; ni < 4; ++ni) {
            short8 bw = loadB(p1wp, 4*wid + ni, 4 + kk, 16, l);
#pragma unroll
            for (int mi = 0; mi < 4; ++mi) acc1[mi][ni] = MFMA16(af[mi], bw, acc1[mi][ni]);
        }
    }
    __syncthreads();

    // ---- stage gf -> bufChunk (ef dead), MFMA (ks 8..11), tanh -> bufWide ----
    stageRows(bufChunk, gfbf, sGf, t);
    __syncthreads();
#pragma unroll
    for (int kk = 0; kk < 4; ++kk) {
        short8 af[4];
#pragma unroll
        for (int mi = 0; mi < 4; ++mi) af[mi] = loadA(bufChunk, mi, kk, l);
#pragma unroll
        for (int ni = 0; ni < 4; ++ni) {
            short8 bw = loadB(p1wp, 4*wid + ni, 8 + kk, 16, l);
#pragma unroll
            for (int mi = 0; mi < 4; ++mi) acc1[mi][ni] = MFMA16(af[mi], bw, acc1[mi][ni]);
        }
    }
#pragma unroll
    for (int ni = 0; ni < 4; ++ni) {
        int col = (4*wid + ni)*16 + (l & 15);
        u32* dst = (u32*)bufWide + ((col >> 7) << 12);
        int cc = col & 127;
#pragma unroll
        for (int mi = 0; mi < 4; ++mi) {
            int R = mi*16 + ((l >> 4) << 2);
            storeQuad(dst, R, cc, l,
                      fast_tanh(acc1[mi][ni][0]), fast_tanh(acc1[mi][ni][1]),
                      fast_tanh(acc1[mi][ni][2]), fast_tanh(acc1[mi][ni][3]));
        }
    }
    __syncthreads();

    // ---- ep2: [64,256]@p2w[256,128], tanh -> bufChunk ----
    {
        f32x4 acc[4][2];
#pragma unroll
        for (int ni = 0; ni < 2; ++ni) {
            float b = p2b[(2*wid + ni)*16 + (l & 15)];
#pragma unroll
            for (int mi = 0; mi < 4; ++mi) acc[mi][ni] = (f32x4){b,b,b,b};
        }
        for (int kc = 0; kc < 2; ++kc) {
            const u16* abuf = bufWide + (kc << 13);
#pragma unroll
            for (int kk = 0; kk < 4; ++kk) {
                short8 af[4];
#pragma unroll
                for (int mi = 0; mi < 4; ++mi) af[mi] = loadA(abuf, mi, kk, l);
                int ks = kc*4 + kk;
#pragma unroll
                for (int ni = 0; ni < 2; ++ni) {
                    short8 bw = loadB(p2wp, 2*wid + ni, ks, 8, l);
#pragma unroll
                    for (int mi = 0; mi < 4; ++mi) acc[mi][ni] = MFMA16(af[mi], bw, acc[mi][ni]);
                }
            }
        }
#pragma unroll
        for (int ni = 0; ni < 2; ++ni) {
            int col = (2*wid + ni)*16 + (l & 15);
#pragma unroll
            for (int mi = 0; mi < 4; ++mi) {
                int R = mi*16 + ((l >> 4) << 2);
                storeQuad((u32*)bufChunk, R, col, l,
                          fast_tanh(acc[mi][ni][0]), fast_tanh(acc[mi][ni][1]),
                          fast_tanh(acc[mi][ni][2]), fast_tanh(acc[mi][ni][3]));
            }
        }
    }
    __syncthreads();

    // ---- ep3: [64,128]@p3w[128,64], relu -> bufWide fp32 stride-65 ----
    {
        f32x4 acc[4];
        {
            float b = p3b[wid*16 + (l & 15)];
#pragma unroll
            for (int mi = 0; mi < 4; ++mi) acc[mi] = (f32x4){b,b,b,b};
        }
#pragma unroll
        for (int kk = 0; kk < 4; ++kk) {
            short8 af[4];
#pragma unroll
            for (int mi = 0; mi < 4; ++mi) af[mi] = loadA(bufChunk, mi, kk, l);
            short8 bw = loadB(p3wp, wid, kk, 4, l);
#pragma unroll
            for (int mi = 0; mi < 4; ++mi) acc[mi] = MFMA16(af[mi], bw, acc[mi]);
        }
        float* fb = (float*)bufWide;
        int col = wid*16 + (l & 15);
#pragma unroll
        for (int mi = 0; mi < 4; ++mi)
#pragma unroll
            for (int rr = 0; rr < 4; ++rr) {
                int row = mi*16 + ((l >> 4) << 2) + rr;
                fb[row*65 + col] = fmaxf(acc[mi][rr], 0.f);
            }
    }
    __syncthreads();

    // ---- ep4: 4 lanes/edge dot-64 + sigmoid ----
    {
        const float* fb = (const float*)bufWide;
        int e = wid*16 + (l >> 2), q = l & 3;
        float v = 0.f;
#pragma unroll
        for (int k = 0; k < 16; ++k) {
            int i = q*16 + k;
            v = fmaf(fb[e*65 + i], p4w[i], v);
        }
        v += __shfl_xor(v, 1);
        v += __shfl_xor(v, 2);
        if (q == 0) out[e0 + e] = fast_sigmoid(v + p4b[0]);
    }
}

// ---------------------------------------------------------------------------
extern "C" void kernel_launch(void* const* d_in, const int* in_sizes, int n_in,
                              void* d_out, int out_size, void* d_ws, size_t ws_size,
                              hipStream_t stream)
{
    const float* x     = (const float*)d_in[0];
    const int*   ei    = (const int*)  d_in[1];
    const float* ea    = (const float*)d_in[2];
    const int*   batch = (const int*)  d_in[3];
    const float* ne1w = (const float*)d_in[4];  const float* ne1b = (const float*)d_in[5];
    const float* ne2w = (const float*)d_in[6];  const float* ne2b = (const float*)d_in[7];
    const float* ne3w = (const float*)d_in[8];  const float* ne3b = (const float*)d_in[9];
    const float* neg  = (const float*)d_in[10]; const float* nebb = (const float*)d_in[11];
    const float* ee1w = (const float*)d_in[12]; const float* ee1b = (const float*)d_in[13];
    const float* ee2w = (const float*)d_in[14]; const float* ee2b = (const float*)d_in[15];
    const float* ee3w = (const float*)d_in[16]; const float* ee3b = (const float*)d_in[17];
    const float* eeg  = (const float*)d_in[18]; const float* eebb = (const float*)d_in[19];
    const float* g1w  = (const float*)d_in[20]; const float* g1b  = (const float*)d_in[21];
    const float* g2w  = (const float*)d_in[22]; const float* g2b  = (const float*)d_in[23];
    const float* gp1w = (const float*)d_in[24]; const float* gp1b = (const float*)d_in[25];
    const float* gp2w = (const float*)d_in[26]; const float* gp2b = (const float*)d_in[27];
    const float* gpg  = (const float*)d_in[28]; const float* gpbb = (const float*)d_in[29];
    const float* p1w  = (const float*)d_in[30]; const float* p1b  = (const float*)d_in[31];
    const float* p2w  = (const float*)d_in[32]; const float* p2b  = (const float*)d_in[33];
    const float* p3w  = (const float*)d_in[34]; const float* p3b  = (const float*)d_in[35];
    const float* p4w  = (const float*)d_in[36]; const float* p4b  = (const float*)d_in[37];

    float* dinv = (float*)d_ws;                // NN
    float* sums = dinv + NN;                   // NG*HD
    float* cnts = sums + NG*HD;                // NG
    int* degi   = (int*)(cnts + NG);           // NN
    int* cursor = degi + NN;                   // NN+2
    int* rowptr = cursor + NN + 2;             // NN+2
    int* sadj   = rowptr + NN + 2;             // NE
    u16* xw1p   = (u16*)(sadj + NE);           // NN*HD
    u16* xw2p   = xw1p + (size_t)NN*HD;        // NN*HD
    u16* hbf    = xw2p + (size_t)NN*HD;        // NN*HD
    u16* gf16   = hbf + (size_t)NN*HD;         // NG*HD
    u16* wpk    = gf16 + NG*HD;                // 270336
    u16* ee2p = wpk;
    u16* ee3p = wpk + 16384;
    u16* p1p  = wpk + 32768;
    u16* p2p  = wpk + 163840;
    u16* p3p  = wpk + 196608;
    u16* ne2p = wpk + 204800;
    u16* ne3p = wpk + 221184;
    u16* g1p  = wpk + 237568;
    u16* g2p  = wpk + 253952;

    float* out = (float*)d_out;

    hipMemsetAsync(degi, 0, (size_t)(2*NN + 2)*sizeof(int), stream);
    hipMemsetAsync(sums, 0, (size_t)(NG*HD + NG)*sizeof(float), stream);

    pack_all<<<(270336 + 255)/256, 256, 0, stream>>>(ee2w, ee3w, p1w, p2w, p3w,
                                                     ne2w, ne3w, g1w, g2w, wpk);

    // CSR build (+dinv fused into scan)
    deg_count_int<<<(NE + 255)/256, 256, 0, stream>>>(ei, degi);
    scan_excl<<<1, 1024, 0, stream>>>(degi, rowptr, dinv);
    fill_csr<<<(NE + 255)/256, 256, 0, stream>>>(ei, rowptr, cursor, sadj);

    // node encoder + g1 GEMM (bf16 out, prescaled by dinv)
    enc_mfma<<<(NN + 63)/64, 256, 0, stream>>>(x, ne1w, ne1b, ne2p, ne2b, ne3p, ne3b,
                                               neg, nebb, g1p, dinv, (u32*)xw1p);
    // GCN1 gather + relu + g2 GEMM
    gcn_agg1_mfma<<<(NN + 63)/64, 256, 0, stream>>>(xw1p, rowptr, sadj, dinv,
                                                    g1b, g2p, (u32*)xw2p);
    // GCN2 gather -> hbf bf16
    gcn_agg2_gather<<<(NN + 63)/64, 256, 0, stream>>>(xw2p, rowptr, sadj, dinv,
                                                      g2b, (u32*)hbf);

    // pool (+counts fused) + graph MLP
    pool_sorted<<<POOL_B, 128, 0, stream>>>(hbf, batch, sums, cnts);
    graph_feat<<<NG, 128, 0, stream>>>(sums, cnts, gp1w, gp1b, gp2w, gp2b,
                                       gpg, gpbb, gf16);

    // fused edge encoder + edge-score MLP
    edge_mlp_mfma<<<NE/64, 256, 0, stream>>>(hbf, gf16, ei, batch, ea,
                                             ee1w, ee1b, ee2p, ee2b, ee3p, ee3b,
                                             eeg, eebb,
                                             p1p, p1b, p2p, p2b, p3p, p3b,
                                             p4w, p4b, out);
}

// Round 8
// 532.692 us; speedup vs baseline: 9.6409x; 1.2047x over previous
//
#include <hip/hip_runtime.h>
#include <math.h>

#define NN 50000
#define NE 400000
#define NG 64
#define HD 128
#define LN_EPS 1e-5f

typedef unsigned short u16;
typedef unsigned int u32;
typedef __attribute__((ext_vector_type(8))) short short8;
typedef __attribute__((ext_vector_type(4))) float f32x4;

#define MFMA16(a,b,c) __builtin_amdgcn_mfma_f32_16x16x32_bf16((a),(b),(c),0,0,0)

__device__ __forceinline__ u16 f2bf(float f) {
    union { float f; u32 u; } v; v.f = f;
    u32 r = v.u + 0x7FFFu + ((v.u >> 16) & 1u);
    return (u16)(r >> 16);
}
__device__ __forceinline__ float bf2f(u32 hs) {
    union { u32 u; float f; } v; v.u = hs << 16;
    return v.f;
}
__device__ __forceinline__ float fast_rcp(float x) {
    float r; asm("v_rcp_f32 %0, %1" : "=v"(r) : "v"(x)); return r;
}
__device__ __forceinline__ float fast_exp2(float x) {
    float r; asm("v_exp_f32 %0, %1" : "=v"(r) : "v"(x)); return r;
}
__device__ __forceinline__ u32 cvtpk(float lo, float hi) {
    u32 r; asm("v_cvt_pk_bf16_f32 %0, %1, %2" : "=v"(r) : "v"(lo), "v"(hi)); return r;
}
// tanh(x) = 1 - 2/(1+2^(2*log2e*x)); exp2 saturates correctly at +-inf
__device__ __forceinline__ float fast_tanh(float x) {
    return fmaf(-2.f, fast_rcp(1.f + fast_exp2(2.885390082f * x)), 1.f);
}
__device__ __forceinline__ float fast_sigmoid(float x) {
    return fast_rcp(1.f + fast_exp2(-1.442695041f * x));
}

// swizzle term for row within 16-row group
__device__ __forceinline__ int swzr(int row) {
    return (row & 7) ^ ((row & 8) >> 2);
}

// A-fragment load from swizzled [64][128] bf16 chunk buffer.
__device__ __forceinline__ short8 loadA(const u16* buf, int mi, int kk, int l) {
    int row = mi*16 + (l & 15);
    int ci  = (kk*4 + (l >> 4)) ^ swzr(l & 15);
    return *(const short8*)(buf + row*128 + (ci << 3));
}
__device__ __forceinline__ short8 loadB(const u16* wp, int nt, int ks, int nk, int l) {
    return *(const short8*)(wp + (((nt*nk + ks)*64 + l) << 3));
}

// Store 4 accumulator values (rows R..R+3, col c) into swizzled bf16 chunk as
// packed u32 via lane-pair exchange + v_cvt_pk_bf16_f32.
__device__ __forceinline__ void storeQuad(u32* buf, int R, int c, int l,
                                          float v0, float v1, float v2, float v3)
{
    int cw = c >> 1;
    int par = l & 1;
    float send = par ? v0 : v1;
    float recv = __shfl_xor(send, 1);
    int row = R + par;
    u32 word = par ? cvtpk(recv, v1) : cvtpk(v0, recv);
    buf[row*64 + (((cw >> 2) ^ swzr(row & 15)) << 2) + (cw & 3)] = word;
    send = par ? v2 : v3;
    recv = __shfl_xor(send, 1);
    row = R + 2 + par;
    word = par ? cvtpk(recv, v3) : cvtpk(v2, recv);
    buf[row*64 + (((cw >> 2) ^ swzr(row & 15)) << 2) + (cw & 3)] = word;
}

// Unswizzle copy: LDS chunk -> global bf16 [64][128] rows n0..n0+63 (u32 words)
__device__ __forceinline__ void copyChunkOut(const u32* chunk, u32* gout, int n0, int t)
{
    for (int it = 0; it < 16; ++it) {
        int dw = it*256 + t;
        int row = dw >> 6, cw = dw & 63;
        if (n0 + row < NN)
            gout[(size_t)(n0 + row)*64 + cw] =
                chunk[row*64 + (((cw >> 2) ^ swzr(row & 15)) << 2) + (cw & 3)];
    }
}

// ---------------------------------------------------------------------------
// One-shot weight packing of all 9 GEMM weights -> bf16 MFMA B-fragment order.
// ---------------------------------------------------------------------------
__global__ __launch_bounds__(256)
void pack_all(const float* __restrict__ ee2w, const float* __restrict__ ee3w,
              const float* __restrict__ p1w,  const float* __restrict__ p2w,
              const float* __restrict__ p3w,  const float* __restrict__ ne2w,
              const float* __restrict__ ne3w, const float* __restrict__ g1w,
              const float* __restrict__ g2w,  u16* __restrict__ wpk)
{
    int idx = blockIdx.x*256 + threadIdx.x;
    if (idx >= 270336) return;
    const float* w; int K, N, local;
    if      (idx < 16384)  { w = ee2w; K = 128; N = 128; local = idx; }
    else if (idx < 32768)  { w = ee3w; K = 128; N = 128; local = idx - 16384; }
    else if (idx < 163840) { w = p1w;  K = 512; N = 256; local = idx - 32768; }
    else if (idx < 196608) { w = p2w;  K = 256; N = 128; local = idx - 163840; }
    else if (idx < 204800) { w = p3w;  K = 128; N = 64;  local = idx - 196608; }
    else if (idx < 221184) { w = ne2w; K = 128; N = 128; local = idx - 204800; }
    else if (idx < 237568) { w = ne3w; K = 128; N = 128; local = idx - 221184; }
    else if (idx < 253952) { w = g1w;  K = 128; N = 128; local = idx - 237568; }
    else                   { w = g2w;  K = 128; N = 128; local = idx - 253952; }
    int e = local & 7, l = (local >> 3) & 63, r = local >> 9;
    int nk = K >> 5;
    int nt = r / nk, kk = r % nk;
    int k = kk*32 + ((l >> 4) << 3) + e;
    int n = nt*16 + (l & 15);
    wpk[idx] = f2bf(w[k*N + n]);
}

// ---------------------------------------------------------------------------
// CSR build
// ---------------------------------------------------------------------------
__global__ __launch_bounds__(256)
void deg_count_int(const int* __restrict__ ei, int* __restrict__ degi)
{
    int e = blockIdx.x*256 + threadIdx.x;
    if (e < NE) atomicAdd(&degi[ei[NE + e]], 1);
}

__global__ __launch_bounds__(1024)
void scan_excl(const int* __restrict__ cnt, int* __restrict__ rp,
               float* __restrict__ dinv)
{
    __shared__ int wsum[16];
    __shared__ int carry;
    int t = threadIdx.x, lane = t & 63, w = t >> 6;
    int base = 0;
    for (int off = 0; off < NN; off += 4096) {
        int i0 = off + t*4;
        int v0 = (i0   < NN) ? cnt[i0]   : 0;
        int v1 = (i0+1 < NN) ? cnt[i0+1] : 0;
        int v2 = (i0+2 < NN) ? cnt[i0+2] : 0;
        int v3 = (i0+3 < NN) ? cnt[i0+3] : 0;
        int tot = v0 + v1 + v2 + v3;
        int s = tot;
#pragma unroll
        for (int d = 1; d < 64; d <<= 1) { int u = __shfl_up(s, d); if (lane >= d) s += u; }
        if (lane == 63) wsum[w] = s;
        __syncthreads();
        if (w == 0) {
            int wv = (lane < 16) ? wsum[lane] : 0;
            int ss = wv;
#pragma unroll
            for (int d = 1; d < 16; d <<= 1) { int u = __shfl_up(ss, d); if (lane >= d) ss += u; }
            if (lane < 16) wsum[lane] = ss - wv;
            if (lane == 15) carry = ss;
        }
        __syncthreads();
        int excl = base + wsum[w] + s - tot;
        if (i0   < NN) { rp[i0]   = excl;              dinv[i0]   = rsqrtf((float)v0 + 1.f); }
        if (i0+1 < NN) { rp[i0+1] = excl + v0;         dinv[i0+1] = rsqrtf((float)v1 + 1.f); }
        if (i0+2 < NN) { rp[i0+2] = excl + v0 + v1;    dinv[i0+2] = rsqrtf((float)v2 + 1.f); }
        if (i0+3 < NN) { rp[i0+3] = excl + v0 + v1 + v2; dinv[i0+3] = rsqrtf((float)v3 + 1.f); }
        base += carry;
        __syncthreads();
    }
    if (t == 0) rp[NN] = base;
}

__global__ __launch_bounds__(256)
void fill_csr(const int* __restrict__ ei, const int* __restrict__ rp,
              int* __restrict__ cursor, int* __restrict__ sadj)
{
    int e = blockIdx.x*256 + threadIdx.x;
    if (e >= NE) return;
    int d = ei[NE + e];
    int slot = atomicAdd(&cursor[d], 1);
    sadj[rp[d] + slot] = ei[e];
}

// ---------------------------------------------------------------------------
// Node encoder + g1w GEMM, MFMA. 64 nodes/block, 256 threads.
// ---------------------------------------------------------------------------
__global__ __launch_bounds__(256, 4)
void enc_mfma(const float* __restrict__ x,
              const float* __restrict__ w1, const float* __restrict__ b1,
              const u16* __restrict__ w2p, const float* __restrict__ b2,
              const u16* __restrict__ w3p, const float* __restrict__ b3,
              const float* __restrict__ gg, const float* __restrict__ bb,
              const u16* __restrict__ g1p, const float* __restrict__ dinv,
              u32* __restrict__ xw1p)
{
    __shared__ u16 chunkA[64*HD];
    __shared__ u16 chunkB[64*HD];
    __shared__ float sX[192];
    __shared__ float sDi[64];
    __shared__ float rstat[128];

    const int t = threadIdx.x;
    const int l = t & 63;
    const int wid = t >> 6;
    const int n0 = blockIdx.x * 64;

    if (t < 192) sX[t] = (n0*3 + t < NN*3) ? x[n0*3 + t] : 0.f;
    if (t < 64)  sDi[t] = (n0 + t < NN) ? dinv[n0 + t] : 0.f;
    __syncthreads();

    // L1: 3->128 relu (VALU) -> chunkA
    for (int it = 0; it < 16; ++it) {
        int dw = it*256 + t;
        int e = dw >> 6, cd = dw & 63;
        int c0 = cd*2;
        float x0 = sX[e*3], x1 = sX[e*3+1], x2 = sX[e*3+2];
        float v0 = b1[c0]   + x0*w1[c0]   + x1*w1[HD+c0]   + x2*w1[2*HD+c0];
        float v1 = b1[c0+1] + x0*w1[c0+1] + x1*w1[HD+c0+1] + x2*w1[2*HD+c0+1];
        v0 = fmaxf(v0, 0.f); v1 = fmaxf(v1, 0.f);
        int ci = cd >> 2;
        ((u32*)chunkA)[e*64 + ((ci ^ swzr(e & 15)) << 2) + (cd & 3)] = cvtpk(v0, v1);
    }
    __syncthreads();

    // L2 MFMA: relu(A@w2+b2) -> chunkB
    {
        f32x4 acc[4][2];
#pragma unroll
        for (int ni = 0; ni < 2; ++ni) {
            float b = b2[(2*wid + ni)*16 + (l & 15)];
#pragma unroll
            for (int mi = 0; mi < 4; ++mi) acc[mi][ni] = (f32x4){b,b,b,b};
        }
#pragma unroll
        for (int kk = 0; kk < 4; ++kk) {
            short8 af[4];
#pragma unroll
            for (int mi = 0; mi < 4; ++mi) af[mi] = loadA(chunkA, mi, kk, l);
#pragma unroll
            for (int ni = 0; ni < 2; ++ni) {
                short8 bw = loadB(w2p, 2*wid + ni, kk, 4, l);
#pragma unroll
                for (int mi = 0; mi < 4; ++mi) acc[mi][ni] = MFMA16(af[mi], bw, acc[mi][ni]);
            }
        }
#pragma unroll
        for (int ni = 0; ni < 2; ++ni) {
            int col = (2*wid + ni)*16 + (l & 15);
#pragma unroll
            for (int mi = 0; mi < 4; ++mi) {
                int R = mi*16 + ((l >> 4) << 2);
                storeQuad((u32*)chunkB, R, col, l,
                          fmaxf(acc[mi][ni][0], 0.f), fmaxf(acc[mi][ni][1], 0.f),
                          fmaxf(acc[mi][ni][2], 0.f), fmaxf(acc[mi][ni][3], 0.f));
            }
        }
    }
    __syncthreads();

    // L3 MFMA: B@w3+b3 (pre-LN) -> chunkA
    {
        f32x4 acc[4][2];
#pragma unroll
        for (int ni = 0; ni < 2; ++ni) {
            float b = b3[(2*wid + ni)*16 + (l & 15)];
#pragma unroll
            for (int mi = 0; mi < 4; ++mi) acc[mi][ni] = (f32x4){b,b,b,b};
        }
#pragma unroll
        for (int kk = 0; kk < 4; ++kk) {
            short8 af[4];
#pragma unroll
            for (int mi = 0; mi < 4; ++mi) af[mi] = loadA(chunkB, mi, kk, l);
#pragma unroll
            for (int ni = 0; ni < 2; ++ni) {
                short8 bw = loadB(w3p, 2*wid + ni, kk, 4, l);
#pragma unroll
                for (int mi = 0; mi < 4; ++mi) acc[mi][ni] = MFMA16(af[mi], bw, acc[mi][ni]);
            }
        }
#pragma unroll
        for (int ni = 0; ni < 2; ++ni) {
            int col = (2*wid + ni)*16 + (l & 15);
#pragma unroll
            for (int mi = 0; mi < 4; ++mi) {
                int R = mi*16 + ((l >> 4) << 2);
                storeQuad((u32*)chunkA, R, col, l,
                          acc[mi][ni][0], acc[mi][ni][1], acc[mi][ni][2], acc[mi][ni][3]);
            }
        }
    }
    __syncthreads();

    // LN stats: 4 lanes per row
    {
        int e = wid*16 + (l >> 2);
        int q = l & 3;
        const u32* rowp = (const u32*)chunkA + e*64;
        float s = 0.f, sq = 0.f;
#pragma unroll
        for (int i = 0; i < 16; ++i) {
            u32 pk = rowp[q*16 + ((i + e) & 15)];
            float a = bf2f(pk & 0xffffu), b = bf2f(pk >> 16);
            s += a + b;
            sq = fmaf(a, a, fmaf(b, b, sq));
        }
        s  += __shfl_xor(s, 1);  sq += __shfl_xor(sq, 1);
        s  += __shfl_xor(s, 2);  sq += __shfl_xor(sq, 2);
        if (q == 0) {
            float mu = s * (1.f/HD);
            rstat[e] = mu;
            rstat[64 + e] = rsqrtf(sq*(1.f/HD) - mu*mu + LN_EPS);
        }
    }
    __syncthreads();

    // normalize in place
    for (int it = 0; it < 16; ++it) {
        int pd = it*256 + t;
        int row = pd >> 6, cwd = pd & 63;
        int ci = (cwd >> 2) ^ swzr(row & 15);
        int col = ci*8 + (cwd & 3)*2;
        u32 pk = ((u32*)chunkA)[pd];
        float mu = rstat[row], ri = rstat[64 + row];
        float v0 = (bf2f(pk & 0xffffu) - mu)*ri*gg[col]     + bb[col];
        float v1 = (bf2f(pk >> 16)     - mu)*ri*gg[col + 1] + bb[col + 1];
        ((u32*)chunkA)[pd] = cvtpk(v0, v1);
    }
    __syncthreads();

    // GEMM @g1w, scale by dinv -> chunkB -> global
    {
        f32x4 acc[4][2];
#pragma unroll
        for (int mi = 0; mi < 4; ++mi)
#pragma unroll
            for (int ni = 0; ni < 2; ++ni) acc[mi][ni] = (f32x4){0.f,0.f,0.f,0.f};
#pragma unroll
        for (int kk = 0; kk < 4; ++kk) {
            short8 af[4];
#pragma unroll
            for (int mi = 0; mi < 4; ++mi) af[mi] = loadA(chunkA, mi, kk, l);
#pragma unroll
            for (int ni = 0; ni < 2; ++ni) {
                short8 bw = loadB(g1p, 2*wid + ni, kk, 4, l);
#pragma unroll
                for (int mi = 0; mi < 4; ++mi) acc[mi][ni] = MFMA16(af[mi], bw, acc[mi][ni]);
            }
        }
#pragma unroll
        for (int ni = 0; ni < 2; ++ni) {
            int col = (2*wid + ni)*16 + (l & 15);
#pragma unroll
            for (int mi = 0; mi < 4; ++mi) {
                int R = mi*16 + ((l >> 4) << 2);
                storeQuad((u32*)chunkB, R, col, l,
                          acc[mi][ni][0]*sDi[R], acc[mi][ni][1]*sDi[R+1],
                          acc[mi][ni][2]*sDi[R+2], acc[mi][ni][3]*sDi[R+3]);
            }
        }
    }
    __syncthreads();
    copyChunkOut((const u32*)chunkB, xw1p, n0, t);
}

// ---------------------------------------------------------------------------
// GCN layer 1: gather bf16 xw1p (prescaled), relu(+g1b), MFMA @g2w, *dinv -> xw2p
// ---------------------------------------------------------------------------
__global__ __launch_bounds__(256, 4)
void gcn_agg1_mfma(const u16* __restrict__ xw1p, const int* __restrict__ rp,
                   const int* __restrict__ sadj, const float* __restrict__ dinv,
                   const float* __restrict__ g1b, const u16* __restrict__ g2p,
                   u32* __restrict__ xw2p)
{
    __shared__ u16 chunkA[64*HD];
    __shared__ u16 chunkB[64*HD];
    __shared__ float sDi[64];
    __shared__ float sB[HD];

    const int t = threadIdx.x;
    const int l = t & 63;
    const int wid = t >> 6;
    const int n0 = blockIdx.x * 64;

    if (t < 64)  sDi[t] = (n0 + t < NN) ? dinv[n0 + t] : 0.f;
    if (t < HD)  sB[t] = g1b[t];
    __syncthreads();

    {
        int s = t >> 2, part = t & 3, n = n0 + s;
        float acc[32];
#pragma unroll
        for (int j = 0; j < 32; ++j) acc[j] = 0.f;
        float di = 0.f;
        if (n < NN) {
            di = sDi[s];
            const short8* selfp = (const short8*)(xw1p + (size_t)n*HD + part*32);
#pragma unroll
            for (int w = 0; w < 4; ++w) {
                short8 v = selfp[w];
#pragma unroll
                for (int j = 0; j < 8; ++j) acc[w*8+j] += bf2f((u16)v[j]);
            }
            int k1 = rp[n+1];
            for (int k = rp[n]; k < k1; ++k) {
                const short8* rp8 = (const short8*)(xw1p + (size_t)sadj[k]*HD + part*32);
#pragma unroll
                for (int w = 0; w < 4; ++w) {
                    short8 v = rp8[w];
#pragma unroll
                    for (int j = 0; j < 8; ++j) acc[w*8+j] += bf2f((u16)v[j]);
                }
            }
        }
#pragma unroll
        for (int p = 0; p < 16; ++p) {
            float v0 = fmaxf(fmaf(acc[2*p],   di, sB[part*32 + 2*p]),   0.f);
            float v1 = fmaxf(fmaf(acc[2*p+1], di, sB[part*32 + 2*p+1]), 0.f);
            int cw = part*16 + p;
            ((u32*)chunkA)[s*64 + (((cw >> 2) ^ swzr(s & 15)) << 2) + (cw & 3)] = cvtpk(v0, v1);
        }
    }
    __syncthreads();

    {
        f32x4 acc[4][2];
#pragma unroll
        for (int mi = 0; mi < 4; ++mi)
#pragma unroll
            for (int ni = 0; ni < 2; ++ni) acc[mi][ni] = (f32x4){0.f,0.f,0.f,0.f};
#pragma unroll
        for (int kk = 0; kk < 4; ++kk) {
            short8 af[4];
#pragma unroll
            for (int mi = 0; mi < 4; ++mi) af[mi] = loadA(chunkA, mi, kk, l);
#pragma unroll
            for (int ni = 0; ni < 2; ++ni) {
                short8 bw = loadB(g2p, 2*wid + ni, kk, 4, l);
#pragma unroll
                for (int mi = 0; mi < 4; ++mi) acc[mi][ni] = MFMA16(af[mi], bw, acc[mi][ni]);
            }
        }
#pragma unroll
        for (int ni = 0; ni < 2; ++ni) {
            int col = (2*wid + ni)*16 + (l & 15);
#pragma unroll
            for (int mi = 0; mi < 4; ++mi) {
                int R = mi*16 + ((l >> 4) << 2);
                storeQuad((u32*)chunkB, R, col, l,
                          acc[mi][ni][0]*sDi[R], acc[mi][ni][1]*sDi[R+1],
                          acc[mi][ni][2]*sDi[R+2], acc[mi][ni][3]*sDi[R+3]);
            }
        }
    }
    __syncthreads();
    copyChunkOut((const u32*)chunkB, xw2p, n0, t);
}

// ---------------------------------------------------------------------------
// GCN layer 2: gather bf16 xw2p, +g2b -> hbf (bf16 only)
// ---------------------------------------------------------------------------
__global__ __launch_bounds__(256)
void gcn_agg2_gather(const u16* __restrict__ xw2p, const int* __restrict__ rp,
                     const int* __restrict__ sadj, const float* __restrict__ dinv,
                     const float* __restrict__ g2b, u32* __restrict__ hbw)
{
    int t = threadIdx.x;
    int s = t >> 2, part = t & 3;
    int n = blockIdx.x * 64 + s;
    if (n >= NN) return;
    float acc[32];
#pragma unroll
    for (int j = 0; j < 32; ++j) acc[j] = 0.f;
    const short8* selfp = (const short8*)(xw2p + (size_t)n*HD + part*32);
#pragma unroll
    for (int w = 0; w < 4; ++w) {
        short8 v = selfp[w];
#pragma unroll
        for (int j = 0; j < 8; ++j) acc[w*8+j] += bf2f((u16)v[j]);
    }
    int k1 = rp[n+1];
    for (int k = rp[n]; k < k1; ++k) {
        const short8* rp8 = (const short8*)(xw2p + (size_t)sadj[k]*HD + part*32);
#pragma unroll
        for (int w = 0; w < 4; ++w) {
            short8 v = rp8[w];
#pragma unroll
            for (int j = 0; j < 8; ++j) acc[w*8+j] += bf2f((u16)v[j]);
        }
    }
    float di = dinv[n];
    u32* hb = hbw + (size_t)n*64 + part*16;
#pragma unroll
    for (int p = 0; p < 16; ++p) {
        float v0 = fmaf(acc[2*p],   di, g2b[part*32 + 2*p]);
        float v1 = fmaf(acc[2*p+1], di, g2b[part*32 + 2*p+1]);
        hb[p] = cvtpk(v0, v1);
    }
}

// ---------------------------------------------------------------------------
// Pool (batch sorted, bf16 input) + fused counts + graph MLP.
// graph_feat also precomputes gfp1[g][0:256] = gf[g] @ p1w[256:384,:] (fp32).
// ---------------------------------------------------------------------------
#define POOL_B 512
__global__ __launch_bounds__(128)
void pool_sorted(const u16* __restrict__ h, const int* __restrict__ batch,
                 float* __restrict__ sums, float* __restrict__ cnts)
{
    int b = blockIdx.x, j = threadIdx.x;
    int n0 = (int)(((long long)NN * b) / POOL_B);
    int n1 = (int)(((long long)NN * (b+1)) / POOL_B);
    int g = -1; float acc = 0.f, cl = 0.f;
    for (int n = n0; n < n1; ++n) {
        int bg = batch[n];
        if (bg != g) {
            if (g >= 0) {
                atomicAdd(&sums[g*HD + j], acc);
                if (j == 0) atomicAdd(&cnts[g], cl);
            }
            g = bg; acc = 0.f; cl = 0.f;
        }
        acc += bf2f(h[(size_t)n*HD + j]);
        cl += 1.f;
    }
    if (g >= 0) {
        atomicAdd(&sums[g*HD + j], acc);
        if (j == 0) atomicAdd(&cnts[g], cl);
    }
}

__global__ __launch_bounds__(128)
void graph_feat(const float* __restrict__ sums, const float* __restrict__ cnts,
                const float* __restrict__ w1, const float* __restrict__ b1,
                const float* __restrict__ w2, const float* __restrict__ b2,
                const float* __restrict__ gg, const float* __restrict__ bb,
                const float* __restrict__ p1w, float* __restrict__ gfp1)
{
    int gi = blockIdx.x, j = threadIdx.x;
    __shared__ float s0[HD];
    __shared__ float s1[HD];
    __shared__ float part[4];
    __shared__ float stat[2];
    float cnt = fmaxf(cnts[gi], 1.f);
    s0[j] = sums[gi*HD + j] / cnt;
    __syncthreads();
    float a = b1[j];
    for (int i = 0; i < HD; ++i) a = fmaf(s0[i], w1[i*HD + j], a);
    s1[j] = fmaxf(a, 0.f);
    __syncthreads();
    a = b2[j];
    for (int i = 0; i < HD; ++i) a = fmaf(s1[i], w2[i*HD + j], a);
    float s = a, q = a*a;
    for (int o = 32; o > 0; o >>= 1) { s += __shfl_down(s, o); q += __shfl_down(q, o); }
    int wid = j >> 6, lane = j & 63;
    if (lane == 0) { part[wid] = s; part[2 + wid] = q; }
    __syncthreads();
    if (j == 0) {
        float S = part[0] + part[1], Q = part[2] + part[3];
        float mu = S * (1.f/HD);
        stat[0] = mu;
        stat[1] = Q * (1.f/HD) - mu*mu;
    }
    __syncthreads();
    float v = (a - stat[0]) * rsqrtf(stat[1] + LN_EPS) * gg[j] + bb[j];
    __syncthreads();
    s0[j] = v;        // gf row for this graph (fp32)
    __syncthreads();
    // gfp1[gi][j] and [gi][j+128]: dot over gf-chunk of p1w (comb rows 256..383)
    float a0 = 0.f, a1 = 0.f;
    for (int k = 0; k < HD; ++k) {
        float gv = s0[k];
        a0 = fmaf(gv, p1w[(size_t)(256 + k)*256 + j],       a0);
        a1 = fmaf(gv, p1w[(size_t)(256 + k)*256 + j + 128], a1);
    }
    gfp1[gi*256 + j]       = a0;
    gfp1[gi*256 + j + 128] = a1;
}

// ---------------------------------------------------------------------------
// Stage 64 gathered bf16 rows into swizzled LDS chunk (4 threads/row)
// ---------------------------------------------------------------------------
__device__ __forceinline__ void stageRows(u16* dst, const u16* __restrict__ srcBase,
                                          const int* ridx, int t)
{
    int e = t >> 2, part = t & 3;
    const u16* src = srcBase + (size_t)ridx[e]*HD + part*32;
    u16* drow = dst + e*128;
    int re = swzr(e & 15);
#pragma unroll
    for (int w = 0; w < 4; ++w) {
        int ci = (part*4 + w) ^ re;
        *(short8*)(drow + (ci << 3)) = *(const short8*)(src + w*8);
    }
}

// ---------------------------------------------------------------------------
// Fused edge kernel (MFMA bf16). 64 edges/block, 256 threads, 3 blocks/CU.
// gf contribution precomputed per-graph (gfp1, G=64) -> ep1 is 2-pass with
// acc[2][4] = 32 AGPRs (fits 3 blocks/CU without spill).
// ---------------------------------------------------------------------------
__global__ __launch_bounds__(256, 3)
void edge_mlp_mfma(const u16* __restrict__ hbf, const float* __restrict__ gfp1,
                   const int* __restrict__ ei, const int* __restrict__ batch,
                   const float* __restrict__ ea,
                   const float* __restrict__ ew1, const float* __restrict__ eb1,
                   const u16* __restrict__ ew2p, const float* __restrict__ eb2,
                   const u16* __restrict__ ew3p, const float* __restrict__ eb3,
                   const float* __restrict__ egm, const float* __restrict__ ebb,
                   const u16* __restrict__ p1wp, const float* __restrict__ p1b,
                   const u16* __restrict__ p2wp, const float* __restrict__ p2b,
                   const u16* __restrict__ p3wp, const float* __restrict__ p3b,
                   const float* __restrict__ p4w, const float* __restrict__ p4b,
                   float* __restrict__ out)
{
    __shared__ u16 bufChunk[64*HD];    // 16KB swizzled A-chunk
    __shared__ u16 bufWide[64*256];    // 32KB (2 chunks / fp32 scratch)
    __shared__ float sEa[192];
    __shared__ int sSrc[64], sDst[64], sGf[64];
    __shared__ float rstat[128];

    const int t = threadIdx.x;
    const int l = t & 63;
    const int wid = t >> 6;
    const int e0 = blockIdx.x * 64;

    if (t < 64) {
        int s = ei[e0 + t];
        sSrc[t] = s;
        sDst[t] = ei[NE + e0 + t];
        sGf[t]  = batch[s];
    }
    if (t < 192) sEa[t] = ea[e0*3 + t];
    __syncthreads();

    // ---- enc1: relu(ea@ew1+b1) -> bufChunk ----
    for (int it = 0; it < 16; ++it) {
        int dw = it*256 + t;
        int e = dw >> 6, cd = dw & 63;
        int c0 = cd*2;
        float x0 = sEa[e*3], x1 = sEa[e*3+1], x2 = sEa[e*3+2];
        float v0 = eb1[c0]   + x0*ew1[c0]   + x1*ew1[HD+c0]   + x2*ew1[2*HD+c0];
        float v1 = eb1[c0+1] + x0*ew1[c0+1] + x1*ew1[HD+c0+1] + x2*ew1[2*HD+c0+1];
        v0 = fmaxf(v0, 0.f); v1 = fmaxf(v1, 0.f);
        int ci = cd >> 2;
        ((u32*)bufChunk)[e*64 + ((ci ^ swzr(e & 15)) << 2) + (cd & 3)] = cvtpk(v0, v1);
    }
    __syncthreads();

    // ---- enc2: relu(A@ew2+b2) -> bufWide chunk0 ----
    {
        f32x4 acc[4][2];
#pragma unroll
        for (int ni = 0; ni < 2; ++ni) {
            float b = eb2[(2*wid + ni)*16 + (l & 15)];
#pragma unroll
            for (int mi = 0; mi < 4; ++mi) acc[mi][ni] = (f32x4){b,b,b,b};
        }
#pragma unroll
        for (int kk = 0; kk < 4; ++kk) {
            short8 af[4];
#pragma unroll
            for (int mi = 0; mi < 4; ++mi) af[mi] = loadA(bufChunk, mi, kk, l);
#pragma unroll
            for (int ni = 0; ni < 2; ++ni) {
                short8 bw = loadB(ew2p, 2*wid + ni, kk, 4, l);
#pragma unroll
                for (int mi = 0; mi < 4; ++mi) acc[mi][ni] = MFMA16(af[mi], bw, acc[mi][ni]);
            }
        }
#pragma unroll
        for (int ni = 0; ni < 2; ++ni) {
            int col = (2*wid + ni)*16 + (l & 15);
#pragma unroll
            for (int mi = 0; mi < 4; ++mi) {
                int R = mi*16 + ((l >> 4) << 2);
                storeQuad((u32*)bufWide, R, col, l,
                          fmaxf(acc[mi][ni][0], 0.f), fmaxf(acc[mi][ni][1], 0.f),
                          fmaxf(acc[mi][ni][2], 0.f), fmaxf(acc[mi][ni][3], 0.f));
            }
        }
    }
    __syncthreads();

    // ---- enc3: W0@ew3+b3 (pre-LN) -> bufChunk ----
    {
        f32x4 acc[4][2];
#pragma unroll
        for (int ni = 0; ni < 2; ++ni) {
            float b = eb3[(2*wid + ni)*16 + (l & 15)];
#pragma unroll
            for (int mi = 0; mi < 4; ++mi) acc[mi][ni] = (f32x4){b,b,b,b};
        }
#pragma unroll
        for (int kk = 0; kk < 4; ++kk) {
            short8 af[4];
#pragma unroll
            for (int mi = 0; mi < 4; ++mi) af[mi] = loadA(bufWide, mi, kk, l);
#pragma unroll
            for (int ni = 0; ni < 2; ++ni) {
                short8 bw = loadB(ew3p, 2*wid + ni, kk, 4, l);
#pragma unroll
                for (int mi = 0; mi < 4; ++mi) acc[mi][ni] = MFMA16(af[mi], bw, acc[mi][ni]);
            }
        }
#pragma unroll
        for (int ni = 0; ni < 2; ++ni) {
            int col = (2*wid + ni)*16 + (l & 15);
#pragma unroll
            for (int mi = 0; mi < 4; ++mi) {
                int R = mi*16 + ((l >> 4) << 2);
                storeQuad((u32*)bufChunk, R, col, l,
                          acc[mi][ni][0], acc[mi][ni][1], acc[mi][ni][2], acc[mi][ni][3]);
            }
        }
    }
    __syncthreads();

    // ---- stage h[src]->bufWide[0], h[dst]->bufWide[1] (enc2 data dead) ----
    stageRows(bufWide,        hbf, sSrc, t);
    stageRows(bufWide + 8192, hbf, sDst, t);

    // ---- LN stats: 4 lanes per edge ----
    {
        int e = wid*16 + (l >> 2);
        int q = l & 3;
        const u32* rowp = (const u32*)bufChunk + e*64;
        float s = 0.f, sq = 0.f;
#pragma unroll
        for (int i = 0; i < 16; ++i) {
            u32 pk = rowp[q*16 + ((i + e) & 15)];
            float a = bf2f(pk & 0xffffu), b = bf2f(pk >> 16);
            s += a + b;
            sq = fmaf(a, a, fmaf(b, b, sq));
        }
        s  += __shfl_xor(s, 1);  sq += __shfl_xor(sq, 1);
        s  += __shfl_xor(s, 2);  sq += __shfl_xor(sq, 2);
        if (q == 0) {
            float mu = s * (1.f/HD);
            rstat[e] = mu;
            rstat[64 + e] = rsqrtf(sq*(1.f/HD) - mu*mu + LN_EPS);
        }
    }
    __syncthreads();

    // ---- normalize in place: bufChunk = ef ----
    for (int it = 0; it < 16; ++it) {
        int pd = it*256 + t;
        int row = pd >> 6, cwd = pd & 63;
        int ci = (cwd >> 2) ^ swzr(row & 15);
        int col = ci*8 + (cwd & 3)*2;
        u32 pk = ((u32*)bufChunk)[pd];
        float mu = rstat[row], ri = rstat[64 + row];
        float v0 = (bf2f(pk & 0xffffu) - mu)*ri*egm[col]     + ebb[col];
        float v1 = (bf2f(pk >> 16)     - mu)*ri*egm[col + 1] + ebb[col + 1];
        ((u32*)bufChunk)[pd] = cvtpk(v0, v1);
    }
    __syncthreads();

    // ---- ep1 MFMA: 2 passes over row halves, acc[2][4] = 32 AGPRs.
    //      K-slices: hsrc (ks 0..3, bufWide), hdst (ks 4..7, bufWide+8192),
    //      ef (ks 12..15, bufChunk). gf contribution added from gfp1 table.
    //      Pass ph writes output rows 32*ph..32*ph+31; pass 1 reads A rows
    //      32..63 only -> no intra-loop barrier needed (disjoint LDS rows).
#pragma unroll
    for (int ph = 0; ph < 2; ++ph) {
        f32x4 acc[2][4];
#pragma unroll
        for (int ni = 0; ni < 4; ++ni) {
            float b = p1b[(4*wid + ni)*16 + (l & 15)];
#pragma unroll
            for (int m = 0; m < 2; ++m) acc[m][ni] = (f32x4){b,b,b,b};
        }
#pragma unroll
        for (int kk = 0; kk < 4; ++kk) {
            short8 af[2];
#pragma unroll
            for (int m = 0; m < 2; ++m) af[m] = loadA(bufWide, 2*ph + m, kk, l);
#pragma unroll
            for (int ni = 0; ni < 4; ++ni) {
                short8 bw = loadB(p1wp, 4*wid + ni, kk, 16, l);
#pragma unroll
                for (int m = 0; m < 2; ++m) acc[m][ni] = MFMA16(af[m], bw, acc[m][ni]);
            }
        }
#pragma unroll
        for (int kk = 0; kk < 4; ++kk) {
            short8 af[2];
#pragma unroll
            for (int m = 0; m < 2; ++m) af[m] = loadA(bufWide + 8192, 2*ph + m, kk, l);
#pragma unroll
            for (int ni = 0; ni < 4; ++ni) {
                short8 bw = loadB(p1wp, 4*wid + ni, 4 + kk, 16, l);
#pragma unroll
                for (int m = 0; m < 2; ++m) acc[m][ni] = MFMA16(af[m], bw, acc[m][ni]);
            }
        }
#pragma unroll
        for (int kk = 0; kk < 4; ++kk) {
            short8 af[2];
#pragma unroll
            for (int m = 0; m < 2; ++m) af[m] = loadA(bufChunk, 2*ph + m, kk, l);
#pragma unroll
            for (int ni = 0; ni < 4; ++ni) {
                short8 bw = loadB(p1wp, 4*wid + ni, 12 + kk, 16, l);
#pragma unroll
                for (int m = 0; m < 2; ++m) acc[m][ni] = MFMA16(af[m], bw, acc[m][ni]);
            }
        }
        // epilogue: add per-graph gfp1 row, tanh, pack to bufWide rows 32ph..
#pragma unroll
        for (int m = 0; m < 2; ++m) {
            int R = (2*ph + m)*16 + ((l >> 4) << 2);
            int g0 = sGf[R], g1 = sGf[R+1], g2 = sGf[R+2], g3 = sGf[R+3];
#pragma unroll
            for (int ni = 0; ni < 4; ++ni) {
                int col = (4*wid + ni)*16 + (l & 15);
                u32* dst = (u32*)bufWide + ((col >> 7) << 12);
                int cc = col & 127;
                storeQuad(dst, R, cc, l,
                          fast_tanh(acc[m][ni][0] + gfp1[g0*256 + col]),
                          fast_tanh(acc[m][ni][1] + gfp1[g1*256 + col]),
                          fast_tanh(acc[m][ni][2] + gfp1[g2*256 + col]),
                          fast_tanh(acc[m][ni][3] + gfp1[g3*256 + col]));
            }
        }
    }
    __syncthreads();

    // ---- ep2: [64,256]@p2w[256,128], tanh -> bufChunk ----
    {
        f32x4 acc[4][2];
#pragma unroll
        for (int ni = 0; ni < 2; ++ni) {
            float b = p2b[(2*wid + ni)*16 + (l & 15)];
#pragma unroll
            for (int mi = 0; mi < 4; ++mi) acc[mi][ni] = (f32x4){b,b,b,b};
        }
        for (int kc = 0; kc < 2; ++kc) {
            const u16* abuf = bufWide + (kc << 13);
#pragma unroll
            for (int kk = 0; kk < 4; ++kk) {
                short8 af[4];
#pragma unroll
                for (int mi = 0; mi < 4; ++mi) af[mi] = loadA(abuf, mi, kk, l);
                int ks = kc*4 + kk;
#pragma unroll
                for (int ni = 0; ni < 2; ++ni) {
                    short8 bw = loadB(p2wp, 2*wid + ni, ks, 8, l);
#pragma unroll
                    for (int mi = 0; mi < 4; ++mi) acc[mi][ni] = MFMA16(af[mi], bw, acc[mi][ni]);
                }
            }
        }
#pragma unroll
        for (int ni = 0; ni < 2; ++ni) {
            int col = (2*wid + ni)*16 + (l & 15);
#pragma unroll
            for (int mi = 0; mi < 4; ++mi) {
                int R = mi*16 + ((l >> 4) << 2);
                storeQuad((u32*)bufChunk, R, col, l,
                          fast_tanh(acc[mi][ni][0]), fast_tanh(acc[mi][ni][1]),
                          fast_tanh(acc[mi][ni][2]), fast_tanh(acc[mi][ni][3]));
            }
        }
    }
    __syncthreads();

    // ---- ep3: [64,128]@p3w[128,64], relu -> bufWide fp32 stride-65 ----
    {
        f32x4 acc[4];
        {
            float b = p3b[wid*16 + (l & 15)];
#pragma unroll
            for (int mi = 0; mi < 4; ++mi) acc[mi] = (f32x4){b,b,b,b};
        }
#pragma unroll
        for (int kk = 0; kk < 4; ++kk) {
            short8 af[4];
#pragma unroll
            for (int mi = 0; mi < 4; ++mi) af[mi] = loadA(bufChunk, mi, kk, l);
            short8 bw = loadB(p3wp, wid, kk, 4, l);
#pragma unroll
            for (int mi = 0; mi < 4; ++mi) acc[mi] = MFMA16(af[mi], bw, acc[mi]);
        }
        float* fb = (float*)bufWide;
        int col = wid*16 + (l & 15);
#pragma unroll
        for (int mi = 0; mi < 4; ++mi)
#pragma unroll
            for (int rr = 0; rr < 4; ++rr) {
                int row = mi*16 + ((l >> 4) << 2) + rr;
                fb[row*65 + col] = fmaxf(acc[mi][rr], 0.f);
            }
    }
    __syncthreads();

    // ---- ep4: 4 lanes/edge dot-64 + sigmoid ----
    {
        const float* fb = (const float*)bufWide;
        int e = wid*16 + (l >> 2), q = l & 3;
        float v = 0.f;
#pragma unroll
        for (int k = 0; k < 16; ++k) {
            int i = q*16 + k;
            v = fmaf(fb[e*65 + i], p4w[i], v);
        }
        v += __shfl_xor(v, 1);
        v += __shfl_xor(v, 2);
        if (q == 0) out[e0 + e] = fast_sigmoid(v + p4b[0]);
    }
}

// ---------------------------------------------------------------------------
extern "C" void kernel_launch(void* const* d_in, const int* in_sizes, int n_in,
                              void* d_out, int out_size, void* d_ws, size_t ws_size,
                              hipStream_t stream)
{
    const float* x     = (const float*)d_in[0];
    const int*   ei    = (const int*)  d_in[1];
    const float* ea    = (const float*)d_in[2];
    const int*   batch = (const int*)  d_in[3];
    const float* ne1w = (const float*)d_in[4];  const float* ne1b = (const float*)d_in[5];
    const float* ne2w = (const float*)d_in[6];  const float* ne2b = (const float*)d_in[7];
    const float* ne3w = (const float*)d_in[8];  const float* ne3b = (const float*)d_in[9];
    const float* neg  = (const float*)d_in[10]; const float* nebb = (const float*)d_in[11];
    const float* ee1w = (const float*)d_in[12]; const float* ee1b = (const float*)d_in[13];
    const float* ee2w = (const float*)d_in[14]; const float* ee2b = (const float*)d_in[15];
    const float* ee3w = (const float*)d_in[16]; const float* ee3b = (const float*)d_in[17];
    const float* eeg  = (const float*)d_in[18]; const float* eebb = (const float*)d_in[19];
    const float* g1w  = (const float*)d_in[20]; const float* g1b  = (const float*)d_in[21];
    const float* g2w  = (const float*)d_in[22]; const float* g2b  = (const float*)d_in[23];
    const float* gp1w = (const float*)d_in[24]; const float* gp1b = (const float*)d_in[25];
    const float* gp2w = (const float*)d_in[26]; const float* gp2b = (const float*)d_in[27];
    const float* gpg  = (const float*)d_in[28]; const float* gpbb = (const float*)d_in[29];
    const float* p1w  = (const float*)d_in[30]; const float* p1b  = (const float*)d_in[31];
    const float* p2w  = (const float*)d_in[32]; const float* p2b  = (const float*)d_in[33];
    const float* p3w  = (const float*)d_in[34]; const float* p3b  = (const float*)d_in[35];
    const float* p4w  = (const float*)d_in[36]; const float* p4b  = (const float*)d_in[37];

    float* dinv = (float*)d_ws;                // NN
    float* sums = dinv + NN;                   // NG*HD
    float* cnts = sums + NG*HD;                // NG
    float* gfp1 = cnts + NG;                   // NG*256
    int* degi   = (int*)(gfp1 + NG*256);       // NN
    int* cursor = degi + NN;                   // NN+2
    int* rowptr = cursor + NN + 2;             // NN+2
    int* sadj   = rowptr + NN + 2;             // NE
    u16* xw1p   = (u16*)(sadj + NE);           // NN*HD
    u16* xw2p   = xw1p + (size_t)NN*HD;        // NN*HD
    u16* hbf    = xw2p + (size_t)NN*HD;        // NN*HD
    u16* wpk    = hbf + (size_t)NN*HD;         // 270336
    u16* ee2p = wpk;
    u16* ee3p = wpk + 16384;
    u16* p1p  = wpk + 32768;
    u16* p2p  = wpk + 163840;
    u16* p3p  = wpk + 196608;
    u16* ne2p = wpk + 204800;
    u16* ne3p = wpk + 221184;
    u16* g1p  = wpk + 237568;
    u16* g2p  = wpk + 253952;

    float* out = (float*)d_out;

    hipMemsetAsync(degi, 0, (size_t)(2*NN + 2)*sizeof(int), stream);
    hipMemsetAsync(sums, 0, (size_t)(NG*HD + NG)*sizeof(float), stream);

    pack_all<<<(270336 + 255)/256, 256, 0, stream>>>(ee2w, ee3w, p1w, p2w, p3w,
                                                     ne2w, ne3w, g1w, g2w, wpk);

    // CSR build (+dinv fused into scan)
    deg_count_int<<<(NE + 255)/256, 256, 0, stream>>>(ei, degi);
    scan_excl<<<1, 1024, 0, stream>>>(degi, rowptr, dinv);
    fill_csr<<<(NE + 255)/256, 256, 0, stream>>>(ei, rowptr, cursor, sadj);

    // node encoder + g1 GEMM (bf16 out, prescaled by dinv)
    enc_mfma<<<(NN + 63)/64, 256, 0, stream>>>(x, ne1w, ne1b, ne2p, ne2b, ne3p, ne3b,
                                               neg, nebb, g1p, dinv, (u32*)xw1p);
    // GCN1 gather + relu + g2 GEMM
    gcn_agg1_mfma<<<(NN + 63)/64, 256, 0, stream>>>(xw1p, rowptr, sadj, dinv,
                                                    g1b, g2p, (u32*)xw2p);
    // GCN2 gather -> hbf bf16
    gcn_agg2_gather<<<(NN + 63)/64, 256, 0, stream>>>(xw2p, rowptr, sadj, dinv,
                                                      g2b, (u32*)hbf);

    // pool (+counts fused) + graph MLP (+gfp1 precompute)
    pool_sorted<<<POOL_B, 128, 0, stream>>>(hbf, batch, sums, cnts);
    graph_feat<<<NG, 128, 0, stream>>>(sums, cnts, gp1w, gp1b, gp2w, gp2b,
                                       gpg, gpbb, p1w, gfp1);

    // fused edge encoder + edge-score MLP
    edge_mlp_mfma<<<NE/64, 256, 0, stream>>>(hbf, gfp1, ei, batch, ea,
                                             ee1w, ee1b, ee2p, ee2b, ee3p, ee3b,
                                             eeg, eebb,
                                             p1p, p1b, p2p, p2b, p3p, p3b,
                                             p4w, p4b, out);
}